// Round 9
// baseline (503.234 us; speedup 1.0000x reference)
//
#include <hip/hip_runtime.h>
#include <hip/hip_bf16.h>

typedef __hip_bfloat16 bf16;
typedef unsigned short u16;
typedef unsigned char u8;
typedef unsigned int u32;
typedef __attribute__((ext_vector_type(8))) unsigned short us8;

static __device__ __forceinline__ float b2f(bf16 v) { return __bfloat162float(v); }
static __device__ __forceinline__ float bfu2f(u32 u) {
    union { u32 i; float f; } c; c.i = u << 16; return c.f;
}
static __device__ __forceinline__ u16 f2bfu(float f) {
    u32 x = __float_as_uint(f);
    return (u16)((x + 0x7FFFu + ((x >> 16) & 1u)) >> 16);
}

#define TILE 4096        // edges per partition block
#define CBITS 12         // coarse bucket = 4096-vertex range (all stages)
#define CRANGE 4096
#define OUTB 26624       // build staging capacity (tot ~24.5K + >8 sigma); 104 KB
#define RPT16(M) M(0) M(1) M(2) M(3) M(4) M(5) M(6) M(7) \
                 M(8) M(9) M(10) M(11) M(12) M(13) M(14) M(15)

struct SP {
    const int* src; const int* dst;
    int E, N, cap, nb, nblk, nbpad;
    int* gcur;      // [nb] per-bucket totals (written by k_part_scan)
    u32* pairs;     // [nb][cap] packed (local_dst12 << 20) | src20
    int* M;         // [nblk][nbpad] counts -> exclusive bases
    int* rowptr; float* dis; int* csr;
};
struct Pack {
    SP s[4];
    int poff[4];  // tile-grid start offset per stage
    int boff[4];  // bucket-grid start offset per stage
};

// ---------------- dtype detection ----------------
__global__ void k_detect(const u16* __restrict__ xraw, int* __restrict__ flag) {
    __shared__ int s;
    if (threadIdx.x == 0) s = 0;
    __syncthreads();
    u16 u = xraw[threadIdx.x];
    int e = (u >> 7) & 0xFF;
    if (e >= 0x8F) atomicAdd(&s, 1);
    __syncthreads();
    if (threadIdx.x == 0) flag[0] = (s > 0) ? 1 : 0;
}

// zero gcur (4 x 256) + rowptr sentinels
__global__ void k_init(int* __restrict__ gcur_all, Pack pk) {
    int i = blockIdx.x * blockDim.x + threadIdx.x;
    if (i < 1024) gcur_all[i] = 0;
    if (i < 4) pk.s[i].rowptr[pk.s[i].N] = pk.s[i].E;
}

// ---------------- pass A0: per-tile bucket counts -> M[tile][bucket] ----------
__global__ void __launch_bounds__(256) k_part_hist(Pack pk) {
    __shared__ int hist[256];
    int bid = blockIdx.x;
    int si = (bid >= pk.poff[3]) ? 3 : (bid >= pk.poff[2]) ? 2 : (bid >= pk.poff[1]) ? 1 : 0;
    const SP sp = pk.s[si];
    int lb = bid - pk.poff[si];
    int t = threadIdx.x;
    int n = min(TILE, sp.E - lb * TILE);
    const int* dstp = sp.dst + lb * TILE;

#define LOADK(k) int d##k; { int i = t + 256*(k); d##k = (i < n) ? dstp[i] : -1; }
    RPT16(LOADK)
#undef LOADK
    hist[t] = 0;
    __syncthreads();
#define HISTK(k) if (d##k >= 0) atomicAdd(&hist[d##k >> CBITS], 1);
    RPT16(HISTK)
#undef HISTK
    __syncthreads();
    int* Mrow = sp.M + (size_t)lb * sp.nbpad;
    for (int b = t; b < sp.nb; b += 256) Mrow[b] = hist[b];
}

// ---------------- pass A-scan: per-bucket column scan of M (in place) --------
__global__ void __launch_bounds__(256) k_part_scan(Pack pk) {
    __shared__ int buf[256];
    int bid = blockIdx.x;
    int si = (bid >= pk.boff[3]) ? 3 : (bid >= pk.boff[2]) ? 2 : (bid >= pk.boff[1]) ? 1 : 0;
    const SP sp = pk.s[si];
    int b = bid - pk.boff[si];
    int t = threadIdx.x;
    int nblk = sp.nblk, nbpad = sp.nbpad;
    int* M = sp.M;
    int carry = 0;
    for (int base = 0; base < nblk; base += 256) {
        int m = min(256, nblk - base);
        int v = (t < m) ? M[(size_t)(base + t) * nbpad + b] : 0;
        buf[t] = v;
        __syncthreads();
        for (int off = 1; off < 256; off <<= 1) {
            int w = (t >= off) ? buf[t - off] : 0;
            __syncthreads();
            buf[t] += w;
            __syncthreads();
        }
        int excl = buf[t] - v + carry;
        int ctot = buf[255];
        __syncthreads();
        if (t < m) M[(size_t)(base + t) * nbpad + b] = excl;
        carry += ctot;
    }
    if (t == 0) sp.gcur[b] = carry;
}

// ---------------- pass A1: scatter to pairs at deterministic bases -----------
__global__ void __launch_bounds__(256) k_partition(Pack pk) {
    __shared__ u32 stage[TILE];   // 16 KB
    __shared__ u8  bkt[TILE];     //  4 KB
    __shared__ int hist[256];
    __shared__ int gofs[256];
    __shared__ int tmp[256];

    int bid = blockIdx.x;
    int si = (bid >= pk.poff[3]) ? 3 : (bid >= pk.poff[2]) ? 2 : (bid >= pk.poff[1]) ? 1 : 0;
    const SP sp = pk.s[si];
    int lb = bid - pk.poff[si];
    int t = threadIdx.x;
    int n = min(TILE, sp.E - lb * TILE);
    const int* dstp = sp.dst + lb * TILE;
    const int* srcp = sp.src + lb * TILE;

#define LOADK(k) int d##k, s##k; { int i = t + 256*(k); \
    if (i < n) { d##k = dstp[i]; s##k = srcp[i]; } else { d##k = -1; s##k = 0; } }
    RPT16(LOADK)
#undef LOADK

    hist[t] = 0;
    __syncthreads();
#define HISTK(k) if (d##k >= 0) atomicAdd(&hist[d##k >> CBITS], 1);
    RPT16(HISTK)
#undef HISTK
    __syncthreads();

    int h = hist[t];
    tmp[t] = h; __syncthreads();
    for (int off = 1; off < 256; off <<= 1) {
        int v = (t >= off) ? tmp[t - off] : 0;
        __syncthreads();
        tmp[t] += v;
        __syncthreads();
    }
    int lofs = tmp[t] - h;
    int gb = (t < sp.nb) ? sp.M[(size_t)lb * sp.nbpad + t] : 0;  // scanned base
    gofs[t] = gb - lofs;
    hist[t] = lofs;   // scatter cursor
    __syncthreads();

#define SCATK(k) if (d##k >= 0) { int b = d##k >> CBITS; \
    int pos = atomicAdd(&hist[b], 1); \
    stage[pos] = (((u32)d##k & 4095u) << 20) | (u32)s##k; \
    bkt[pos] = (u8)b; }
    RPT16(SCATK)
#undef SCATK
    __syncthreads();

    int cap = sp.cap;
    u32* pairs = sp.pairs;
    for (int i = t; i < n; i += 256) {
        int b = bkt[i];
        pairs[(size_t)b * cap + gofs[b] + i] = stage[i];
    }
}

// ---------------- bucket-base scan (one block per stage) ----------------
__global__ void k_scan_bbase(Pack pk, int* __restrict__ bbase_all) {
    __shared__ int tmp[256];
    int si = blockIdx.x;
    int t = threadIdx.x;
    int nb = pk.s[si].nb;
    int v = (t < nb) ? pk.s[si].gcur[t] : 0;
    tmp[t] = v; __syncthreads();
    for (int off = 1; off < 256; off <<= 1) {
        int w = (t >= off) ? tmp[t - off] : 0;
        __syncthreads();
        tmp[t] += w;
        __syncthreads();
    }
    bbase_all[si * 256 + t] = tmp[t] - v;
}

// ---------------- build: one block per coarse bucket, 3 passes --------------
__global__ void __launch_bounds__(512) k_build(Pack pk, const int* __restrict__ bbase_all) {
    __shared__ int hist[4096];    //  16 KB: counts -> local offsets -> cursor
    __shared__ int outb[OUTB];    // 104 KB staged csr for the whole bucket
    __shared__ int tmp[512];

    int bid = blockIdx.x;
    int si = (bid >= pk.boff[3]) ? 3 : (bid >= pk.boff[2]) ? 2 : (bid >= pk.boff[1]) ? 1 : 0;
    const SP sp = pk.s[si];
    int b = bid - pk.boff[si];
    int t = threadIdx.x;

    int bbase = bbase_all[si * 256 + b];
    int tot = sp.gcur[b];
    const u32* p = sp.pairs + (size_t)b * sp.cap;   // 16B aligned (cap % 4 == 0)
    const uint4* p4 = (const uint4*)p;
    int tot4 = tot >> 2;

    for (int i = t; i < 4096; i += 512) hist[i] = 0;
    __syncthreads();
    for (int i = t; i < tot4; i += 512) {
        uint4 u = p4[i];
        atomicAdd(&hist[u.x >> 20], 1);
        atomicAdd(&hist[u.y >> 20], 1);
        atomicAdd(&hist[u.z >> 20], 1);
        atomicAdd(&hist[u.w >> 20], 1);
    }
    for (int i = (tot4 << 2) + t; i < tot; i += 512)
        atomicAdd(&hist[p[i] >> 20], 1);
    __syncthreads();

    // in-place exclusive scan of 4096 bins; counts in registers (8/thread)
    int lbase = t * 8;
    int cnt[8], cof[8];
    #pragma unroll
    for (int k = 0; k < 8; k++) cnt[k] = hist[lbase + k];
    int s = 0;
    #pragma unroll
    for (int k = 0; k < 8; k++) { cof[k] = s; s += cnt[k]; }
    tmp[t] = s; __syncthreads();
    for (int off = 1; off < 512; off <<= 1) {
        int v = (t >= off) ? tmp[t - off] : 0;
        __syncthreads();
        tmp[t] += v;
        __syncthreads();
    }
    int tb = tmp[t] - s;

    int nbase = b << CBITS;
    #pragma unroll
    for (int k = 0; k < 8; k++) {
        int bin = lbase + k;
        hist[bin] = tb + cof[k];          // bucket-local offset (-> cursor)
        int v = nbase + bin;
        if (v < sp.N) {
            sp.rowptr[v] = bbase + tb + cof[k];
            sp.dis[v] = rsqrtf((float)(cnt[k] + 1));
        }
    }
    __syncthreads();

    if (tot <= OUTB) {
        for (int i = t; i < tot4; i += 512) {
            uint4 u = p4[i];
            int pos;
            pos = atomicAdd(&hist[u.x >> 20], 1); outb[pos] = (int)(u.x & 0xFFFFFu);
            pos = atomicAdd(&hist[u.y >> 20], 1); outb[pos] = (int)(u.y & 0xFFFFFu);
            pos = atomicAdd(&hist[u.z >> 20], 1); outb[pos] = (int)(u.z & 0xFFFFFu);
            pos = atomicAdd(&hist[u.w >> 20], 1); outb[pos] = (int)(u.w & 0xFFFFFu);
        }
        for (int i = (tot4 << 2) + t; i < tot; i += 512) {
            u32 u = p[i];
            int pos = atomicAdd(&hist[u >> 20], 1);
            outb[pos] = (int)(u & 0xFFFFFu);
        }
        __syncthreads();
        for (int i = t; i < tot; i += 512)
            sp.csr[bbase + i] = outb[i];
    } else {  // statistical overflow fallback: direct global scatter
        for (int i = t; i < tot; i += 512) {
            u32 u = p[i];
            int pos = atomicAdd(&hist[u >> 20], 1);
            sp.csr[bbase + pos] = (int)(u & 0xFFFFFu);
        }
    }
}

// ---------------- pre-scale: g[v,f] = dis[v] * x_in[row(v), f] ----------------
template <int F, bool EXT>
__global__ void k_pre(const void* __restrict__ xin, const int* __restrict__ gidx,
                      const bf16* __restrict__ actin, const float* __restrict__ dis,
                      bf16* __restrict__ g, const int* __restrict__ flag, int total) {
    int i = blockIdx.x * blockDim.x + threadIdx.x;
    if (i >= total) return;
    int v = i / F;
    int f = i - v * F;
    float x;
    if (EXT) {
        if (flag[0]) x = ((const float*)xin)[i];
        else         x = b2f(((const bf16*)xin)[i]);
    } else {
        int row = gidx[v];
        x = b2f(actin[(size_t)row * F + f]);
    }
    g[i] = __float2bfloat16(dis[v] * x);
}

// ---------------- streaming matmul: h[v,:] = actin[v,:] @ W  (no gather) -----
// x streamed 8-at-a-time -> only y[FOUT] live (no spill at FIN=64).
template <int FIN, int FOUT>
__global__ void __launch_bounds__(256) k_matmul_seq(
        const bf16* __restrict__ actin, const void* __restrict__ W,
        bf16* __restrict__ h, const int* __restrict__ flag, int n) {
    __shared__ float Ws[FIN * FOUT];
    const int f32m = flag[0];
    for (int i = threadIdx.x; i < FIN * FOUT; i += blockDim.x)
        Ws[i] = f32m ? ((const float*)W)[i] : b2f(((const bf16*)W)[i]);
    __syncthreads();
    int v = blockIdx.x * blockDim.x + threadIdx.x;
    if (v >= n) return;
    float y[FOUT];
    #pragma unroll
    for (int f = 0; f < FOUT; f++) y[f] = 0.f;
    #pragma unroll
    for (int k8 = 0; k8 < FIN / 8; k8++) {
        us8 xv = *(const us8*)(actin + (size_t)v * FIN + k8 * 8);
        #pragma unroll
        for (int j = 0; j < 8; j++) {
            float xk = bfu2f((u32)(u16)xv[j]);
            const float* wrow = &Ws[(k8 * 8 + j) * FOUT];
            #pragma unroll
            for (int f = 0; f < FOUT; f++) y[f] = fmaf(xk, wrow[f], y[f]);
        }
    }
    if constexpr (FOUT % 8 == 0) {
        #pragma unroll
        for (int f8 = 0; f8 < FOUT / 8; f8++) {
            us8 ov;
            #pragma unroll
            for (int j = 0; j < 8; j++) ov[j] = f2bfu(y[f8 * 8 + j]);
            *(us8*)(h + (size_t)v * FOUT + f8 * 8) = ov;
        }
    } else {
        #pragma unroll
        for (int f = 0; f < FOUT; f++)
            h[(size_t)v * FOUT + f] = __float2bfloat16(y[f]);
    }
}

// ---------------- post matmul (agg-first): act = relu(xt @ W + b) -----------
// FOUT processed in chunks of <=32: x[FIN] + y[chunk] live -> no spill.
template <int FIN, int FOUT>
__global__ void __launch_bounds__(256) k_matmul_post(
        const bf16* __restrict__ xt, const void* __restrict__ W,
        const void* __restrict__ bias, bf16* __restrict__ act,
        const int* __restrict__ flag, int n) {
    __shared__ float Ws[FIN * FOUT];
    __shared__ float Bs[FOUT];
    const int f32m = flag[0];
    for (int i = threadIdx.x; i < FIN * FOUT; i += blockDim.x)
        Ws[i] = f32m ? ((const float*)W)[i] : b2f(((const bf16*)W)[i]);
    for (int i = threadIdx.x; i < FOUT; i += blockDim.x)
        Bs[i] = f32m ? ((const float*)bias)[i] : b2f(((const bf16*)bias)[i]);
    __syncthreads();
    int v = blockIdx.x * blockDim.x + threadIdx.x;
    if (v >= n) return;
    float x[FIN];
    if constexpr (FIN % 8 == 0) {
        #pragma unroll
        for (int k8 = 0; k8 < FIN / 8; k8++) {
            us8 xv = *(const us8*)(xt + (size_t)v * FIN + k8 * 8);
            #pragma unroll
            for (int j = 0; j < 8; j++) x[k8 * 8 + j] = bfu2f((u32)(u16)xv[j]);
        }
    } else {
        #pragma unroll
        for (int k = 0; k < FIN; k++) x[k] = b2f(xt[(size_t)v * FIN + k]);
    }
    constexpr int CH = (FOUT > 32) ? 32 : FOUT;
    #pragma unroll
    for (int c = 0; c < FOUT; c += CH) {
        float y[CH];
        #pragma unroll
        for (int f = 0; f < CH; f++) y[f] = Bs[c + f];
        #pragma unroll
        for (int k = 0; k < FIN; k++) {
            float xk = x[k];
            const float* wrow = &Ws[k * FOUT + c];
            #pragma unroll
            for (int f = 0; f < CH; f++) y[f] = fmaf(xk, wrow[f], y[f]);
        }
        if constexpr (CH % 8 == 0) {
            #pragma unroll
            for (int f8 = 0; f8 < CH / 8; f8++) {
                us8 ov;
                #pragma unroll
                for (int j = 0; j < 8; j++) {
                    float val = y[f8 * 8 + j];
                    ov[j] = f2bfu(val > 0.f ? val : 0.f);
                }
                *(us8*)(act + (size_t)v * FOUT + c + f8 * 8) = ov;
            }
        } else {
            #pragma unroll
            for (int f = 0; f < CH; f++)
                act[(size_t)v * FOUT + c + f] = __float2bfloat16(y[f] > 0.f ? y[f] : 0.f);
        }
    }
}

// ---------------- CSR gather, QUAD-FEATURE x DUAL-ROW (FOUT%4==0) ----------
template <int FOUT, bool FINALIZE>
__global__ void __launch_bounds__(256) k_gather2v(
        const bf16* __restrict__ g, const int* __restrict__ rowptr,
        const int* __restrict__ csr, const float* __restrict__ dis,
        const void* __restrict__ bias, bf16* __restrict__ out,
        const int* __restrict__ flag, int totq, int E) {
    constexpr int Q = FOUT / 4;         // quads per row
    constexpr int W2 = FOUT / 2;        // u32 words per row
    int H = (totq + 1) >> 1;
    int i = blockIdx.x * blockDim.x + threadIdx.x;
    if (i >= H) return;
    int Em1 = E - 1;
    int e1 = i;
    int e2 = i + H;
    int e2c = (e2 < totq) ? e2 : e1;
    int v1 = e1 / Q, q1 = e1 - v1 * Q;
    int v2 = e2c / Q, q2 = e2c - v2 * Q;
    const u32* g32 = (const u32*)g;

    uint2 sv1 = *(const uint2*)(g32 + (size_t)v1 * W2 + q1 * 2);
    uint2 sv2 = *(const uint2*)(g32 + (size_t)v2 * W2 + q2 * 2);
    float s10 = bfu2f(sv1.x & 0xFFFFu), s11 = bfu2f(sv1.x >> 16);
    float s12 = bfu2f(sv1.y & 0xFFFFu), s13 = bfu2f(sv1.y >> 16);
    float s20 = bfu2f(sv2.x & 0xFFFFu), s21 = bfu2f(sv2.x >> 16);
    float s22 = bfu2f(sv2.y & 0xFFFFu), s23 = bfu2f(sv2.y >> 16);

    int r1 = rowptr[v1]; int c1 = rowptr[v1 + 1] - r1;
    int r2 = rowptr[v2]; int c2 = rowptr[v2 + 1] - r2;
    int last1 = min(r1 + (c1 > 0 ? c1 - 1 : 0), Em1);
    int last2 = min(r2 + (c2 > 0 ? c2 - 1 : 0), Em1);
    int j1 = 0, j2 = 0;
    while (j1 < c1 || j2 < c2) {
        int i10 = min(r1 + j1 + 0, last1), i11 = min(r1 + j1 + 1, last1);
        int i12 = min(r1 + j1 + 2, last1), i13 = min(r1 + j1 + 3, last1);
        int i20 = min(r2 + j2 + 0, last2), i21 = min(r2 + j2 + 1, last2);
        int i22 = min(r2 + j2 + 2, last2), i23 = min(r2 + j2 + 3, last2);
        int u10 = csr[i10], u11 = csr[i11], u12 = csr[i12], u13 = csr[i13];
        int u20 = csr[i20], u21 = csr[i21], u22 = csr[i22], u23 = csr[i23];
        uint2 a10 = *(const uint2*)(g32 + (size_t)u10 * W2 + q1 * 2);
        uint2 a11 = *(const uint2*)(g32 + (size_t)u11 * W2 + q1 * 2);
        uint2 a12 = *(const uint2*)(g32 + (size_t)u12 * W2 + q1 * 2);
        uint2 a13 = *(const uint2*)(g32 + (size_t)u13 * W2 + q1 * 2);
        uint2 a20 = *(const uint2*)(g32 + (size_t)u20 * W2 + q2 * 2);
        uint2 a21 = *(const uint2*)(g32 + (size_t)u21 * W2 + q2 * 2);
        uint2 a22 = *(const uint2*)(g32 + (size_t)u22 * W2 + q2 * 2);
        uint2 a23 = *(const uint2*)(g32 + (size_t)u23 * W2 + q2 * 2);
        // zero masked edges on the raw words (bf16 0x0000 == 0.0f)
        if (j1 + 0 >= c1) { a10.x = 0; a10.y = 0; }
        if (j1 + 1 >= c1) { a11.x = 0; a11.y = 0; }
        if (j1 + 2 >= c1) { a12.x = 0; a12.y = 0; }
        if (j1 + 3 >= c1) { a13.x = 0; a13.y = 0; }
        if (j2 + 0 >= c2) { a20.x = 0; a20.y = 0; }
        if (j2 + 1 >= c2) { a21.x = 0; a21.y = 0; }
        if (j2 + 2 >= c2) { a22.x = 0; a22.y = 0; }
        if (j2 + 3 >= c2) { a23.x = 0; a23.y = 0; }
        s10 += bfu2f(a10.x & 0xFFFFu) + bfu2f(a11.x & 0xFFFFu)
             + bfu2f(a12.x & 0xFFFFu) + bfu2f(a13.x & 0xFFFFu);
        s11 += bfu2f(a10.x >> 16) + bfu2f(a11.x >> 16)
             + bfu2f(a12.x >> 16) + bfu2f(a13.x >> 16);
        s12 += bfu2f(a10.y & 0xFFFFu) + bfu2f(a11.y & 0xFFFFu)
             + bfu2f(a12.y & 0xFFFFu) + bfu2f(a13.y & 0xFFFFu);
        s13 += bfu2f(a10.y >> 16) + bfu2f(a11.y >> 16)
             + bfu2f(a12.y >> 16) + bfu2f(a13.y >> 16);
        s20 += bfu2f(a20.x & 0xFFFFu) + bfu2f(a21.x & 0xFFFFu)
             + bfu2f(a22.x & 0xFFFFu) + bfu2f(a23.x & 0xFFFFu);
        s21 += bfu2f(a20.x >> 16) + bfu2f(a21.x >> 16)
             + bfu2f(a22.x >> 16) + bfu2f(a23.x >> 16);
        s22 += bfu2f(a20.y & 0xFFFFu) + bfu2f(a21.y & 0xFFFFu)
             + bfu2f(a22.y & 0xFFFFu) + bfu2f(a23.y & 0xFFFFu);
        s23 += bfu2f(a20.y >> 16) + bfu2f(a21.y >> 16)
             + bfu2f(a22.y >> 16) + bfu2f(a23.y >> 16);
        j1 += 4; j2 += 4;
    }
    float dv1 = dis[v1], dv2 = dis[v2];
    float o1[4] = {s10, s11, s12, s13};
    float o2[4] = {s20, s21, s22, s23};
    uint2 w1, w2;
    if (FINALIZE) {
        int f32m = flag[0];
        #pragma unroll
        for (int k = 0; k < 4; k++) {
            int f1 = q1 * 4 + k, f2 = q2 * 4 + k;
            float bf1 = f32m ? ((const float*)bias)[f1] : b2f(((const bf16*)bias)[f1]);
            float bf2 = f32m ? ((const float*)bias)[f2] : b2f(((const bf16*)bias)[f2]);
            o1[k] = fmaf(dv1, o1[k], bf1); o1[k] = o1[k] > 0.f ? o1[k] : 0.f;
            o2[k] = fmaf(dv2, o2[k], bf2); o2[k] = o2[k] > 0.f ? o2[k] : 0.f;
        }
    } else {
        #pragma unroll
        for (int k = 0; k < 4; k++) { o1[k] *= dv1; o2[k] *= dv2; }
    }
    w1.x = (u32)f2bfu(o1[0]) | ((u32)f2bfu(o1[1]) << 16);
    w1.y = (u32)f2bfu(o1[2]) | ((u32)f2bfu(o1[3]) << 16);
    w2.x = (u32)f2bfu(o2[0]) | ((u32)f2bfu(o2[1]) << 16);
    w2.y = (u32)f2bfu(o2[2]) | ((u32)f2bfu(o2[3]) << 16);
    u32* o32 = (u32*)out;
    *(uint2*)(o32 + (size_t)v1 * W2 + q1 * 2) = w1;
    if (e2 < totq) *(uint2*)(o32 + (size_t)v2 * W2 + q2 * 2) = w2;
}

// ---------------- CSR gather, DUAL-ROW per thread (FOUT=3 path) -------------
template <int FOUT, bool FINALIZE>
__global__ void __launch_bounds__(256) k_gather2(
        const bf16* __restrict__ g, const int* __restrict__ rowptr,
        const int* __restrict__ csr, const float* __restrict__ dis,
        const void* __restrict__ bias, bf16* __restrict__ out,
        const int* __restrict__ flag, int total, int E) {
    int H = (total + 1) >> 1;
    int i = blockIdx.x * blockDim.x + threadIdx.x;
    if (i >= H) return;
    int Em1 = E - 1;
    int e1 = i;
    int e2 = i + H;
    int e2c = (e2 < total) ? e2 : e1;
    int v1 = e1 / FOUT, f1 = e1 - v1 * FOUT;
    int v2 = e2c / FOUT, f2 = e2c - v2 * FOUT;
    float s1 = b2f(g[e1]);    // self-loop terms
    float s2 = b2f(g[e2c]);
    int r1 = rowptr[v1]; int c1 = rowptr[v1 + 1] - r1;
    int r2 = rowptr[v2]; int c2 = rowptr[v2 + 1] - r2;
    int last1 = min(r1 + (c1 > 0 ? c1 - 1 : 0), Em1);
    int last2 = min(r2 + (c2 > 0 ? c2 - 1 : 0), Em1);
    int j1 = 0, j2 = 0;
    while (j1 < c1 || j2 < c2) {
        int i10 = min(r1 + j1 + 0, last1), i11 = min(r1 + j1 + 1, last1);
        int i12 = min(r1 + j1 + 2, last1), i13 = min(r1 + j1 + 3, last1);
        int i20 = min(r2 + j2 + 0, last2), i21 = min(r2 + j2 + 1, last2);
        int i22 = min(r2 + j2 + 2, last2), i23 = min(r2 + j2 + 3, last2);
        int u10 = csr[i10], u11 = csr[i11], u12 = csr[i12], u13 = csr[i13];
        int u20 = csr[i20], u21 = csr[i21], u22 = csr[i22], u23 = csr[i23];
        float a10 = b2f(g[(size_t)u10 * FOUT + f1]);
        float a11 = b2f(g[(size_t)u11 * FOUT + f1]);
        float a12 = b2f(g[(size_t)u12 * FOUT + f1]);
        float a13 = b2f(g[(size_t)u13 * FOUT + f1]);
        float a20 = b2f(g[(size_t)u20 * FOUT + f2]);
        float a21 = b2f(g[(size_t)u21 * FOUT + f2]);
        float a22 = b2f(g[(size_t)u22 * FOUT + f2]);
        float a23 = b2f(g[(size_t)u23 * FOUT + f2]);
        s1 += ((j1 + 0 < c1 ? a10 : 0.f) + (j1 + 1 < c1 ? a11 : 0.f))
            + ((j1 + 2 < c1 ? a12 : 0.f) + (j1 + 3 < c1 ? a13 : 0.f));
        s2 += ((j2 + 0 < c2 ? a20 : 0.f) + (j2 + 1 < c2 ? a21 : 0.f))
            + ((j2 + 2 < c2 ? a22 : 0.f) + (j2 + 3 < c2 ? a23 : 0.f));
        j1 += 4; j2 += 4;
    }
    float dv1 = dis[v1], dv2 = dis[v2];
    float o1, o2;
    if (FINALIZE) {
        float bf1 = flag[0] ? ((const float*)bias)[f1] : b2f(((const bf16*)bias)[f1]);
        float bf2 = flag[0] ? ((const float*)bias)[f2] : b2f(((const bf16*)bias)[f2]);
        o1 = fmaf(dv1, s1, bf1); o1 = o1 > 0.f ? o1 : 0.f;
        o2 = fmaf(dv2, s2, bf2); o2 = o2 > 0.f ? o2 : 0.f;
    } else {
        o1 = dv1 * s1;
        o2 = dv2 * s2;
    }
    out[e1] = __float2bfloat16(o1);
    if (e2 < total) out[e2] = __float2bfloat16(o2);
}

// ---------------- final unpool gather -> out (dtype per flag) ----------------
__global__ void k_gather_out(const bf16* __restrict__ act, const int* __restrict__ idx,
                             void* __restrict__ out, const int* __restrict__ flag, int n) {
    int u = blockIdx.x * blockDim.x + threadIdx.x;
    if (u >= n) return;
    size_t r = (size_t)idx[u];
    float v0 = b2f(act[3 * r + 0]);
    float v1 = b2f(act[3 * r + 1]);
    float v2 = b2f(act[3 * r + 2]);
    if (flag[0]) {
        float* o = (float*)out;
        o[3 * (size_t)u + 0] = v0; o[3 * (size_t)u + 1] = v1; o[3 * (size_t)u + 2] = v2;
    } else {
        bf16* o = (bf16*)out;
        o[3 * (size_t)u + 0] = __float2bfloat16(v0);
        o[3 * (size_t)u + 1] = __float2bfloat16(v1);
        o[3 * (size_t)u + 2] = __float2bfloat16(v2);
    }
}

static inline int cdiv(long long a, long long b) { return (int)((a + b - 1) / b); }

extern "C" void kernel_launch(void* const* d_in, const int* in_sizes, int n_in,
                              void* d_out, int out_size, void* d_ws, size_t ws_size,
                              hipStream_t stream) {
    const void* x  = d_in[0];
    const void* W1 = d_in[1]; const void* b1 = d_in[2];
    const void* W2 = d_in[3]; const void* b2 = d_in[4];
    const void* W3 = d_in[5]; const void* b3 = d_in[6];
    const void* W4 = d_in[7]; const void* b4 = d_in[8];
    const int* e0  = (const int*)d_in[9];
    const int* up1 = (const int*)d_in[10];
    const int* e1  = (const int*)d_in[11];
    const int* up2 = (const int*)d_in[12];
    const int* e2  = (const int*)d_in[13];
    const int* up3 = (const int*)d_in[14];
    const int* e3  = (const int*)d_in[15];
    const int* up4 = (const int*)d_in[16];

    const int N0 = in_sizes[0] / 3;
    const int N1 = in_sizes[10];
    const int N2 = in_sizes[12];
    const int N3 = in_sizes[14];
    const int N4 = in_sizes[16];
    const int E0 = in_sizes[9] / 2, E1 = in_sizes[11] / 2;
    const int E2 = in_sizes[13] / 2, E3 = in_sizes[15] / 2;

    int Ns[4] = {N0, N1, N2, N3};
    int Es[4] = {E0, E1, E2, E3};
    const int* srcs[4] = {e0, e1, e2, e3};
    const int* dsts[4] = {e0 + E0, e1 + E1, e2 + E2, e3 + E3};

    // buffer element counts
    size_t gmax = (size_t)N0 * 3;
    if ((size_t)N1 * 32 > gmax) gmax = (size_t)N1 * 32;
    if ((size_t)N2 * 32 > gmax) gmax = (size_t)N2 * 32;
    if ((size_t)N3 * 3  > gmax) gmax = (size_t)N3 * 3;
    size_t amax = (size_t)N0 * 32;
    if ((size_t)N1 * 64 > amax) amax = (size_t)N1 * 64;
    if ((size_t)N2 * 32 > amax) amax = (size_t)N2 * 32;
    if ((size_t)N3 * 3  > amax) amax = (size_t)N3 * 3;
    gmax = (gmax + 7) & ~(size_t)7;
    amax = (amax + 7) & ~(size_t)7;

    Pack pk;
    char* p = (char*)d_ws;
    int* flag = (int*)p;            p += 256;
    int* gcur_all = (int*)p;        p += 1024 * 4;
    int* bbase_all = (int*)p;       p += 1024 * 4;

    for (int s = 0; s < 4; s++) {
        pk.s[s].src = srcs[s]; pk.s[s].dst = dsts[s];
        pk.s[s].E = Es[s]; pk.s[s].N = Ns[s];
        int nb = cdiv(Ns[s], CRANGE);
        pk.s[s].nb = nb;
        pk.s[s].nblk = cdiv(Es[s], TILE);
        pk.s[s].nbpad = (nb + 15) & ~15;
        pk.s[s].cap = (Es[s] / nb + Es[s] / (8 * nb) + 256 + 3) & ~3;  // % 4 == 0
        pk.s[s].gcur = gcur_all + s * 256;
        pk.s[s].M = (int*)p;        p += (size_t)pk.s[s].nblk * pk.s[s].nbpad * 4;
        pk.s[s].rowptr = (int*)p;   p += ((size_t)(Ns[s] + 1 + 3) & ~(size_t)3) * 4;
        pk.s[s].dis = (float*)p;    p += ((size_t)(Ns[s] + 3) & ~(size_t)3) * 4;
    }
    for (int s = 0; s < 4; s++) {
        pk.s[s].csr = (int*)p;      p += ((size_t)(Es[s] + 3) & ~(size_t)3) * 4;
    }

    // union region (16B aligned): pairs (build) aliases g|act|xt (compute)
    char* U = (char*)(((size_t)p + 15) & ~(size_t)15);
    size_t pairsBytes = 0;
    for (int s = 0; s < 4; s++) {
        pk.s[s].pairs = (u32*)(U + pairsBytes);
        pairsBytes += (size_t)pk.s[s].cap * pk.s[s].nb * 4;
    }
    bf16* g   = (bf16*)U;
    bf16* act = g + gmax;
    bf16* xt  = act + amax;

    // grids
    int ptot = 0, btot = 0;
    for (int s = 0; s < 4; s++) {
        pk.poff[s] = ptot; ptot += pk.s[s].nblk;
        pk.boff[s] = btot; btot += pk.s[s].nb;
    }

    const int B = 256;

    k_detect<<<1, 256, 0, stream>>>((const u16*)x, flag);
    k_init<<<4, 256, 0, stream>>>(gcur_all, pk);
    k_part_hist<<<ptot, B, 0, stream>>>(pk);
    k_part_scan<<<btot, B, 0, stream>>>(pk);
    k_partition<<<ptot, B, 0, stream>>>(pk);
    k_scan_bbase<<<4, B, 0, stream>>>(pk, bbase_all);
    k_build<<<btot, 512, 0, stream>>>(pk, bbase_all);

    // ---- stage 1 (agg-first): aggregate x (3 feats), then @W1 -> 32
    {
        int T = N0 * 3, Hh = (T + 1) >> 1;
        k_pre<3, true><<<cdiv(T, B), B, 0, stream>>>(
            x, nullptr, nullptr, pk.s[0].dis, g, flag, T);
        k_gather2<3, false><<<cdiv(Hh, B), B, 0, stream>>>(
            g, pk.s[0].rowptr, pk.s[0].csr, pk.s[0].dis, nullptr, xt, flag, T, E0);
        k_matmul_post<3, 32><<<cdiv(N0, B), B, 0, stream>>>(xt, W1, b1, act, flag, N0);
    }

    // ---- stage 2 (agg-first): aggregate act1[up1] (32 feats), then @W2 -> 64
    {
        int Tq = N1 * 8, Hq = (Tq + 1) >> 1;
        k_pre<32, false><<<cdiv((long long)N1 * 32, B), B, 0, stream>>>(
            nullptr, up1, act, pk.s[1].dis, g, flag, N1 * 32);
        k_gather2v<32, false><<<cdiv(Hq, B), B, 0, stream>>>(
            g, pk.s[1].rowptr, pk.s[1].csr, pk.s[1].dis, nullptr, xt, flag, Tq, E1);
        k_matmul_post<32, 64><<<cdiv(N1, B), B, 0, stream>>>(xt, W2, b2, act, flag, N1);
    }

    // ---- stage 3 (W-first, matmul BEFORE unpool): h = act2@W3 at N1,
    //      then g[v] = dis[v] * h[up2[v]], then quad-vector aggregate
    {
        int Tq = N2 * 8, Hq = (Tq + 1) >> 1;
        k_matmul_seq<64, 32><<<cdiv(N1, B), B, 0, stream>>>(act, W3, xt, flag, N1);
        k_pre<32, false><<<cdiv((long long)N2 * 32, B), B, 0, stream>>>(
            nullptr, up2, xt, pk.s[2].dis, g, flag, N2 * 32);
        k_gather2v<32, true><<<cdiv(Hq, B), B, 0, stream>>>(
            g, pk.s[2].rowptr, pk.s[2].csr, pk.s[2].dis, b3, act, flag, Tq, E2);
    }

    // ---- stage 4 (W-first, matmul BEFORE unpool): h = act3@W4 at N2,
    //      then g[v] = dis[v] * h[up3[v]] (6B rows from 2.4 MB), then agg
    {
        int T = N3 * 3, Hh = (T + 1) >> 1;
        k_matmul_seq<32, 3><<<cdiv(N2, B), B, 0, stream>>>(act, W4, xt, flag, N2);
        k_pre<3, false><<<cdiv(T, B), B, 0, stream>>>(
            nullptr, up3, xt, pk.s[3].dis, g, flag, T);
        k_gather2<3, true><<<cdiv(Hh, B), B, 0, stream>>>(
            g, pk.s[3].rowptr, pk.s[3].csr, pk.s[3].dis, b4, act, flag, T, E3);
    }

    // ---- final unpool
    k_gather_out<<<cdiv(N4, B), B, 0, stream>>>(act, up4, d_out, flag, N4);
}

// Round 10
// 499.711 us; speedup vs baseline: 1.0071x; 1.0071x over previous
//
#include <hip/hip_runtime.h>
#include <hip/hip_bf16.h>

typedef __hip_bfloat16 bf16;
typedef unsigned short u16;
typedef unsigned char u8;
typedef unsigned int u32;
typedef __attribute__((ext_vector_type(8))) unsigned short us8;

static __device__ __forceinline__ float b2f(bf16 v) { return __bfloat162float(v); }
static __device__ __forceinline__ float bfu2f(u32 u) {
    union { u32 i; float f; } c; c.i = u << 16; return c.f;
}
static __device__ __forceinline__ u16 f2bfu(float f) {
    u32 x = __float_as_uint(f);
    return (u16)((x + 0x7FFFu + ((x >> 16) & 1u)) >> 16);
}

#define TILE 4096        // edges per partition block
#define CBITS 12         // coarse bucket = 4096-vertex range (all stages)
#define CRANGE 4096
#define OUTB 26624       // build staging capacity (tot ~24.5K + >8 sigma); 104 KB
#define RPT16(M) M(0) M(1) M(2) M(3) M(4) M(5) M(6) M(7) \
                 M(8) M(9) M(10) M(11) M(12) M(13) M(14) M(15)

struct SP {
    const int* src; const int* dst;
    int E, N, cap, nb, nblk, nbpad;
    int* gcur;      // [nb] per-bucket totals (written by k_part_scan)
    u32* pairs;     // [nb][cap] packed (local_dst12 << 20) | src20
    int* M;         // [nblk][nbpad] counts -> exclusive bases
    int* rowptr; float* dis; int* csr;
};
struct Pack {
    SP s[4];
    int poff[4];  // tile-grid start offset per stage
    int boff[4];  // bucket-grid start offset per stage
};

// ---------------- dtype detection ----------------
__global__ void k_detect(const u16* __restrict__ xraw, int* __restrict__ flag) {
    __shared__ int s;
    if (threadIdx.x == 0) s = 0;
    __syncthreads();
    u16 u = xraw[threadIdx.x];
    int e = (u >> 7) & 0xFF;
    if (e >= 0x8F) atomicAdd(&s, 1);
    __syncthreads();
    if (threadIdx.x == 0) flag[0] = (s > 0) ? 1 : 0;
}

// zero gcur (4 x 256) + rowptr sentinels
__global__ void k_init(int* __restrict__ gcur_all, Pack pk) {
    int i = blockIdx.x * blockDim.x + threadIdx.x;
    if (i < 1024) gcur_all[i] = 0;
    if (i < 4) pk.s[i].rowptr[pk.s[i].N] = pk.s[i].E;
}

// ---------------- pass A0: per-tile bucket counts -> M[tile][bucket] ----------
__global__ void __launch_bounds__(256) k_part_hist(Pack pk) {
    __shared__ int hist[256];
    int bid = blockIdx.x;
    int si = (bid >= pk.poff[3]) ? 3 : (bid >= pk.poff[2]) ? 2 : (bid >= pk.poff[1]) ? 1 : 0;
    const SP sp = pk.s[si];
    int lb = bid - pk.poff[si];
    int t = threadIdx.x;
    int n = min(TILE, sp.E - lb * TILE);
    const int* dstp = sp.dst + lb * TILE;

#define LOADK(k) int d##k; { int i = t + 256*(k); d##k = (i < n) ? dstp[i] : -1; }
    RPT16(LOADK)
#undef LOADK
    hist[t] = 0;
    __syncthreads();
#define HISTK(k) if (d##k >= 0) atomicAdd(&hist[d##k >> CBITS], 1);
    RPT16(HISTK)
#undef HISTK
    __syncthreads();
    int* Mrow = sp.M + (size_t)lb * sp.nbpad;
    for (int b = t; b < sp.nb; b += 256) Mrow[b] = hist[b];
}

// ---------------- pass A-scan: per-bucket column scan of M (in place) --------
__global__ void __launch_bounds__(256) k_part_scan(Pack pk) {
    __shared__ int buf[256];
    int bid = blockIdx.x;
    int si = (bid >= pk.boff[3]) ? 3 : (bid >= pk.boff[2]) ? 2 : (bid >= pk.boff[1]) ? 1 : 0;
    const SP sp = pk.s[si];
    int b = bid - pk.boff[si];
    int t = threadIdx.x;
    int nblk = sp.nblk, nbpad = sp.nbpad;
    int* M = sp.M;
    int carry = 0;
    for (int base = 0; base < nblk; base += 256) {
        int m = min(256, nblk - base);
        int v = (t < m) ? M[(size_t)(base + t) * nbpad + b] : 0;
        buf[t] = v;
        __syncthreads();
        for (int off = 1; off < 256; off <<= 1) {
            int w = (t >= off) ? buf[t - off] : 0;
            __syncthreads();
            buf[t] += w;
            __syncthreads();
        }
        int excl = buf[t] - v + carry;
        int ctot = buf[255];
        __syncthreads();
        if (t < m) M[(size_t)(base + t) * nbpad + b] = excl;
        carry += ctot;
    }
    if (t == 0) sp.gcur[b] = carry;
}

// ---------------- pass A1: scatter to pairs at deterministic bases -----------
__global__ void __launch_bounds__(256) k_partition(Pack pk) {
    __shared__ u32 stage[TILE];   // 16 KB
    __shared__ u8  bkt[TILE];     //  4 KB
    __shared__ int hist[256];
    __shared__ int gofs[256];
    __shared__ int tmp[256];

    int bid = blockIdx.x;
    int si = (bid >= pk.poff[3]) ? 3 : (bid >= pk.poff[2]) ? 2 : (bid >= pk.poff[1]) ? 1 : 0;
    const SP sp = pk.s[si];
    int lb = bid - pk.poff[si];
    int t = threadIdx.x;
    int n = min(TILE, sp.E - lb * TILE);
    const int* dstp = sp.dst + lb * TILE;
    const int* srcp = sp.src + lb * TILE;

#define LOADK(k) int d##k, s##k; { int i = t + 256*(k); \
    if (i < n) { d##k = dstp[i]; s##k = srcp[i]; } else { d##k = -1; s##k = 0; } }
    RPT16(LOADK)
#undef LOADK

    hist[t] = 0;
    __syncthreads();
#define HISTK(k) if (d##k >= 0) atomicAdd(&hist[d##k >> CBITS], 1);
    RPT16(HISTK)
#undef HISTK
    __syncthreads();

    int h = hist[t];
    tmp[t] = h; __syncthreads();
    for (int off = 1; off < 256; off <<= 1) {
        int v = (t >= off) ? tmp[t - off] : 0;
        __syncthreads();
        tmp[t] += v;
        __syncthreads();
    }
    int lofs = tmp[t] - h;
    int gb = (t < sp.nb) ? sp.M[(size_t)lb * sp.nbpad + t] : 0;  // scanned base
    gofs[t] = gb - lofs;
    hist[t] = lofs;   // scatter cursor
    __syncthreads();

#define SCATK(k) if (d##k >= 0) { int b = d##k >> CBITS; \
    int pos = atomicAdd(&hist[b], 1); \
    stage[pos] = (((u32)d##k & 4095u) << 20) | (u32)s##k; \
    bkt[pos] = (u8)b; }
    RPT16(SCATK)
#undef SCATK
    __syncthreads();

    int cap = sp.cap;
    u32* pairs = sp.pairs;
    for (int i = t; i < n; i += 256) {
        int b = bkt[i];
        pairs[(size_t)b * cap + gofs[b] + i] = stage[i];
    }
}

// ---------------- bucket-base scan (one block per stage) ----------------
__global__ void k_scan_bbase(Pack pk, int* __restrict__ bbase_all) {
    __shared__ int tmp[256];
    int si = blockIdx.x;
    int t = threadIdx.x;
    int nb = pk.s[si].nb;
    int v = (t < nb) ? pk.s[si].gcur[t] : 0;
    tmp[t] = v; __syncthreads();
    for (int off = 1; off < 256; off <<= 1) {
        int w = (t >= off) ? tmp[t - off] : 0;
        __syncthreads();
        tmp[t] += w;
        __syncthreads();
    }
    bbase_all[si * 256 + t] = tmp[t] - v;
}

// ---------------- build: one block per coarse bucket, 3 passes --------------
__global__ void __launch_bounds__(512) k_build(Pack pk, const int* __restrict__ bbase_all) {
    __shared__ int hist[4096];    //  16 KB: counts -> local offsets -> cursor
    __shared__ int outb[OUTB];    // 104 KB staged csr for the whole bucket
    __shared__ int tmp[512];

    int bid = blockIdx.x;
    int si = (bid >= pk.boff[3]) ? 3 : (bid >= pk.boff[2]) ? 2 : (bid >= pk.boff[1]) ? 1 : 0;
    const SP sp = pk.s[si];
    int b = bid - pk.boff[si];
    int t = threadIdx.x;

    int bbase = bbase_all[si * 256 + b];
    int tot = sp.gcur[b];
    const u32* p = sp.pairs + (size_t)b * sp.cap;   // 16B aligned (cap % 4 == 0)
    const uint4* p4 = (const uint4*)p;
    int tot4 = tot >> 2;

    for (int i = t; i < 4096; i += 512) hist[i] = 0;
    __syncthreads();
    for (int i = t; i < tot4; i += 512) {
        uint4 u = p4[i];
        atomicAdd(&hist[u.x >> 20], 1);
        atomicAdd(&hist[u.y >> 20], 1);
        atomicAdd(&hist[u.z >> 20], 1);
        atomicAdd(&hist[u.w >> 20], 1);
    }
    for (int i = (tot4 << 2) + t; i < tot; i += 512)
        atomicAdd(&hist[p[i] >> 20], 1);
    __syncthreads();

    // in-place exclusive scan of 4096 bins; counts in registers (8/thread)
    int lbase = t * 8;
    int cnt[8], cof[8];
    #pragma unroll
    for (int k = 0; k < 8; k++) cnt[k] = hist[lbase + k];
    int s = 0;
    #pragma unroll
    for (int k = 0; k < 8; k++) { cof[k] = s; s += cnt[k]; }
    tmp[t] = s; __syncthreads();
    for (int off = 1; off < 512; off <<= 1) {
        int v = (t >= off) ? tmp[t - off] : 0;
        __syncthreads();
        tmp[t] += v;
        __syncthreads();
    }
    int tb = tmp[t] - s;

    int nbase = b << CBITS;
    #pragma unroll
    for (int k = 0; k < 8; k++) {
        int bin = lbase + k;
        hist[bin] = tb + cof[k];          // bucket-local offset (-> cursor)
        int v = nbase + bin;
        if (v < sp.N) {
            sp.rowptr[v] = bbase + tb + cof[k];
            sp.dis[v] = rsqrtf((float)(cnt[k] + 1));
        }
    }
    __syncthreads();

    if (tot <= OUTB) {
        for (int i = t; i < tot4; i += 512) {
            uint4 u = p4[i];
            int pos;
            pos = atomicAdd(&hist[u.x >> 20], 1); outb[pos] = (int)(u.x & 0xFFFFFu);
            pos = atomicAdd(&hist[u.y >> 20], 1); outb[pos] = (int)(u.y & 0xFFFFFu);
            pos = atomicAdd(&hist[u.z >> 20], 1); outb[pos] = (int)(u.z & 0xFFFFFu);
            pos = atomicAdd(&hist[u.w >> 20], 1); outb[pos] = (int)(u.w & 0xFFFFFu);
        }
        for (int i = (tot4 << 2) + t; i < tot; i += 512) {
            u32 u = p[i];
            int pos = atomicAdd(&hist[u >> 20], 1);
            outb[pos] = (int)(u & 0xFFFFFu);
        }
        __syncthreads();
        for (int i = t; i < tot; i += 512)
            sp.csr[bbase + i] = outb[i];
    } else {  // statistical overflow fallback: direct global scatter
        for (int i = t; i < tot; i += 512) {
            u32 u = p[i];
            int pos = atomicAdd(&hist[u >> 20], 1);
            sp.csr[bbase + pos] = (int)(u & 0xFFFFFu);
        }
    }
}

// ---------------- pre-scale: g[v,f] = dis[v] * x_in[row(v), f] ----------------
template <int F, bool EXT>
__global__ void k_pre(const void* __restrict__ xin, const int* __restrict__ gidx,
                      const bf16* __restrict__ actin, const float* __restrict__ dis,
                      bf16* __restrict__ g, const int* __restrict__ flag, int total) {
    int i = blockIdx.x * blockDim.x + threadIdx.x;
    if (i >= total) return;
    int v = i / F;
    int f = i - v * F;
    float x;
    if (EXT) {
        if (flag[0]) x = ((const float*)xin)[i];
        else         x = b2f(((const bf16*)xin)[i]);
    } else {
        int row = gidx[v];
        x = b2f(actin[(size_t)row * F + f]);
    }
    g[i] = __float2bfloat16(dis[v] * x);
}

// ---------------- fused stage1-post + stage2-pre ----------------------------
// g2[v] = dis2[v] * relu(xt1[up1[v]] @ W1 + b1),  v in [0, N1)
__global__ void __launch_bounds__(256, 1) k_fuse_mm_pre(
        const bf16* __restrict__ xt1, const int* __restrict__ up,
        const void* __restrict__ W, const void* __restrict__ bias,
        const float* __restrict__ dis, bf16* __restrict__ g,
        const int* __restrict__ flag, int n) {
    __shared__ float Ws[96];
    __shared__ float Bs[32];
    const int f32m = flag[0];
    if (threadIdx.x < 96)
        Ws[threadIdx.x] = f32m ? ((const float*)W)[threadIdx.x]
                               : b2f(((const bf16*)W)[threadIdx.x]);
    if (threadIdx.x < 32)
        Bs[threadIdx.x] = f32m ? ((const float*)bias)[threadIdx.x]
                               : b2f(((const bf16*)bias)[threadIdx.x]);
    __syncthreads();
    int v = blockIdx.x * 256 + threadIdx.x;
    if (v >= n) return;
    int r = up[v];
    float x0 = b2f(xt1[(size_t)r * 3 + 0]);
    float x1 = b2f(xt1[(size_t)r * 3 + 1]);
    float x2 = b2f(xt1[(size_t)r * 3 + 2]);
    float dv = dis[v];
    #pragma unroll
    for (int f8 = 0; f8 < 4; f8++) {
        us8 ov;
        #pragma unroll
        for (int j = 0; j < 8; j++) {
            int f = f8 * 8 + j;
            float y = Bs[f];
            y = fmaf(x0, Ws[f], y);
            y = fmaf(x1, Ws[32 + f], y);
            y = fmaf(x2, Ws[64 + f], y);
            y = y > 0.f ? y : 0.f;
            ov[j] = f2bfu(dv * y);
        }
        *(us8*)(g + (size_t)v * 32 + f8 * 8) = ov;
    }
}

// ---------------- fused stage2-post + stage3-matmul -------------------------
// h3[v] = relu(xt2[v] @ W2 + b2) @ W3,  v in [0, N1).  Intermediate stays f32.
__global__ void __launch_bounds__(256, 1) k_fuse_mm2(
        const bf16* __restrict__ xt2, const void* __restrict__ W2v,
        const void* __restrict__ b2v, const void* __restrict__ W3v,
        bf16* __restrict__ h, const int* __restrict__ flag, int n) {
    __shared__ float Ws2[32 * 64];   // 8 KB
    __shared__ float Ws3[64 * 32];   // 8 KB
    __shared__ float Bs[64];
    const int f32m = flag[0];
    for (int i = threadIdx.x; i < 2048; i += 256) {
        Ws2[i] = f32m ? ((const float*)W2v)[i] : b2f(((const bf16*)W2v)[i]);
        Ws3[i] = f32m ? ((const float*)W3v)[i] : b2f(((const bf16*)W3v)[i]);
    }
    if (threadIdx.x < 64)
        Bs[threadIdx.x] = f32m ? ((const float*)b2v)[threadIdx.x]
                               : b2f(((const bf16*)b2v)[threadIdx.x]);
    __syncthreads();
    int v = blockIdx.x * 256 + threadIdx.x;
    if (v >= n) return;
    float x[32];
    #pragma unroll
    for (int k8 = 0; k8 < 4; k8++) {
        us8 xv = *(const us8*)(xt2 + (size_t)v * 32 + k8 * 8);
        #pragma unroll
        for (int j = 0; j < 8; j++) x[k8 * 8 + j] = bfu2f((u32)(u16)xv[j]);
    }
    float acc[32];
    #pragma unroll
    for (int f = 0; f < 32; f++) acc[f] = 0.f;
    #pragma unroll
    for (int c = 0; c < 64; c += 32) {
        float y[32];
        #pragma unroll
        for (int f = 0; f < 32; f++) y[f] = Bs[c + f];
        #pragma unroll
        for (int k = 0; k < 32; k++) {
            float xk = x[k];
            const float* wr = &Ws2[k * 64 + c];
            #pragma unroll
            for (int f = 0; f < 32; f++) y[f] = fmaf(xk, wr[f], y[f]);
        }
        #pragma unroll
        for (int j = 0; j < 32; j++) {
            float yj = y[j] > 0.f ? y[j] : 0.f;
            const float* wr3 = &Ws3[(c + j) * 32];
            #pragma unroll
            for (int f = 0; f < 32; f++) acc[f] = fmaf(yj, wr3[f], acc[f]);
        }
    }
    #pragma unroll
    for (int f8 = 0; f8 < 4; f8++) {
        us8 ov;
        #pragma unroll
        for (int j = 0; j < 8; j++) ov[j] = f2bfu(acc[f8 * 8 + j]);
        *(us8*)(h + (size_t)v * 32 + f8 * 8) = ov;
    }
}

// ---------------- streaming matmul: h[v,:] = actin[v,:] @ W  (no gather) -----
template <int FIN, int FOUT>
__global__ void __launch_bounds__(256, 1) k_matmul_seq(
        const bf16* __restrict__ actin, const void* __restrict__ W,
        bf16* __restrict__ h, const int* __restrict__ flag, int n) {
    __shared__ float Ws[FIN * FOUT];
    const int f32m = flag[0];
    for (int i = threadIdx.x; i < FIN * FOUT; i += blockDim.x)
        Ws[i] = f32m ? ((const float*)W)[i] : b2f(((const bf16*)W)[i]);
    __syncthreads();
    int v = blockIdx.x * blockDim.x + threadIdx.x;
    if (v >= n) return;
    float y[FOUT];
    #pragma unroll
    for (int f = 0; f < FOUT; f++) y[f] = 0.f;
    #pragma unroll
    for (int k8 = 0; k8 < FIN / 8; k8++) {
        us8 xv = *(const us8*)(actin + (size_t)v * FIN + k8 * 8);
        #pragma unroll
        for (int j = 0; j < 8; j++) {
            float xk = bfu2f((u32)(u16)xv[j]);
            const float* wrow = &Ws[(k8 * 8 + j) * FOUT];
            #pragma unroll
            for (int f = 0; f < FOUT; f++) y[f] = fmaf(xk, wrow[f], y[f]);
        }
    }
    if constexpr (FOUT % 8 == 0) {
        #pragma unroll
        for (int f8 = 0; f8 < FOUT / 8; f8++) {
            us8 ov;
            #pragma unroll
            for (int j = 0; j < 8; j++) ov[j] = f2bfu(y[f8 * 8 + j]);
            *(us8*)(h + (size_t)v * FOUT + f8 * 8) = ov;
        }
    } else {
        #pragma unroll
        for (int f = 0; f < FOUT; f++)
            h[(size_t)v * FOUT + f] = __float2bfloat16(y[f]);
    }
}

// ---------------- CSR gather, QUAD-FEATURE x DUAL-ROW (FOUT%4==0) ----------
// u32 offsets throughout (all arrays < 4 GB): W2=16 -> shifts, no 64-bit mul.
template <int FOUT, bool FINALIZE>
__global__ void __launch_bounds__(256) k_gather2v(
        const bf16* __restrict__ g, const int* __restrict__ rowptr,
        const int* __restrict__ csr, const float* __restrict__ dis,
        const void* __restrict__ bias, bf16* __restrict__ out,
        const int* __restrict__ flag, int totq, int E) {
    constexpr int Q = FOUT / 4;         // quads per row
    constexpr u32 W2 = FOUT / 2;        // u32 words per row
    int H = (totq + 1) >> 1;
    int i = blockIdx.x * blockDim.x + threadIdx.x;
    if (i >= H) return;
    int Em1 = E - 1;
    int e1 = i;
    int e2 = i + H;
    int e2c = (e2 < totq) ? e2 : e1;
    int v1 = e1 / Q, q1 = e1 - v1 * Q;
    int v2 = e2c / Q, q2 = e2c - v2 * Q;
    u32 qo1 = (u32)(q1 * 2), qo2 = (u32)(q2 * 2);
    const u32* g32 = (const u32*)g;

    uint2 sv1 = *(const uint2*)(g32 + (u32)v1 * W2 + qo1);
    uint2 sv2 = *(const uint2*)(g32 + (u32)v2 * W2 + qo2);
    float s10 = bfu2f(sv1.x & 0xFFFFu), s11 = bfu2f(sv1.x >> 16);
    float s12 = bfu2f(sv1.y & 0xFFFFu), s13 = bfu2f(sv1.y >> 16);
    float s20 = bfu2f(sv2.x & 0xFFFFu), s21 = bfu2f(sv2.x >> 16);
    float s22 = bfu2f(sv2.y & 0xFFFFu), s23 = bfu2f(sv2.y >> 16);

    int r1 = rowptr[v1]; int c1 = rowptr[v1 + 1] - r1;
    int r2 = rowptr[v2]; int c2 = rowptr[v2 + 1] - r2;
    int last1 = min(r1 + (c1 > 0 ? c1 - 1 : 0), Em1);
    int last2 = min(r2 + (c2 > 0 ? c2 - 1 : 0), Em1);
    int j1 = 0, j2 = 0;
    while (j1 < c1 || j2 < c2) {
        int i10 = min(r1 + j1 + 0, last1), i11 = min(r1 + j1 + 1, last1);
        int i12 = min(r1 + j1 + 2, last1), i13 = min(r1 + j1 + 3, last1);
        int i20 = min(r2 + j2 + 0, last2), i21 = min(r2 + j2 + 1, last2);
        int i22 = min(r2 + j2 + 2, last2), i23 = min(r2 + j2 + 3, last2);
        u32 u10 = (u32)csr[i10], u11 = (u32)csr[i11];
        u32 u12 = (u32)csr[i12], u13 = (u32)csr[i13];
        u32 u20 = (u32)csr[i20], u21 = (u32)csr[i21];
        u32 u22 = (u32)csr[i22], u23 = (u32)csr[i23];
        uint2 a10 = *(const uint2*)(g32 + u10 * W2 + qo1);
        uint2 a11 = *(const uint2*)(g32 + u11 * W2 + qo1);
        uint2 a12 = *(const uint2*)(g32 + u12 * W2 + qo1);
        uint2 a13 = *(const uint2*)(g32 + u13 * W2 + qo1);
        uint2 a20 = *(const uint2*)(g32 + u20 * W2 + qo2);
        uint2 a21 = *(const uint2*)(g32 + u21 * W2 + qo2);
        uint2 a22 = *(const uint2*)(g32 + u22 * W2 + qo2);
        uint2 a23 = *(const uint2*)(g32 + u23 * W2 + qo2);
        // zero masked edges on the raw words (bf16 0x0000 == 0.0f)
        if (j1 + 0 >= c1) { a10.x = 0; a10.y = 0; }
        if (j1 + 1 >= c1) { a11.x = 0; a11.y = 0; }
        if (j1 + 2 >= c1) { a12.x = 0; a12.y = 0; }
        if (j1 + 3 >= c1) { a13.x = 0; a13.y = 0; }
        if (j2 + 0 >= c2) { a20.x = 0; a20.y = 0; }
        if (j2 + 1 >= c2) { a21.x = 0; a21.y = 0; }
        if (j2 + 2 >= c2) { a22.x = 0; a22.y = 0; }
        if (j2 + 3 >= c2) { a23.x = 0; a23.y = 0; }
        s10 += bfu2f(a10.x & 0xFFFFu) + bfu2f(a11.x & 0xFFFFu)
             + bfu2f(a12.x & 0xFFFFu) + bfu2f(a13.x & 0xFFFFu);
        s11 += bfu2f(a10.x >> 16) + bfu2f(a11.x >> 16)
             + bfu2f(a12.x >> 16) + bfu2f(a13.x >> 16);
        s12 += bfu2f(a10.y & 0xFFFFu) + bfu2f(a11.y & 0xFFFFu)
             + bfu2f(a12.y & 0xFFFFu) + bfu2f(a13.y & 0xFFFFu);
        s13 += bfu2f(a10.y >> 16) + bfu2f(a11.y >> 16)
             + bfu2f(a12.y >> 16) + bfu2f(a13.y >> 16);
        s20 += bfu2f(a20.x & 0xFFFFu) + bfu2f(a21.x & 0xFFFFu)
             + bfu2f(a22.x & 0xFFFFu) + bfu2f(a23.x & 0xFFFFu);
        s21 += bfu2f(a20.x >> 16) + bfu2f(a21.x >> 16)
             + bfu2f(a22.x >> 16) + bfu2f(a23.x >> 16);
        s22 += bfu2f(a20.y & 0xFFFFu) + bfu2f(a21.y & 0xFFFFu)
             + bfu2f(a22.y & 0xFFFFu) + bfu2f(a23.y & 0xFFFFu);
        s23 += bfu2f(a20.y >> 16) + bfu2f(a21.y >> 16)
             + bfu2f(a22.y >> 16) + bfu2f(a23.y >> 16);
        j1 += 4; j2 += 4;
    }
    float dv1 = dis[v1], dv2 = dis[v2];
    float o1[4] = {s10, s11, s12, s13};
    float o2[4] = {s20, s21, s22, s23};
    uint2 w1, w2;
    if (FINALIZE) {
        int f32m = flag[0];
        #pragma unroll
        for (int k = 0; k < 4; k++) {
            int f1 = q1 * 4 + k, f2 = q2 * 4 + k;
            float bf1 = f32m ? ((const float*)bias)[f1] : b2f(((const bf16*)bias)[f1]);
            float bf2 = f32m ? ((const float*)bias)[f2] : b2f(((const bf16*)bias)[f2]);
            o1[k] = fmaf(dv1, o1[k], bf1); o1[k] = o1[k] > 0.f ? o1[k] : 0.f;
            o2[k] = fmaf(dv2, o2[k], bf2); o2[k] = o2[k] > 0.f ? o2[k] : 0.f;
        }
    } else {
        #pragma unroll
        for (int k = 0; k < 4; k++) { o1[k] *= dv1; o2[k] *= dv2; }
    }
    w1.x = (u32)f2bfu(o1[0]) | ((u32)f2bfu(o1[1]) << 16);
    w1.y = (u32)f2bfu(o1[2]) | ((u32)f2bfu(o1[3]) << 16);
    w2.x = (u32)f2bfu(o2[0]) | ((u32)f2bfu(o2[1]) << 16);
    w2.y = (u32)f2bfu(o2[2]) | ((u32)f2bfu(o2[3]) << 16);
    u32* o32 = (u32*)out;
    *(uint2*)(o32 + (u32)v1 * W2 + qo1) = w1;
    if (e2 < totq) *(uint2*)(o32 + (u32)v2 * W2 + qo2) = w2;
}

// ---------------- CSR gather, DUAL-ROW per thread (FOUT=3 path) -------------
template <int FOUT, bool FINALIZE>
__global__ void __launch_bounds__(256) k_gather2(
        const bf16* __restrict__ g, const int* __restrict__ rowptr,
        const int* __restrict__ csr, const float* __restrict__ dis,
        const void* __restrict__ bias, bf16* __restrict__ out,
        const int* __restrict__ flag, int total, int E) {
    int H = (total + 1) >> 1;
    int i = blockIdx.x * blockDim.x + threadIdx.x;
    if (i >= H) return;
    int Em1 = E - 1;
    int e1 = i;
    int e2 = i + H;
    int e2c = (e2 < total) ? e2 : e1;
    int v1 = e1 / FOUT, f1 = e1 - v1 * FOUT;
    int v2 = e2c / FOUT, f2 = e2c - v2 * FOUT;
    float s1 = b2f(g[e1]);    // self-loop terms
    float s2 = b2f(g[e2c]);
    int r1 = rowptr[v1]; int c1 = rowptr[v1 + 1] - r1;
    int r2 = rowptr[v2]; int c2 = rowptr[v2 + 1] - r2;
    int last1 = min(r1 + (c1 > 0 ? c1 - 1 : 0), Em1);
    int last2 = min(r2 + (c2 > 0 ? c2 - 1 : 0), Em1);
    int j1 = 0, j2 = 0;
    while (j1 < c1 || j2 < c2) {
        int i10 = min(r1 + j1 + 0, last1), i11 = min(r1 + j1 + 1, last1);
        int i12 = min(r1 + j1 + 2, last1), i13 = min(r1 + j1 + 3, last1);
        int i20 = min(r2 + j2 + 0, last2), i21 = min(r2 + j2 + 1, last2);
        int i22 = min(r2 + j2 + 2, last2), i23 = min(r2 + j2 + 3, last2);
        int u10 = csr[i10], u11 = csr[i11], u12 = csr[i12], u13 = csr[i13];
        int u20 = csr[i20], u21 = csr[i21], u22 = csr[i22], u23 = csr[i23];
        float a10 = b2f(g[(size_t)u10 * FOUT + f1]);
        float a11 = b2f(g[(size_t)u11 * FOUT + f1]);
        float a12 = b2f(g[(size_t)u12 * FOUT + f1]);
        float a13 = b2f(g[(size_t)u13 * FOUT + f1]);
        float a20 = b2f(g[(size_t)u20 * FOUT + f2]);
        float a21 = b2f(g[(size_t)u21 * FOUT + f2]);
        float a22 = b2f(g[(size_t)u22 * FOUT + f2]);
        float a23 = b2f(g[(size_t)u23 * FOUT + f2]);
        s1 += ((j1 + 0 < c1 ? a10 : 0.f) + (j1 + 1 < c1 ? a11 : 0.f))
            + ((j1 + 2 < c1 ? a12 : 0.f) + (j1 + 3 < c1 ? a13 : 0.f));
        s2 += ((j2 + 0 < c2 ? a20 : 0.f) + (j2 + 1 < c2 ? a21 : 0.f))
            + ((j2 + 2 < c2 ? a22 : 0.f) + (j2 + 3 < c2 ? a23 : 0.f));
        j1 += 4; j2 += 4;
    }
    float dv1 = dis[v1], dv2 = dis[v2];
    float o1, o2;
    if (FINALIZE) {
        float bf1 = flag[0] ? ((const float*)bias)[f1] : b2f(((const bf16*)bias)[f1]);
        float bf2 = flag[0] ? ((const float*)bias)[f2] : b2f(((const bf16*)bias)[f2]);
        o1 = fmaf(dv1, s1, bf1); o1 = o1 > 0.f ? o1 : 0.f;
        o2 = fmaf(dv2, s2, bf2); o2 = o2 > 0.f ? o2 : 0.f;
    } else {
        o1 = dv1 * s1;
        o2 = dv2 * s2;
    }
    out[e1] = __float2bfloat16(o1);
    if (e2 < total) out[e2] = __float2bfloat16(o2);
}

// ---------------- final unpool gather -> out (dtype per flag) ----------------
__global__ void k_gather_out(const bf16* __restrict__ act, const int* __restrict__ idx,
                             void* __restrict__ out, const int* __restrict__ flag, int n) {
    int u = blockIdx.x * blockDim.x + threadIdx.x;
    if (u >= n) return;
    size_t r = (size_t)idx[u];
    float v0 = b2f(act[3 * r + 0]);
    float v1 = b2f(act[3 * r + 1]);
    float v2 = b2f(act[3 * r + 2]);
    if (flag[0]) {
        float* o = (float*)out;
        o[3 * (size_t)u + 0] = v0; o[3 * (size_t)u + 1] = v1; o[3 * (size_t)u + 2] = v2;
    } else {
        bf16* o = (bf16*)out;
        o[3 * (size_t)u + 0] = __float2bfloat16(v0);
        o[3 * (size_t)u + 1] = __float2bfloat16(v1);
        o[3 * (size_t)u + 2] = __float2bfloat16(v2);
    }
}

static inline int cdiv(long long a, long long b) { return (int)((a + b - 1) / b); }

extern "C" void kernel_launch(void* const* d_in, const int* in_sizes, int n_in,
                              void* d_out, int out_size, void* d_ws, size_t ws_size,
                              hipStream_t stream) {
    const void* x  = d_in[0];
    const void* W1 = d_in[1]; const void* b1 = d_in[2];
    const void* W2 = d_in[3]; const void* b2 = d_in[4];
    const void* W3 = d_in[5]; const void* b3 = d_in[6];
    const void* W4 = d_in[7]; const void* b4 = d_in[8];
    const int* e0  = (const int*)d_in[9];
    const int* up1 = (const int*)d_in[10];
    const int* e1  = (const int*)d_in[11];
    const int* up2 = (const int*)d_in[12];
    const int* e2  = (const int*)d_in[13];
    const int* up3 = (const int*)d_in[14];
    const int* e3  = (const int*)d_in[15];
    const int* up4 = (const int*)d_in[16];

    const int N0 = in_sizes[0] / 3;
    const int N1 = in_sizes[10];
    const int N2 = in_sizes[12];
    const int N3 = in_sizes[14];
    const int N4 = in_sizes[16];
    const int E0 = in_sizes[9] / 2, E1 = in_sizes[11] / 2;
    const int E2 = in_sizes[13] / 2, E3 = in_sizes[15] / 2;

    int Ns[4] = {N0, N1, N2, N3};
    int Es[4] = {E0, E1, E2, E3};
    const int* srcs[4] = {e0, e1, e2, e3};
    const int* dsts[4] = {e0 + E0, e1 + E1, e2 + E2, e3 + E3};

    // buffer element counts
    size_t gmax = (size_t)N0 * 3;
    if ((size_t)N1 * 32 > gmax) gmax = (size_t)N1 * 32;
    if ((size_t)N2 * 32 > gmax) gmax = (size_t)N2 * 32;
    if ((size_t)N3 * 3  > gmax) gmax = (size_t)N3 * 3;
    size_t amax = (size_t)N0 * 32;
    if ((size_t)N1 * 64 > amax) amax = (size_t)N1 * 64;
    if ((size_t)N2 * 32 > amax) amax = (size_t)N2 * 32;
    if ((size_t)N3 * 3  > amax) amax = (size_t)N3 * 3;
    gmax = (gmax + 7) & ~(size_t)7;
    amax = (amax + 7) & ~(size_t)7;

    Pack pk;
    char* p = (char*)d_ws;
    int* flag = (int*)p;            p += 256;
    int* gcur_all = (int*)p;        p += 1024 * 4;
    int* bbase_all = (int*)p;       p += 1024 * 4;

    for (int s = 0; s < 4; s++) {
        pk.s[s].src = srcs[s]; pk.s[s].dst = dsts[s];
        pk.s[s].E = Es[s]; pk.s[s].N = Ns[s];
        int nb = cdiv(Ns[s], CRANGE);
        pk.s[s].nb = nb;
        pk.s[s].nblk = cdiv(Es[s], TILE);
        pk.s[s].nbpad = (nb + 15) & ~15;
        pk.s[s].cap = (Es[s] / nb + Es[s] / (8 * nb) + 256 + 3) & ~3;  // % 4 == 0
        pk.s[s].gcur = gcur_all + s * 256;
        pk.s[s].M = (int*)p;        p += (size_t)pk.s[s].nblk * pk.s[s].nbpad * 4;
        pk.s[s].rowptr = (int*)p;   p += ((size_t)(Ns[s] + 1 + 3) & ~(size_t)3) * 4;
        pk.s[s].dis = (float*)p;    p += ((size_t)(Ns[s] + 3) & ~(size_t)3) * 4;
    }
    for (int s = 0; s < 4; s++) {
        pk.s[s].csr = (int*)p;      p += ((size_t)(Es[s] + 3) & ~(size_t)3) * 4;
    }

    // union region (16B aligned): pairs (build) aliases g|act|xt (compute)
    char* U = (char*)(((size_t)p + 15) & ~(size_t)15);
    size_t pairsBytes = 0;
    for (int s = 0; s < 4; s++) {
        pk.s[s].pairs = (u32*)(U + pairsBytes);
        pairsBytes += (size_t)pk.s[s].cap * pk.s[s].nb * 4;
    }
    bf16* g   = (bf16*)U;
    bf16* act = g + gmax;
    bf16* xt  = act + amax;

    // grids
    int ptot = 0, btot = 0;
    for (int s = 0; s < 4; s++) {
        pk.poff[s] = ptot; ptot += pk.s[s].nblk;
        pk.boff[s] = btot; btot += pk.s[s].nb;
    }

    const int B = 256;

    k_detect<<<1, 256, 0, stream>>>((const u16*)x, flag);
    k_init<<<4, 256, 0, stream>>>(gcur_all, pk);
    k_part_hist<<<ptot, B, 0, stream>>>(pk);
    k_part_scan<<<btot, B, 0, stream>>>(pk);
    k_partition<<<ptot, B, 0, stream>>>(pk);
    k_scan_bbase<<<4, B, 0, stream>>>(pk, bbase_all);
    k_build<<<btot, 512, 0, stream>>>(pk, bbase_all);

    // ---- stage 1 (agg-first): aggregate x (3 feats) -> xt1
    {
        int T = N0 * 3, Hh = (T + 1) >> 1;
        k_pre<3, true><<<cdiv(T, B), B, 0, stream>>>(
            x, nullptr, nullptr, pk.s[0].dis, g, flag, T);
        k_gather2<3, false><<<cdiv(Hh, B), B, 0, stream>>>(
            g, pk.s[0].rowptr, pk.s[0].csr, pk.s[0].dis, nullptr, xt, flag, T, E0);
    }

    // ---- fused stage1-post + stage2-pre: g2 = dis2 * relu(xt1[up1]@W1+b1)
    k_fuse_mm_pre<<<cdiv(N1, B), B, 0, stream>>>(
        xt, up1, W1, b1, pk.s[1].dis, g, flag, N1);

    // ---- stage 2 aggregate -> xt2
    {
        int Tq = N1 * 8, Hq = (Tq + 1) >> 1;
        k_gather2v<32, false><<<cdiv(Hq, B), B, 0, stream>>>(
            g, pk.s[1].rowptr, pk.s[1].csr, pk.s[1].dis, nullptr, xt, flag, Tq, E1);
    }

    // ---- fused stage2-post + stage3-matmul: h3 = relu(xt2@W2+b2)@W3 -> act
    k_fuse_mm2<<<cdiv(N1, B), B, 0, stream>>>(xt, W2, b2, W3, act, flag, N1);

    // ---- stage 3: g3 = dis3 * h3[up2], then quad-vector aggregate -> act3
    {
        int Tq = N2 * 8, Hq = (Tq + 1) >> 1;
        k_pre<32, false><<<cdiv((long long)N2 * 32, B), B, 0, stream>>>(
            nullptr, up2, act, pk.s[2].dis, g, flag, N2 * 32);
        k_gather2v<32, true><<<cdiv(Hq, B), B, 0, stream>>>(
            g, pk.s[2].rowptr, pk.s[2].csr, pk.s[2].dis, b3, act, flag, Tq, E2);
    }

    // ---- stage 4 (W-first): h4 = act3@W4 at N2, g4 = dis4*h4[up3], aggregate
    {
        int T = N3 * 3, Hh = (T + 1) >> 1;
        k_matmul_seq<32, 3><<<cdiv(N2, B), B, 0, stream>>>(act, W4, xt, flag, N2);
        k_pre<3, false><<<cdiv(T, B), B, 0, stream>>>(
            nullptr, up3, xt, pk.s[3].dis, g, flag, T);
        k_gather2<3, true><<<cdiv(Hh, B), B, 0, stream>>>(
            g, pk.s[3].rowptr, pk.s[3].csr, pk.s[3].dis, b4, act, flag, T, E3);
    }

    // ---- final unpool
    k_gather_out<<<cdiv(N4, B), B, 0, stream>>>(act, up4, d_out, flag, N4);
}

// Round 11
// 476.049 us; speedup vs baseline: 1.0571x; 1.0497x over previous
//
#include <hip/hip_runtime.h>
#include <hip/hip_bf16.h>

typedef __hip_bfloat16 bf16;
typedef unsigned short u16;
typedef unsigned char u8;
typedef unsigned int u32;
typedef __attribute__((ext_vector_type(8))) unsigned short us8;

static __device__ __forceinline__ float b2f(bf16 v) { return __bfloat162float(v); }
static __device__ __forceinline__ float bfu2f(u32 u) {
    union { u32 i; float f; } c; c.i = u << 16; return c.f;
}
static __device__ __forceinline__ u16 f2bfu(float f) {
    u32 x = __float_as_uint(f);
    return (u16)((x + 0x7FFFu + ((x >> 16) & 1u)) >> 16);
}

#define TILE 4096        // edges per partition block
#define CBITS 12         // coarse bucket = 4096-vertex range (all stages)
#define CRANGE 4096
#define OUTB 26624       // build staging capacity (tot ~24.5K + >8 sigma); 104 KB
#define RPT16(M) M(0) M(1) M(2) M(3) M(4) M(5) M(6) M(7) \
                 M(8) M(9) M(10) M(11) M(12) M(13) M(14) M(15)

struct SP {
    const int* src; const int* dst;
    int E, N, cap, nb, nblk, nbpad;
    int* gcur;      // [nb] per-bucket totals (written by k_part_scan)
    u32* pairs;     // [nb][cap] packed (local_dst12 << 20) | src20
    int* M;         // [nblk][nbpad] counts -> exclusive bases
    int* rowptr; float* dis; int* csr;
};
struct Pack {
    SP s[4];
    int poff[4];  // tile-grid start offset per stage
    int boff[4];  // bucket-grid start offset per stage
};

// ---------------- dtype detection ----------------
__global__ void k_detect(const u16* __restrict__ xraw, int* __restrict__ flag) {
    __shared__ int s;
    if (threadIdx.x == 0) s = 0;
    __syncthreads();
    u16 u = xraw[threadIdx.x];
    int e = (u >> 7) & 0xFF;
    if (e >= 0x8F) atomicAdd(&s, 1);
    __syncthreads();
    if (threadIdx.x == 0) flag[0] = (s > 0) ? 1 : 0;
}

// zero gcur (4 x 256) + rowptr sentinels
__global__ void k_init(int* __restrict__ gcur_all, Pack pk) {
    int i = blockIdx.x * blockDim.x + threadIdx.x;
    if (i < 1024) gcur_all[i] = 0;
    if (i < 4) pk.s[i].rowptr[pk.s[i].N] = pk.s[i].E;
}

// ---------------- pass A0: per-tile bucket counts -> M[tile][bucket] ----------
__global__ void __launch_bounds__(256) k_part_hist(Pack pk) {
    __shared__ int hist[256];
    int bid = blockIdx.x;
    int si = (bid >= pk.poff[3]) ? 3 : (bid >= pk.poff[2]) ? 2 : (bid >= pk.poff[1]) ? 1 : 0;
    const SP sp = pk.s[si];
    int lb = bid - pk.poff[si];
    int t = threadIdx.x;
    int n = min(TILE, sp.E - lb * TILE);
    const int* dstp = sp.dst + lb * TILE;

#define LOADK(k) int d##k; { int i = t + 256*(k); d##k = (i < n) ? dstp[i] : -1; }
    RPT16(LOADK)
#undef LOADK
    hist[t] = 0;
    __syncthreads();
#define HISTK(k) if (d##k >= 0) atomicAdd(&hist[d##k >> CBITS], 1);
    RPT16(HISTK)
#undef HISTK
    __syncthreads();
    int* Mrow = sp.M + (size_t)lb * sp.nbpad;
    for (int b = t; b < sp.nb; b += 256) Mrow[b] = hist[b];
}

// ---------------- pass A-scan: per-bucket column scan of M (in place) --------
__global__ void __launch_bounds__(256) k_part_scan(Pack pk) {
    __shared__ int buf[256];
    int bid = blockIdx.x;
    int si = (bid >= pk.boff[3]) ? 3 : (bid >= pk.boff[2]) ? 2 : (bid >= pk.boff[1]) ? 1 : 0;
    const SP sp = pk.s[si];
    int b = bid - pk.boff[si];
    int t = threadIdx.x;
    int nblk = sp.nblk, nbpad = sp.nbpad;
    int* M = sp.M;
    int carry = 0;
    for (int base = 0; base < nblk; base += 256) {
        int m = min(256, nblk - base);
        int v = (t < m) ? M[(size_t)(base + t) * nbpad + b] : 0;
        buf[t] = v;
        __syncthreads();
        for (int off = 1; off < 256; off <<= 1) {
            int w = (t >= off) ? buf[t - off] : 0;
            __syncthreads();
            buf[t] += w;
            __syncthreads();
        }
        int excl = buf[t] - v + carry;
        int ctot = buf[255];
        __syncthreads();
        if (t < m) M[(size_t)(base + t) * nbpad + b] = excl;
        carry += ctot;
    }
    if (t == 0) sp.gcur[b] = carry;
}

// ---------------- pass A1: scatter to pairs at deterministic bases -----------
__global__ void __launch_bounds__(256) k_partition(Pack pk) {
    __shared__ u32 stage[TILE];   // 16 KB
    __shared__ u8  bkt[TILE];     //  4 KB
    __shared__ int hist[256];
    __shared__ int gofs[256];
    __shared__ int tmp[256];

    int bid = blockIdx.x;
    int si = (bid >= pk.poff[3]) ? 3 : (bid >= pk.poff[2]) ? 2 : (bid >= pk.poff[1]) ? 1 : 0;
    const SP sp = pk.s[si];
    int lb = bid - pk.poff[si];
    int t = threadIdx.x;
    int n = min(TILE, sp.E - lb * TILE);
    const int* dstp = sp.dst + lb * TILE;
    const int* srcp = sp.src + lb * TILE;

#define LOADK(k) int d##k, s##k; { int i = t + 256*(k); \
    if (i < n) { d##k = dstp[i]; s##k = srcp[i]; } else { d##k = -1; s##k = 0; } }
    RPT16(LOADK)
#undef LOADK

    hist[t] = 0;
    __syncthreads();
#define HISTK(k) if (d##k >= 0) atomicAdd(&hist[d##k >> CBITS], 1);
    RPT16(HISTK)
#undef HISTK
    __syncthreads();

    int h = hist[t];
    tmp[t] = h; __syncthreads();
    for (int off = 1; off < 256; off <<= 1) {
        int v = (t >= off) ? tmp[t - off] : 0;
        __syncthreads();
        tmp[t] += v;
        __syncthreads();
    }
    int lofs = tmp[t] - h;
    int gb = (t < sp.nb) ? sp.M[(size_t)lb * sp.nbpad + t] : 0;  // scanned base
    gofs[t] = gb - lofs;
    hist[t] = lofs;   // scatter cursor
    __syncthreads();

#define SCATK(k) if (d##k >= 0) { int b = d##k >> CBITS; \
    int pos = atomicAdd(&hist[b], 1); \
    stage[pos] = (((u32)d##k & 4095u) << 20) | (u32)s##k; \
    bkt[pos] = (u8)b; }
    RPT16(SCATK)
#undef SCATK
    __syncthreads();

    int cap = sp.cap;
    u32* pairs = sp.pairs;
    for (int i = t; i < n; i += 256) {
        int b = bkt[i];
        pairs[(size_t)b * cap + gofs[b] + i] = stage[i];
    }
}

// ---------------- bucket-base scan (one block per stage) ----------------
__global__ void k_scan_bbase(Pack pk, int* __restrict__ bbase_all) {
    __shared__ int tmp[256];
    int si = blockIdx.x;
    int t = threadIdx.x;
    int nb = pk.s[si].nb;
    int v = (t < nb) ? pk.s[si].gcur[t] : 0;
    tmp[t] = v; __syncthreads();
    for (int off = 1; off < 256; off <<= 1) {
        int w = (t >= off) ? tmp[t - off] : 0;
        __syncthreads();
        tmp[t] += w;
        __syncthreads();
    }
    bbase_all[si * 256 + t] = tmp[t] - v;
}

// ---------------- build: one block per coarse bucket, 3 passes --------------
__global__ void __launch_bounds__(512) k_build(Pack pk, const int* __restrict__ bbase_all) {
    __shared__ int hist[4096];    //  16 KB: counts -> local offsets -> cursor
    __shared__ int outb[OUTB];    // 104 KB staged csr for the whole bucket
    __shared__ int tmp[512];

    int bid = blockIdx.x;
    int si = (bid >= pk.boff[3]) ? 3 : (bid >= pk.boff[2]) ? 2 : (bid >= pk.boff[1]) ? 1 : 0;
    const SP sp = pk.s[si];
    int b = bid - pk.boff[si];
    int t = threadIdx.x;

    int bbase = bbase_all[si * 256 + b];
    int tot = sp.gcur[b];
    const u32* p = sp.pairs + (size_t)b * sp.cap;   // 16B aligned (cap % 4 == 0)
    const uint4* p4 = (const uint4*)p;
    int tot4 = tot >> 2;

    for (int i = t; i < 4096; i += 512) hist[i] = 0;
    __syncthreads();
    for (int i = t; i < tot4; i += 512) {
        uint4 u = p4[i];
        atomicAdd(&hist[u.x >> 20], 1);
        atomicAdd(&hist[u.y >> 20], 1);
        atomicAdd(&hist[u.z >> 20], 1);
        atomicAdd(&hist[u.w >> 20], 1);
    }
    for (int i = (tot4 << 2) + t; i < tot; i += 512)
        atomicAdd(&hist[p[i] >> 20], 1);
    __syncthreads();

    // in-place exclusive scan of 4096 bins; counts in registers (8/thread)
    int lbase = t * 8;
    int cnt[8], cof[8];
    #pragma unroll
    for (int k = 0; k < 8; k++) cnt[k] = hist[lbase + k];
    int s = 0;
    #pragma unroll
    for (int k = 0; k < 8; k++) { cof[k] = s; s += cnt[k]; }
    tmp[t] = s; __syncthreads();
    for (int off = 1; off < 512; off <<= 1) {
        int v = (t >= off) ? tmp[t - off] : 0;
        __syncthreads();
        tmp[t] += v;
        __syncthreads();
    }
    int tb = tmp[t] - s;

    int nbase = b << CBITS;
    #pragma unroll
    for (int k = 0; k < 8; k++) {
        int bin = lbase + k;
        hist[bin] = tb + cof[k];          // bucket-local offset (-> cursor)
        int v = nbase + bin;
        if (v < sp.N) {
            sp.rowptr[v] = bbase + tb + cof[k];
            sp.dis[v] = rsqrtf((float)(cnt[k] + 1));
        }
    }
    __syncthreads();

    if (tot <= OUTB) {
        for (int i = t; i < tot4; i += 512) {
            uint4 u = p4[i];
            int pos;
            pos = atomicAdd(&hist[u.x >> 20], 1); outb[pos] = (int)(u.x & 0xFFFFFu);
            pos = atomicAdd(&hist[u.y >> 20], 1); outb[pos] = (int)(u.y & 0xFFFFFu);
            pos = atomicAdd(&hist[u.z >> 20], 1); outb[pos] = (int)(u.z & 0xFFFFFu);
            pos = atomicAdd(&hist[u.w >> 20], 1); outb[pos] = (int)(u.w & 0xFFFFFu);
        }
        for (int i = (tot4 << 2) + t; i < tot; i += 512) {
            u32 u = p[i];
            int pos = atomicAdd(&hist[u >> 20], 1);
            outb[pos] = (int)(u & 0xFFFFFu);
        }
        __syncthreads();
        for (int i = t; i < tot; i += 512)
            sp.csr[bbase + i] = outb[i];
    } else {  // statistical overflow fallback: direct global scatter
        for (int i = t; i < tot; i += 512) {
            u32 u = p[i];
            int pos = atomicAdd(&hist[u >> 20], 1);
            sp.csr[bbase + pos] = (int)(u & 0xFFFFFu);
        }
    }
}

// ---------------- pre-scale: g[v,f] = dis[v] * x_in[row(v), f] ----------------
template <int F, bool EXT>
__global__ void k_pre(const void* __restrict__ xin, const int* __restrict__ gidx,
                      const bf16* __restrict__ actin, const float* __restrict__ dis,
                      bf16* __restrict__ g, const int* __restrict__ flag, int total) {
    int i = blockIdx.x * blockDim.x + threadIdx.x;
    if (i >= total) return;
    int v = i / F;
    int f = i - v * F;
    float x;
    if (EXT) {
        if (flag[0]) x = ((const float*)xin)[i];
        else         x = b2f(((const bf16*)xin)[i]);
    } else {
        int row = gidx[v];
        x = b2f(actin[(size_t)row * F + f]);
    }
    g[i] = __float2bfloat16(dis[v] * x);
}

// ---------------- fused stage1-post + stage2-pre ----------------------------
// g2[v] = dis2[v] * relu(xt1[up1[v]] @ W1 + b1),  v in [0, N1)
__global__ void __launch_bounds__(256, 1) k_fuse_mm_pre(
        const bf16* __restrict__ xt1, const int* __restrict__ up,
        const void* __restrict__ W, const void* __restrict__ bias,
        const float* __restrict__ dis, bf16* __restrict__ g,
        const int* __restrict__ flag, int n) {
    __shared__ float Ws[96];
    __shared__ float Bs[32];
    const int f32m = flag[0];
    if (threadIdx.x < 96)
        Ws[threadIdx.x] = f32m ? ((const float*)W)[threadIdx.x]
                               : b2f(((const bf16*)W)[threadIdx.x]);
    if (threadIdx.x < 32)
        Bs[threadIdx.x] = f32m ? ((const float*)bias)[threadIdx.x]
                               : b2f(((const bf16*)bias)[threadIdx.x]);
    __syncthreads();
    int v = blockIdx.x * 256 + threadIdx.x;
    if (v >= n) return;
    int r = up[v];
    float x0 = b2f(xt1[(size_t)r * 3 + 0]);
    float x1 = b2f(xt1[(size_t)r * 3 + 1]);
    float x2 = b2f(xt1[(size_t)r * 3 + 2]);
    float dv = dis[v];
    #pragma unroll
    for (int f8 = 0; f8 < 4; f8++) {
        us8 ov;
        #pragma unroll
        for (int j = 0; j < 8; j++) {
            int f = f8 * 8 + j;
            float y = Bs[f];
            y = fmaf(x0, Ws[f], y);
            y = fmaf(x1, Ws[32 + f], y);
            y = fmaf(x2, Ws[64 + f], y);
            y = y > 0.f ? y : 0.f;
            ov[j] = f2bfu(dv * y);
        }
        *(us8*)(g + (size_t)v * 32 + f8 * 8) = ov;
    }
}

// ---------------- fused stage2-post + stage3-matmul -------------------------
// h3[v] = relu(xt2[v] @ W2 + b2) @ W3,  v in [0, N1).
// x lives in a per-thread LDS row (stride 33 -> conflict-free), so peak VGPR
// live-set is y[32]+acc[32] only -> no scratch spill (the R10 78us culprit).
__global__ void __launch_bounds__(256, 1) k_fuse_mm2(
        const bf16* __restrict__ xt2, const void* __restrict__ W2v,
        const void* __restrict__ b2v, const void* __restrict__ W3v,
        bf16* __restrict__ h, const int* __restrict__ flag, int n) {
    __shared__ float Ws2[32 * 64];   //  8 KB
    __shared__ float Ws3[64 * 32];   //  8 KB
    __shared__ float Bs[64];
    __shared__ float Xs[256 * 33];   // 33 KB per-thread x rows, pad 33
    const int f32m = flag[0];
    for (int i = threadIdx.x; i < 2048; i += 256) {
        Ws2[i] = f32m ? ((const float*)W2v)[i] : b2f(((const bf16*)W2v)[i]);
        Ws3[i] = f32m ? ((const float*)W3v)[i] : b2f(((const bf16*)W3v)[i]);
    }
    if (threadIdx.x < 64)
        Bs[threadIdx.x] = f32m ? ((const float*)b2v)[threadIdx.x]
                               : b2f(((const bf16*)b2v)[threadIdx.x]);
    __syncthreads();
    int v = blockIdx.x * 256 + threadIdx.x;
    if (v >= n) return;
    float* xs = &Xs[threadIdx.x * 33];   // private row, no barrier needed
    #pragma unroll
    for (int k8 = 0; k8 < 4; k8++) {
        us8 xv = *(const us8*)(xt2 + (size_t)v * 32 + k8 * 8);
        #pragma unroll
        for (int j = 0; j < 8; j++) xs[k8 * 8 + j] = bfu2f((u32)(u16)xv[j]);
    }
    float acc[32];
    #pragma unroll
    for (int f = 0; f < 32; f++) acc[f] = 0.f;
    #pragma unroll
    for (int c = 0; c < 64; c += 32) {
        float y[32];
        #pragma unroll
        for (int f = 0; f < 32; f++) y[f] = Bs[c + f];
        #pragma unroll
        for (int k = 0; k < 32; k++) {
            float xk = xs[k];
            const float* wr = &Ws2[k * 64 + c];
            #pragma unroll
            for (int f = 0; f < 32; f++) y[f] = fmaf(xk, wr[f], y[f]);
        }
        #pragma unroll
        for (int j = 0; j < 32; j++) {
            float yj = y[j] > 0.f ? y[j] : 0.f;
            const float* wr3 = &Ws3[(c + j) * 32];
            #pragma unroll
            for (int f = 0; f < 32; f++) acc[f] = fmaf(yj, wr3[f], acc[f]);
        }
    }
    #pragma unroll
    for (int f8 = 0; f8 < 4; f8++) {
        us8 ov;
        #pragma unroll
        for (int j = 0; j < 8; j++) ov[j] = f2bfu(acc[f8 * 8 + j]);
        *(us8*)(h + (size_t)v * 32 + f8 * 8) = ov;
    }
}

// ---------------- streaming matmul: h[v,:] = actin[v,:] @ W  (no gather) -----
template <int FIN, int FOUT>
__global__ void __launch_bounds__(256, 1) k_matmul_seq(
        const bf16* __restrict__ actin, const void* __restrict__ W,
        bf16* __restrict__ h, const int* __restrict__ flag, int n) {
    __shared__ float Ws[FIN * FOUT];
    const int f32m = flag[0];
    for (int i = threadIdx.x; i < FIN * FOUT; i += blockDim.x)
        Ws[i] = f32m ? ((const float*)W)[i] : b2f(((const bf16*)W)[i]);
    __syncthreads();
    int v = blockIdx.x * blockDim.x + threadIdx.x;
    if (v >= n) return;
    float y[FOUT];
    #pragma unroll
    for (int f = 0; f < FOUT; f++) y[f] = 0.f;
    #pragma unroll
    for (int k8 = 0; k8 < FIN / 8; k8++) {
        us8 xv = *(const us8*)(actin + (size_t)v * FIN + k8 * 8);
        #pragma unroll
        for (int j = 0; j < 8; j++) {
            float xk = bfu2f((u32)(u16)xv[j]);
            const float* wrow = &Ws[(k8 * 8 + j) * FOUT];
            #pragma unroll
            for (int f = 0; f < FOUT; f++) y[f] = fmaf(xk, wrow[f], y[f]);
        }
    }
    if constexpr (FOUT % 8 == 0) {
        #pragma unroll
        for (int f8 = 0; f8 < FOUT / 8; f8++) {
            us8 ov;
            #pragma unroll
            for (int j = 0; j < 8; j++) ov[j] = f2bfu(y[f8 * 8 + j]);
            *(us8*)(h + (size_t)v * FOUT + f8 * 8) = ov;
        }
    } else {
        #pragma unroll
        for (int f = 0; f < FOUT; f++)
            h[(size_t)v * FOUT + f] = __float2bfloat16(y[f]);
    }
}

// ---------------- CSR gather, QUAD-FEATURE x DUAL-ROW (FOUT%4==0) ----------
// u32 offsets throughout (all arrays < 4 GB): W2=16 -> shifts, no 64-bit mul.
template <int FOUT, bool FINALIZE>
__global__ void __launch_bounds__(256) k_gather2v(
        const bf16* __restrict__ g, const int* __restrict__ rowptr,
        const int* __restrict__ csr, const float* __restrict__ dis,
        const void* __restrict__ bias, bf16* __restrict__ out,
        const int* __restrict__ flag, int totq, int E) {
    constexpr int Q = FOUT / 4;         // quads per row
    constexpr u32 W2 = FOUT / 2;        // u32 words per row
    int H = (totq + 1) >> 1;
    int i = blockIdx.x * blockDim.x + threadIdx.x;
    if (i >= H) return;
    int Em1 = E - 1;
    int e1 = i;
    int e2 = i + H;
    int e2c = (e2 < totq) ? e2 : e1;
    int v1 = e1 / Q, q1 = e1 - v1 * Q;
    int v2 = e2c / Q, q2 = e2c - v2 * Q;
    u32 qo1 = (u32)(q1 * 2), qo2 = (u32)(q2 * 2);
    const u32* g32 = (const u32*)g;

    uint2 sv1 = *(const uint2*)(g32 + (u32)v1 * W2 + qo1);
    uint2 sv2 = *(const uint2*)(g32 + (u32)v2 * W2 + qo2);
    float s10 = bfu2f(sv1.x & 0xFFFFu), s11 = bfu2f(sv1.x >> 16);
    float s12 = bfu2f(sv1.y & 0xFFFFu), s13 = bfu2f(sv1.y >> 16);
    float s20 = bfu2f(sv2.x & 0xFFFFu), s21 = bfu2f(sv2.x >> 16);
    float s22 = bfu2f(sv2.y & 0xFFFFu), s23 = bfu2f(sv2.y >> 16);

    int r1 = rowptr[v1]; int c1 = rowptr[v1 + 1] - r1;
    int r2 = rowptr[v2]; int c2 = rowptr[v2 + 1] - r2;
    int last1 = min(r1 + (c1 > 0 ? c1 - 1 : 0), Em1);
    int last2 = min(r2 + (c2 > 0 ? c2 - 1 : 0), Em1);
    int j1 = 0, j2 = 0;
    while (j1 < c1 || j2 < c2) {
        int i10 = min(r1 + j1 + 0, last1), i11 = min(r1 + j1 + 1, last1);
        int i12 = min(r1 + j1 + 2, last1), i13 = min(r1 + j1 + 3, last1);
        int i20 = min(r2 + j2 + 0, last2), i21 = min(r2 + j2 + 1, last2);
        int i22 = min(r2 + j2 + 2, last2), i23 = min(r2 + j2 + 3, last2);
        u32 u10 = (u32)csr[i10], u11 = (u32)csr[i11];
        u32 u12 = (u32)csr[i12], u13 = (u32)csr[i13];
        u32 u20 = (u32)csr[i20], u21 = (u32)csr[i21];
        u32 u22 = (u32)csr[i22], u23 = (u32)csr[i23];
        uint2 a10 = *(const uint2*)(g32 + u10 * W2 + qo1);
        uint2 a11 = *(const uint2*)(g32 + u11 * W2 + qo1);
        uint2 a12 = *(const uint2*)(g32 + u12 * W2 + qo1);
        uint2 a13 = *(const uint2*)(g32 + u13 * W2 + qo1);
        uint2 a20 = *(const uint2*)(g32 + u20 * W2 + qo2);
        uint2 a21 = *(const uint2*)(g32 + u21 * W2 + qo2);
        uint2 a22 = *(const uint2*)(g32 + u22 * W2 + qo2);
        uint2 a23 = *(const uint2*)(g32 + u23 * W2 + qo2);
        // zero masked edges on the raw words (bf16 0x0000 == 0.0f)
        if (j1 + 0 >= c1) { a10.x = 0; a10.y = 0; }
        if (j1 + 1 >= c1) { a11.x = 0; a11.y = 0; }
        if (j1 + 2 >= c1) { a12.x = 0; a12.y = 0; }
        if (j1 + 3 >= c1) { a13.x = 0; a13.y = 0; }
        if (j2 + 0 >= c2) { a20.x = 0; a20.y = 0; }
        if (j2 + 1 >= c2) { a21.x = 0; a21.y = 0; }
        if (j2 + 2 >= c2) { a22.x = 0; a22.y = 0; }
        if (j2 + 3 >= c2) { a23.x = 0; a23.y = 0; }
        s10 += bfu2f(a10.x & 0xFFFFu) + bfu2f(a11.x & 0xFFFFu)
             + bfu2f(a12.x & 0xFFFFu) + bfu2f(a13.x & 0xFFFFu);
        s11 += bfu2f(a10.x >> 16) + bfu2f(a11.x >> 16)
             + bfu2f(a12.x >> 16) + bfu2f(a13.x >> 16);
        s12 += bfu2f(a10.y & 0xFFFFu) + bfu2f(a11.y & 0xFFFFu)
             + bfu2f(a12.y & 0xFFFFu) + bfu2f(a13.y & 0xFFFFu);
        s13 += bfu2f(a10.y >> 16) + bfu2f(a11.y >> 16)
             + bfu2f(a12.y >> 16) + bfu2f(a13.y >> 16);
        s20 += bfu2f(a20.x & 0xFFFFu) + bfu2f(a21.x & 0xFFFFu)
             + bfu2f(a22.x & 0xFFFFu) + bfu2f(a23.x & 0xFFFFu);
        s21 += bfu2f(a20.x >> 16) + bfu2f(a21.x >> 16)
             + bfu2f(a22.x >> 16) + bfu2f(a23.x >> 16);
        s22 += bfu2f(a20.y & 0xFFFFu) + bfu2f(a21.y & 0xFFFFu)
             + bfu2f(a22.y & 0xFFFFu) + bfu2f(a23.y & 0xFFFFu);
        s23 += bfu2f(a20.y >> 16) + bfu2f(a21.y >> 16)
             + bfu2f(a22.y >> 16) + bfu2f(a23.y >> 16);
        j1 += 4; j2 += 4;
    }
    float dv1 = dis[v1], dv2 = dis[v2];
    float o1[4] = {s10, s11, s12, s13};
    float o2[4] = {s20, s21, s22, s23};
    uint2 w1, w2;
    if (FINALIZE) {
        int f32m = flag[0];
        #pragma unroll
        for (int k = 0; k < 4; k++) {
            int f1 = q1 * 4 + k, f2 = q2 * 4 + k;
            float bf1 = f32m ? ((const float*)bias)[f1] : b2f(((const bf16*)bias)[f1]);
            float bf2 = f32m ? ((const float*)bias)[f2] : b2f(((const bf16*)bias)[f2]);
            o1[k] = fmaf(dv1, o1[k], bf1); o1[k] = o1[k] > 0.f ? o1[k] : 0.f;
            o2[k] = fmaf(dv2, o2[k], bf2); o2[k] = o2[k] > 0.f ? o2[k] : 0.f;
        }
    } else {
        #pragma unroll
        for (int k = 0; k < 4; k++) { o1[k] *= dv1; o2[k] *= dv2; }
    }
    w1.x = (u32)f2bfu(o1[0]) | ((u32)f2bfu(o1[1]) << 16);
    w1.y = (u32)f2bfu(o1[2]) | ((u32)f2bfu(o1[3]) << 16);
    w2.x = (u32)f2bfu(o2[0]) | ((u32)f2bfu(o2[1]) << 16);
    w2.y = (u32)f2bfu(o2[2]) | ((u32)f2bfu(o2[3]) << 16);
    u32* o32 = (u32*)out;
    *(uint2*)(o32 + (u32)v1 * W2 + qo1) = w1;
    if (e2 < totq) *(uint2*)(o32 + (u32)v2 * W2 + qo2) = w2;
}

// ---------------- CSR gather, DUAL-ROW per thread (FOUT=3 path) -------------
template <int FOUT, bool FINALIZE>
__global__ void __launch_bounds__(256) k_gather2(
        const bf16* __restrict__ g, const int* __restrict__ rowptr,
        const int* __restrict__ csr, const float* __restrict__ dis,
        const void* __restrict__ bias, bf16* __restrict__ out,
        const int* __restrict__ flag, int total, int E) {
    int H = (total + 1) >> 1;
    int i = blockIdx.x * blockDim.x + threadIdx.x;
    if (i >= H) return;
    int Em1 = E - 1;
    int e1 = i;
    int e2 = i + H;
    int e2c = (e2 < total) ? e2 : e1;
    int v1 = e1 / FOUT, f1 = e1 - v1 * FOUT;
    int v2 = e2c / FOUT, f2 = e2c - v2 * FOUT;
    float s1 = b2f(g[e1]);    // self-loop terms
    float s2 = b2f(g[e2c]);
    int r1 = rowptr[v1]; int c1 = rowptr[v1 + 1] - r1;
    int r2 = rowptr[v2]; int c2 = rowptr[v2 + 1] - r2;
    int last1 = min(r1 + (c1 > 0 ? c1 - 1 : 0), Em1);
    int last2 = min(r2 + (c2 > 0 ? c2 - 1 : 0), Em1);
    int j1 = 0, j2 = 0;
    while (j1 < c1 || j2 < c2) {
        int i10 = min(r1 + j1 + 0, last1), i11 = min(r1 + j1 + 1, last1);
        int i12 = min(r1 + j1 + 2, last1), i13 = min(r1 + j1 + 3, last1);
        int i20 = min(r2 + j2 + 0, last2), i21 = min(r2 + j2 + 1, last2);
        int i22 = min(r2 + j2 + 2, last2), i23 = min(r2 + j2 + 3, last2);
        int u10 = csr[i10], u11 = csr[i11], u12 = csr[i12], u13 = csr[i13];
        int u20 = csr[i20], u21 = csr[i21], u22 = csr[i22], u23 = csr[i23];
        float a10 = b2f(g[(size_t)u10 * FOUT + f1]);
        float a11 = b2f(g[(size_t)u11 * FOUT + f1]);
        float a12 = b2f(g[(size_t)u12 * FOUT + f1]);
        float a13 = b2f(g[(size_t)u13 * FOUT + f1]);
        float a20 = b2f(g[(size_t)u20 * FOUT + f2]);
        float a21 = b2f(g[(size_t)u21 * FOUT + f2]);
        float a22 = b2f(g[(size_t)u22 * FOUT + f2]);
        float a23 = b2f(g[(size_t)u23 * FOUT + f2]);
        s1 += ((j1 + 0 < c1 ? a10 : 0.f) + (j1 + 1 < c1 ? a11 : 0.f))
            + ((j1 + 2 < c1 ? a12 : 0.f) + (j1 + 3 < c1 ? a13 : 0.f));
        s2 += ((j2 + 0 < c2 ? a20 : 0.f) + (j2 + 1 < c2 ? a21 : 0.f))
            + ((j2 + 2 < c2 ? a22 : 0.f) + (j2 + 3 < c2 ? a23 : 0.f));
        j1 += 4; j2 += 4;
    }
    float dv1 = dis[v1], dv2 = dis[v2];
    float o1, o2;
    if (FINALIZE) {
        float bf1 = flag[0] ? ((const float*)bias)[f1] : b2f(((const bf16*)bias)[f1]);
        float bf2 = flag[0] ? ((const float*)bias)[f2] : b2f(((const bf16*)bias)[f2]);
        o1 = fmaf(dv1, s1, bf1); o1 = o1 > 0.f ? o1 : 0.f;
        o2 = fmaf(dv2, s2, bf2); o2 = o2 > 0.f ? o2 : 0.f;
    } else {
        o1 = dv1 * s1;
        o2 = dv2 * s2;
    }
    out[e1] = __float2bfloat16(o1);
    if (e2 < total) out[e2] = __float2bfloat16(o2);
}

// ---------------- final unpool gather -> out (dtype per flag) ----------------
__global__ void k_gather_out(const bf16* __restrict__ act, const int* __restrict__ idx,
                             void* __restrict__ out, const int* __restrict__ flag, int n) {
    int u = blockIdx.x * blockDim.x + threadIdx.x;
    if (u >= n) return;
    size_t r = (size_t)idx[u];
    float v0 = b2f(act[3 * r + 0]);
    float v1 = b2f(act[3 * r + 1]);
    float v2 = b2f(act[3 * r + 2]);
    if (flag[0]) {
        float* o = (float*)out;
        o[3 * (size_t)u + 0] = v0; o[3 * (size_t)u + 1] = v1; o[3 * (size_t)u + 2] = v2;
    } else {
        bf16* o = (bf16*)out;
        o[3 * (size_t)u + 0] = __float2bfloat16(v0);
        o[3 * (size_t)u + 1] = __float2bfloat16(v1);
        o[3 * (size_t)u + 2] = __float2bfloat16(v2);
    }
}

static inline int cdiv(long long a, long long b) { return (int)((a + b - 1) / b); }

extern "C" void kernel_launch(void* const* d_in, const int* in_sizes, int n_in,
                              void* d_out, int out_size, void* d_ws, size_t ws_size,
                              hipStream_t stream) {
    const void* x  = d_in[0];
    const void* W1 = d_in[1]; const void* b1 = d_in[2];
    const void* W2 = d_in[3]; const void* b2 = d_in[4];
    const void* W3 = d_in[5]; const void* b3 = d_in[6];
    const void* W4 = d_in[7]; const void* b4 = d_in[8];
    const int* e0  = (const int*)d_in[9];
    const int* up1 = (const int*)d_in[10];
    const int* e1  = (const int*)d_in[11];
    const int* up2 = (const int*)d_in[12];
    const int* e2  = (const int*)d_in[13];
    const int* up3 = (const int*)d_in[14];
    const int* e3  = (const int*)d_in[15];
    const int* up4 = (const int*)d_in[16];

    const int N0 = in_sizes[0] / 3;
    const int N1 = in_sizes[10];
    const int N2 = in_sizes[12];
    const int N3 = in_sizes[14];
    const int N4 = in_sizes[16];
    const int E0 = in_sizes[9] / 2, E1 = in_sizes[11] / 2;
    const int E2 = in_sizes[13] / 2, E3 = in_sizes[15] / 2;

    int Ns[4] = {N0, N1, N2, N3};
    int Es[4] = {E0, E1, E2, E3};
    const int* srcs[4] = {e0, e1, e2, e3};
    const int* dsts[4] = {e0 + E0, e1 + E1, e2 + E2, e3 + E3};

    // buffer element counts
    size_t gmax = (size_t)N0 * 3;
    if ((size_t)N1 * 32 > gmax) gmax = (size_t)N1 * 32;
    if ((size_t)N2 * 32 > gmax) gmax = (size_t)N2 * 32;
    if ((size_t)N3 * 3  > gmax) gmax = (size_t)N3 * 3;
    size_t amax = (size_t)N0 * 32;
    if ((size_t)N1 * 64 > amax) amax = (size_t)N1 * 64;
    if ((size_t)N2 * 32 > amax) amax = (size_t)N2 * 32;
    if ((size_t)N3 * 3  > amax) amax = (size_t)N3 * 3;
    gmax = (gmax + 7) & ~(size_t)7;
    amax = (amax + 7) & ~(size_t)7;

    Pack pk;
    char* p = (char*)d_ws;
    int* flag = (int*)p;            p += 256;
    int* gcur_all = (int*)p;        p += 1024 * 4;
    int* bbase_all = (int*)p;       p += 1024 * 4;

    for (int s = 0; s < 4; s++) {
        pk.s[s].src = srcs[s]; pk.s[s].dst = dsts[s];
        pk.s[s].E = Es[s]; pk.s[s].N = Ns[s];
        int nb = cdiv(Ns[s], CRANGE);
        pk.s[s].nb = nb;
        pk.s[s].nblk = cdiv(Es[s], TILE);
        pk.s[s].nbpad = (nb + 15) & ~15;
        pk.s[s].cap = (Es[s] / nb + Es[s] / (8 * nb) + 256 + 3) & ~3;  // % 4 == 0
        pk.s[s].gcur = gcur_all + s * 256;
        pk.s[s].M = (int*)p;        p += (size_t)pk.s[s].nblk * pk.s[s].nbpad * 4;
        pk.s[s].rowptr = (int*)p;   p += ((size_t)(Ns[s] + 1 + 3) & ~(size_t)3) * 4;
        pk.s[s].dis = (float*)p;    p += ((size_t)(Ns[s] + 3) & ~(size_t)3) * 4;
    }
    for (int s = 0; s < 4; s++) {
        pk.s[s].csr = (int*)p;      p += ((size_t)(Es[s] + 3) & ~(size_t)3) * 4;
    }

    // union region (16B aligned): pairs (build) aliases g|act|xt (compute)
    char* U = (char*)(((size_t)p + 15) & ~(size_t)15);
    size_t pairsBytes = 0;
    for (int s = 0; s < 4; s++) {
        pk.s[s].pairs = (u32*)(U + pairsBytes);
        pairsBytes += (size_t)pk.s[s].cap * pk.s[s].nb * 4;
    }
    bf16* g   = (bf16*)U;
    bf16* act = g + gmax;
    bf16* xt  = act + amax;

    // grids
    int ptot = 0, btot = 0;
    for (int s = 0; s < 4; s++) {
        pk.poff[s] = ptot; ptot += pk.s[s].nblk;
        pk.boff[s] = btot; btot += pk.s[s].nb;
    }

    const int B = 256;

    k_detect<<<1, 256, 0, stream>>>((const u16*)x, flag);
    k_init<<<4, 256, 0, stream>>>(gcur_all, pk);
    k_part_hist<<<ptot, B, 0, stream>>>(pk);
    k_part_scan<<<btot, B, 0, stream>>>(pk);
    k_partition<<<ptot, B, 0, stream>>>(pk);
    k_scan_bbase<<<4, B, 0, stream>>>(pk, bbase_all);
    k_build<<<btot, 512, 0, stream>>>(pk, bbase_all);

    // ---- stage 1 (agg-first): aggregate x (3 feats) -> xt1
    {
        int T = N0 * 3, Hh = (T + 1) >> 1;
        k_pre<3, true><<<cdiv(T, B), B, 0, stream>>>(
            x, nullptr, nullptr, pk.s[0].dis, g, flag, T);
        k_gather2<3, false><<<cdiv(Hh, B), B, 0, stream>>>(
            g, pk.s[0].rowptr, pk.s[0].csr, pk.s[0].dis, nullptr, xt, flag, T, E0);
    }

    // ---- fused stage1-post + stage2-pre: g2 = dis2 * relu(xt1[up1]@W1+b1)
    k_fuse_mm_pre<<<cdiv(N1, B), B, 0, stream>>>(
        xt, up1, W1, b1, pk.s[1].dis, g, flag, N1);

    // ---- stage 2 aggregate -> xt2
    {
        int Tq = N1 * 8, Hq = (Tq + 1) >> 1;
        k_gather2v<32, false><<<cdiv(Hq, B), B, 0, stream>>>(
            g, pk.s[1].rowptr, pk.s[1].csr, pk.s[1].dis, nullptr, xt, flag, Tq, E1);
    }

    // ---- fused stage2-post + stage3-matmul: h3 = relu(xt2@W2+b2)@W3 -> act
    k_fuse_mm2<<<cdiv(N1, B), B, 0, stream>>>(xt, W2, b2, W3, act, flag, N1);

    // ---- stage 3: g3 = dis3 * h3[up2], then quad-vector aggregate -> act3
    {
        int Tq = N2 * 8, Hq = (Tq + 1) >> 1;
        k_pre<32, false><<<cdiv((long long)N2 * 32, B), B, 0, stream>>>(
            nullptr, up2, act, pk.s[2].dis, g, flag, N2 * 32);
        k_gather2v<32, true><<<cdiv(Hq, B), B, 0, stream>>>(
            g, pk.s[2].rowptr, pk.s[2].csr, pk.s[2].dis, b3, act, flag, Tq, E2);
    }

    // ---- stage 4 (W-first): h4 = act3@W4 at N2, g4 = dis4*h4[up3], aggregate
    {
        int T = N3 * 3, Hh = (T + 1) >> 1;
        k_matmul_seq<32, 3><<<cdiv(N2, B), B, 0, stream>>>(act, W4, xt, flag, N2);
        k_pre<3, false><<<cdiv(T, B), B, 0, stream>>>(
            nullptr, up3, xt, pk.s[3].dis, g, flag, T);
        k_gather2<3, true><<<cdiv(Hh, B), B, 0, stream>>>(
            g, pk.s[3].rowptr, pk.s[3].csr, pk.s[3].dis, b4, act, flag, T, E3);
    }

    // ---- final unpool
    k_gather_out<<<cdiv(N4, B), B, 0, stream>>>(act, up4, d_out, flag, N4);
}

// Round 12
// 465.024 us; speedup vs baseline: 1.0822x; 1.0237x over previous
//
#include <hip/hip_runtime.h>
#include <hip/hip_bf16.h>

typedef __hip_bfloat16 bf16;
typedef unsigned short u16;
typedef unsigned char u8;
typedef unsigned int u32;
typedef __attribute__((ext_vector_type(8))) unsigned short us8;

static __device__ __forceinline__ float b2f(bf16 v) { return __bfloat162float(v); }
static __device__ __forceinline__ float bfu2f(u32 u) {
    union { u32 i; float f; } c; c.i = u << 16; return c.f;
}
static __device__ __forceinline__ u16 f2bfu(float f) {
    u32 x = __float_as_uint(f);
    return (u16)((x + 0x7FFFu + ((x >> 16) & 1u)) >> 16);
}

#define TILE 4096        // edges per partition block
#define CBITS 12         // coarse bucket = 4096-vertex range (all stages)
#define CRANGE 4096
#define OUTB 26624       // build staging capacity (tot ~24.5K + >8 sigma); 104 KB
// f32 weight scratch layout (floats, offsets 64B-aligned)
#define WF_W1 0
#define WF_B1 128
#define WF_W2 192
#define WF_B2 2240
#define WF_W3 2304
#define WF_W4 4352
#define WF_TOT 4608
#define RPT16(M) M(0) M(1) M(2) M(3) M(4) M(5) M(6) M(7) \
                 M(8) M(9) M(10) M(11) M(12) M(13) M(14) M(15)

struct SP {
    const int* src; const int* dst;
    int E, N, cap, nb, nblk, nbpad;
    int* gcur;      // [nb] per-bucket totals (written by k_part_scan)
    u32* pairs;     // [nb][cap] packed (local_dst12 << 20) | src20
    int* M;         // [nblk][nbpad] counts -> exclusive bases
    int* rowptr; float* dis; int* csr;
};
struct Pack {
    SP s[4];
    int poff[4];  // tile-grid start offset per stage
    int boff[4];  // bucket-grid start offset per stage
};

// ---------------- dtype detection ----------------
__global__ void k_detect(const u16* __restrict__ xraw, int* __restrict__ flag) {
    __shared__ int s;
    if (threadIdx.x == 0) s = 0;
    __syncthreads();
    u16 u = xraw[threadIdx.x];
    int e = (u >> 7) & 0xFF;
    if (e >= 0x8F) atomicAdd(&s, 1);
    __syncthreads();
    if (threadIdx.x == 0) flag[0] = (s > 0) ? 1 : 0;
}

// ---------------- one-time weight conversion to f32 scratch -----------------
__global__ void k_prep_w(const void* W1, const void* b1, const void* W2,
                         const void* b2, const void* W3, const void* W4,
                         float* __restrict__ wf, const int* __restrict__ flag) {
    int t = blockIdx.x * 256 + threadIdx.x;
    int f32m = flag[0];
    const void* src; int off; int len;
    if      (t < WF_B1)  { src = W1; off = t - WF_W1; len = 96;  }
    else if (t < WF_W2)  { src = b1; off = t - WF_B1; len = 32;  }
    else if (t < WF_B2)  { src = W2; off = t - WF_W2; len = 2048;}
    else if (t < WF_W3)  { src = b2; off = t - WF_B2; len = 64;  }
    else if (t < WF_W4)  { src = W3; off = t - WF_W3; len = 2048;}
    else if (t < WF_TOT) { src = W4; off = t - WF_W4; len = 96;  }
    else return;
    if (off >= len) return;
    wf[t] = f32m ? ((const float*)src)[off] : b2f(((const bf16*)src)[off]);
}

// zero gcur (4 x 256) + rowptr sentinels
__global__ void k_init(int* __restrict__ gcur_all, Pack pk) {
    int i = blockIdx.x * blockDim.x + threadIdx.x;
    if (i < 1024) gcur_all[i] = 0;
    if (i < 4) pk.s[i].rowptr[pk.s[i].N] = pk.s[i].E;
}

// ---------------- pass A0: per-tile bucket counts -> M[tile][bucket] ----------
__global__ void __launch_bounds__(256) k_part_hist(Pack pk) {
    __shared__ int hist[256];
    int bid = blockIdx.x;
    int si = (bid >= pk.poff[3]) ? 3 : (bid >= pk.poff[2]) ? 2 : (bid >= pk.poff[1]) ? 1 : 0;
    const SP sp = pk.s[si];
    int lb = bid - pk.poff[si];
    int t = threadIdx.x;
    int n = min(TILE, sp.E - lb * TILE);
    const int* dstp = sp.dst + lb * TILE;

#define LOADK(k) int d##k; { int i = t + 256*(k); d##k = (i < n) ? dstp[i] : -1; }
    RPT16(LOADK)
#undef LOADK
    hist[t] = 0;
    __syncthreads();
#define HISTK(k) if (d##k >= 0) atomicAdd(&hist[d##k >> CBITS], 1);
    RPT16(HISTK)
#undef HISTK
    __syncthreads();
    int* Mrow = sp.M + (size_t)lb * sp.nbpad;
    for (int b = t; b < sp.nb; b += 256) Mrow[b] = hist[b];
}

// ---------------- pass A-scan: per-bucket column scan of M (in place) --------
__global__ void __launch_bounds__(256) k_part_scan(Pack pk) {
    __shared__ int buf[256];
    int bid = blockIdx.x;
    int si = (bid >= pk.boff[3]) ? 3 : (bid >= pk.boff[2]) ? 2 : (bid >= pk.boff[1]) ? 1 : 0;
    const SP sp = pk.s[si];
    int b = bid - pk.boff[si];
    int t = threadIdx.x;
    int nblk = sp.nblk, nbpad = sp.nbpad;
    int* M = sp.M;
    int carry = 0;
    for (int base = 0; base < nblk; base += 256) {
        int m = min(256, nblk - base);
        int v = (t < m) ? M[(size_t)(base + t) * nbpad + b] : 0;
        buf[t] = v;
        __syncthreads();
        for (int off = 1; off < 256; off <<= 1) {
            int w = (t >= off) ? buf[t - off] : 0;
            __syncthreads();
            buf[t] += w;
            __syncthreads();
        }
        int excl = buf[t] - v + carry;
        int ctot = buf[255];
        __syncthreads();
        if (t < m) M[(size_t)(base + t) * nbpad + b] = excl;
        carry += ctot;
    }
    if (t == 0) sp.gcur[b] = carry;
}

// ---------------- pass A1: scatter to pairs at deterministic bases -----------
__global__ void __launch_bounds__(256) k_partition(Pack pk) {
    __shared__ u32 stage[TILE];   // 16 KB
    __shared__ u8  bkt[TILE];     //  4 KB
    __shared__ int hist[256];
    __shared__ int gofs[256];
    __shared__ int tmp[256];

    int bid = blockIdx.x;
    int si = (bid >= pk.poff[3]) ? 3 : (bid >= pk.poff[2]) ? 2 : (bid >= pk.poff[1]) ? 1 : 0;
    const SP sp = pk.s[si];
    int lb = bid - pk.poff[si];
    int t = threadIdx.x;
    int n = min(TILE, sp.E - lb * TILE);
    const int* dstp = sp.dst + lb * TILE;
    const int* srcp = sp.src + lb * TILE;

#define LOADK(k) int d##k, s##k; { int i = t + 256*(k); \
    if (i < n) { d##k = dstp[i]; s##k = srcp[i]; } else { d##k = -1; s##k = 0; } }
    RPT16(LOADK)
#undef LOADK

    hist[t] = 0;
    __syncthreads();
#define HISTK(k) if (d##k >= 0) atomicAdd(&hist[d##k >> CBITS], 1);
    RPT16(HISTK)
#undef HISTK
    __syncthreads();

    int h = hist[t];
    tmp[t] = h; __syncthreads();
    for (int off = 1; off < 256; off <<= 1) {
        int v = (t >= off) ? tmp[t - off] : 0;
        __syncthreads();
        tmp[t] += v;
        __syncthreads();
    }
    int lofs = tmp[t] - h;
    int gb = (t < sp.nb) ? sp.M[(size_t)lb * sp.nbpad + t] : 0;  // scanned base
    gofs[t] = gb - lofs;
    hist[t] = lofs;   // scatter cursor
    __syncthreads();

#define SCATK(k) if (d##k >= 0) { int b = d##k >> CBITS; \
    int pos = atomicAdd(&hist[b], 1); \
    stage[pos] = (((u32)d##k & 4095u) << 20) | (u32)s##k; \
    bkt[pos] = (u8)b; }
    RPT16(SCATK)
#undef SCATK
    __syncthreads();

    int cap = sp.cap;
    u32* pairs = sp.pairs;
    for (int i = t; i < n; i += 256) {
        int b = bkt[i];
        pairs[(size_t)b * cap + gofs[b] + i] = stage[i];
    }
}

// ---------------- bucket-base scan (one block per stage) ----------------
__global__ void k_scan_bbase(Pack pk, int* __restrict__ bbase_all) {
    __shared__ int tmp[256];
    int si = blockIdx.x;
    int t = threadIdx.x;
    int nb = pk.s[si].nb;
    int v = (t < nb) ? pk.s[si].gcur[t] : 0;
    tmp[t] = v; __syncthreads();
    for (int off = 1; off < 256; off <<= 1) {
        int w = (t >= off) ? tmp[t - off] : 0;
        __syncthreads();
        tmp[t] += w;
        __syncthreads();
    }
    bbase_all[si * 256 + t] = tmp[t] - v;
}

// ---------------- build: one block per coarse bucket, 3 passes --------------
__global__ void __launch_bounds__(512) k_build(Pack pk, const int* __restrict__ bbase_all) {
    __shared__ int hist[4096];    //  16 KB: counts -> local offsets -> cursor
    __shared__ int outb[OUTB];    // 104 KB staged csr for the whole bucket
    __shared__ int tmp[512];

    int bid = blockIdx.x;
    int si = (bid >= pk.boff[3]) ? 3 : (bid >= pk.boff[2]) ? 2 : (bid >= pk.boff[1]) ? 1 : 0;
    const SP sp = pk.s[si];
    int b = bid - pk.boff[si];
    int t = threadIdx.x;

    int bbase = bbase_all[si * 256 + b];
    int tot = sp.gcur[b];
    const u32* p = sp.pairs + (size_t)b * sp.cap;   // 16B aligned (cap % 4 == 0)
    const uint4* p4 = (const uint4*)p;
    int tot4 = tot >> 2;

    for (int i = t; i < 4096; i += 512) hist[i] = 0;
    __syncthreads();
    for (int i = t; i < tot4; i += 512) {
        uint4 u = p4[i];
        atomicAdd(&hist[u.x >> 20], 1);
        atomicAdd(&hist[u.y >> 20], 1);
        atomicAdd(&hist[u.z >> 20], 1);
        atomicAdd(&hist[u.w >> 20], 1);
    }
    for (int i = (tot4 << 2) + t; i < tot; i += 512)
        atomicAdd(&hist[p[i] >> 20], 1);
    __syncthreads();

    // in-place exclusive scan of 4096 bins; counts in registers (8/thread)
    int lbase = t * 8;
    int cnt[8], cof[8];
    #pragma unroll
    for (int k = 0; k < 8; k++) cnt[k] = hist[lbase + k];
    int s = 0;
    #pragma unroll
    for (int k = 0; k < 8; k++) { cof[k] = s; s += cnt[k]; }
    tmp[t] = s; __syncthreads();
    for (int off = 1; off < 512; off <<= 1) {
        int v = (t >= off) ? tmp[t - off] : 0;
        __syncthreads();
        tmp[t] += v;
        __syncthreads();
    }
    int tb = tmp[t] - s;

    int nbase = b << CBITS;
    #pragma unroll
    for (int k = 0; k < 8; k++) {
        int bin = lbase + k;
        hist[bin] = tb + cof[k];          // bucket-local offset (-> cursor)
        int v = nbase + bin;
        if (v < sp.N) {
            sp.rowptr[v] = bbase + tb + cof[k];
            sp.dis[v] = rsqrtf((float)(cnt[k] + 1));
        }
    }
    __syncthreads();

    if (tot <= OUTB) {
        for (int i = t; i < tot4; i += 512) {
            uint4 u = p4[i];
            int pos;
            pos = atomicAdd(&hist[u.x >> 20], 1); outb[pos] = (int)(u.x & 0xFFFFFu);
            pos = atomicAdd(&hist[u.y >> 20], 1); outb[pos] = (int)(u.y & 0xFFFFFu);
            pos = atomicAdd(&hist[u.z >> 20], 1); outb[pos] = (int)(u.z & 0xFFFFFu);
            pos = atomicAdd(&hist[u.w >> 20], 1); outb[pos] = (int)(u.w & 0xFFFFFu);
        }
        for (int i = (tot4 << 2) + t; i < tot; i += 512) {
            u32 u = p[i];
            int pos = atomicAdd(&hist[u >> 20], 1);
            outb[pos] = (int)(u & 0xFFFFFu);
        }
        __syncthreads();
        for (int i = t; i < tot; i += 512)
            sp.csr[bbase + i] = outb[i];
    } else {  // statistical overflow fallback: direct global scatter
        for (int i = t; i < tot; i += 512) {
            u32 u = p[i];
            int pos = atomicAdd(&hist[u >> 20], 1);
            sp.csr[bbase + pos] = (int)(u & 0xFFFFFu);
        }
    }
}

// ---------------- pre-scale: g[v,f] = dis[v] * x_in[row(v), f] ----------------
template <int F, bool EXT>
__global__ void k_pre(const void* __restrict__ xin, const int* __restrict__ gidx,
                      const bf16* __restrict__ actin, const float* __restrict__ dis,
                      bf16* __restrict__ g, const int* __restrict__ flag, int total) {
    int i = blockIdx.x * blockDim.x + threadIdx.x;
    if (i >= total) return;
    int v = i / F;
    int f = i - v * F;
    float x;
    if (EXT) {
        if (flag[0]) x = ((const float*)xin)[i];
        else         x = b2f(((const bf16*)xin)[i]);
    } else {
        int row = gidx[v];
        x = b2f(actin[(size_t)row * F + f]);
    }
    g[i] = __float2bfloat16(dis[v] * x);
}

// ---------------- fused stage1-post + stage2-pre ----------------------------
// g2[v] = dis2[v] * relu(xt1[up1[v]] @ W1 + b1).  Weights: f32 global,
// wave-uniform addresses -> scalar loads, SGPR operands.
__global__ void __launch_bounds__(256, 1) k_fuse_mm_pre(
        const bf16* __restrict__ xt1, const int* __restrict__ up,
        const float* __restrict__ wf, const float* __restrict__ dis,
        bf16* __restrict__ g, int n) {
    const float* W = wf + WF_W1;
    const float* B = wf + WF_B1;
    int v = blockIdx.x * 256 + threadIdx.x;
    if (v >= n) return;
    int r = up[v];
    float x0 = b2f(xt1[(size_t)r * 3 + 0]);
    float x1 = b2f(xt1[(size_t)r * 3 + 1]);
    float x2 = b2f(xt1[(size_t)r * 3 + 2]);
    float dv = dis[v];
    #pragma unroll
    for (int f8 = 0; f8 < 4; f8++) {
        us8 ov;
        #pragma unroll
        for (int j = 0; j < 8; j++) {
            int f = f8 * 8 + j;
            float y = B[f];
            y = fmaf(x0, W[f], y);
            y = fmaf(x1, W[32 + f], y);
            y = fmaf(x2, W[64 + f], y);
            y = y > 0.f ? y : 0.f;
            ov[j] = f2bfu(dv * y);
        }
        *(us8*)(g + (size_t)v * 32 + f8 * 8) = ov;
    }
}

// ---------------- fused stage2-post + stage3-matmul -------------------------
// h3[v] = relu(xt2[v] @ W2 + b2) @ W3.  x in per-thread LDS row (no spill);
// weights f32 global uniform -> scalar loads feed FMAs (no LDS weight reads).
__global__ void __launch_bounds__(256, 1) k_fuse_mm2(
        const bf16* __restrict__ xt2, const float* __restrict__ wf,
        bf16* __restrict__ h, int n) {
    __shared__ float Xs[256 * 33];   // 33 KB per-thread x rows, pad 33
    const float* W2f = wf + WF_W2;
    const float* B2f = wf + WF_B2;
    const float* W3f = wf + WF_W3;
    int v = blockIdx.x * 256 + threadIdx.x;
    if (v >= n) return;
    float* xs = &Xs[threadIdx.x * 33];   // private row, no barrier needed
    #pragma unroll
    for (int k8 = 0; k8 < 4; k8++) {
        us8 xv = *(const us8*)(xt2 + (size_t)v * 32 + k8 * 8);
        #pragma unroll
        for (int j = 0; j < 8; j++) xs[k8 * 8 + j] = bfu2f((u32)(u16)xv[j]);
    }
    float acc[32];
    #pragma unroll
    for (int f = 0; f < 32; f++) acc[f] = 0.f;
    #pragma unroll
    for (int c = 0; c < 64; c += 32) {
        float y[32];
        #pragma unroll
        for (int f = 0; f < 32; f++) y[f] = B2f[c + f];
        #pragma unroll
        for (int k = 0; k < 32; k++) {
            float xk = xs[k];
            const float* wr = &W2f[k * 64 + c];
            #pragma unroll
            for (int f = 0; f < 32; f++) y[f] = fmaf(xk, wr[f], y[f]);
        }
        #pragma unroll
        for (int j = 0; j < 32; j++) {
            float yj = y[j] > 0.f ? y[j] : 0.f;
            const float* wr3 = &W3f[(c + j) * 32];
            #pragma unroll
            for (int f = 0; f < 32; f++) acc[f] = fmaf(yj, wr3[f], acc[f]);
        }
    }
    #pragma unroll
    for (int f8 = 0; f8 < 4; f8++) {
        us8 ov;
        #pragma unroll
        for (int j = 0; j < 8; j++) ov[j] = f2bfu(acc[f8 * 8 + j]);
        *(us8*)(h + (size_t)v * 32 + f8 * 8) = ov;
    }
}

// ---------------- streaming matmul: h[v,:] = actin[v,:] @ W  (f32 weights) ---
template <int FIN, int FOUT>
__global__ void __launch_bounds__(256, 1) k_matmul_seq(
        const bf16* __restrict__ actin, const float* __restrict__ W,
        bf16* __restrict__ h, int n) {
    int v = blockIdx.x * blockDim.x + threadIdx.x;
    if (v >= n) return;
    float y[FOUT];
    #pragma unroll
    for (int f = 0; f < FOUT; f++) y[f] = 0.f;
    #pragma unroll
    for (int k8 = 0; k8 < FIN / 8; k8++) {
        us8 xv = *(const us8*)(actin + (size_t)v * FIN + k8 * 8);
        #pragma unroll
        for (int j = 0; j < 8; j++) {
            float xk = bfu2f((u32)(u16)xv[j]);
            const float* wrow = &W[(k8 * 8 + j) * FOUT];
            #pragma unroll
            for (int f = 0; f < FOUT; f++) y[f] = fmaf(xk, wrow[f], y[f]);
        }
    }
    if constexpr (FOUT % 8 == 0) {
        #pragma unroll
        for (int f8 = 0; f8 < FOUT / 8; f8++) {
            us8 ov;
            #pragma unroll
            for (int j = 0; j < 8; j++) ov[j] = f2bfu(y[f8 * 8 + j]);
            *(us8*)(h + (size_t)v * FOUT + f8 * 8) = ov;
        }
    } else {
        #pragma unroll
        for (int f = 0; f < FOUT; f++)
            h[(size_t)v * FOUT + f] = __float2bfloat16(y[f]);
    }
}

// ---------------- CSR gather, QUAD-FEATURE x DUAL-ROW (FOUT%4==0) ----------
// u32 offsets throughout (all arrays < 4 GB): W2=16 -> shifts, no 64-bit mul.
template <int FOUT, bool FINALIZE>
__global__ void __launch_bounds__(256) k_gather2v(
        const bf16* __restrict__ g, const int* __restrict__ rowptr,
        const int* __restrict__ csr, const float* __restrict__ dis,
        const void* __restrict__ bias, bf16* __restrict__ out,
        const int* __restrict__ flag, int totq, int E) {
    constexpr int Q = FOUT / 4;         // quads per row
    constexpr u32 W2 = FOUT / 2;        // u32 words per row
    int H = (totq + 1) >> 1;
    int i = blockIdx.x * blockDim.x + threadIdx.x;
    if (i >= H) return;
    int Em1 = E - 1;
    int e1 = i;
    int e2 = i + H;
    int e2c = (e2 < totq) ? e2 : e1;
    int v1 = e1 / Q, q1 = e1 - v1 * Q;
    int v2 = e2c / Q, q2 = e2c - v2 * Q;
    u32 qo1 = (u32)(q1 * 2), qo2 = (u32)(q2 * 2);
    const u32* g32 = (const u32*)g;

    uint2 sv1 = *(const uint2*)(g32 + (u32)v1 * W2 + qo1);
    uint2 sv2 = *(const uint2*)(g32 + (u32)v2 * W2 + qo2);
    float s10 = bfu2f(sv1.x & 0xFFFFu), s11 = bfu2f(sv1.x >> 16);
    float s12 = bfu2f(sv1.y & 0xFFFFu), s13 = bfu2f(sv1.y >> 16);
    float s20 = bfu2f(sv2.x & 0xFFFFu), s21 = bfu2f(sv2.x >> 16);
    float s22 = bfu2f(sv2.y & 0xFFFFu), s23 = bfu2f(sv2.y >> 16);

    int r1 = rowptr[v1]; int c1 = rowptr[v1 + 1] - r1;
    int r2 = rowptr[v2]; int c2 = rowptr[v2 + 1] - r2;
    int last1 = min(r1 + (c1 > 0 ? c1 - 1 : 0), Em1);
    int last2 = min(r2 + (c2 > 0 ? c2 - 1 : 0), Em1);
    int j1 = 0, j2 = 0;
    while (j1 < c1 || j2 < c2) {
        int i10 = min(r1 + j1 + 0, last1), i11 = min(r1 + j1 + 1, last1);
        int i12 = min(r1 + j1 + 2, last1), i13 = min(r1 + j1 + 3, last1);
        int i20 = min(r2 + j2 + 0, last2), i21 = min(r2 + j2 + 1, last2);
        int i22 = min(r2 + j2 + 2, last2), i23 = min(r2 + j2 + 3, last2);
        u32 u10 = (u32)csr[i10], u11 = (u32)csr[i11];
        u32 u12 = (u32)csr[i12], u13 = (u32)csr[i13];
        u32 u20 = (u32)csr[i20], u21 = (u32)csr[i21];
        u32 u22 = (u32)csr[i22], u23 = (u32)csr[i23];
        uint2 a10 = *(const uint2*)(g32 + u10 * W2 + qo1);
        uint2 a11 = *(const uint2*)(g32 + u11 * W2 + qo1);
        uint2 a12 = *(const uint2*)(g32 + u12 * W2 + qo1);
        uint2 a13 = *(const uint2*)(g32 + u13 * W2 + qo1);
        uint2 a20 = *(const uint2*)(g32 + u20 * W2 + qo2);
        uint2 a21 = *(const uint2*)(g32 + u21 * W2 + qo2);
        uint2 a22 = *(const uint2*)(g32 + u22 * W2 + qo2);
        uint2 a23 = *(const uint2*)(g32 + u23 * W2 + qo2);
        // zero masked edges on the raw words (bf16 0x0000 == 0.0f)
        if (j1 + 0 >= c1) { a10.x = 0; a10.y = 0; }
        if (j1 + 1 >= c1) { a11.x = 0; a11.y = 0; }
        if (j1 + 2 >= c1) { a12.x = 0; a12.y = 0; }
        if (j1 + 3 >= c1) { a13.x = 0; a13.y = 0; }
        if (j2 + 0 >= c2) { a20.x = 0; a20.y = 0; }
        if (j2 + 1 >= c2) { a21.x = 0; a21.y = 0; }
        if (j2 + 2 >= c2) { a22.x = 0; a22.y = 0; }
        if (j2 + 3 >= c2) { a23.x = 0; a23.y = 0; }
        s10 += bfu2f(a10.x & 0xFFFFu) + bfu2f(a11.x & 0xFFFFu)
             + bfu2f(a12.x & 0xFFFFu) + bfu2f(a13.x & 0xFFFFu);
        s11 += bfu2f(a10.x >> 16) + bfu2f(a11.x >> 16)
             + bfu2f(a12.x >> 16) + bfu2f(a13.x >> 16);
        s12 += bfu2f(a10.y & 0xFFFFu) + bfu2f(a11.y & 0xFFFFu)
             + bfu2f(a12.y & 0xFFFFu) + bfu2f(a13.y & 0xFFFFu);
        s13 += bfu2f(a10.y >> 16) + bfu2f(a11.y >> 16)
             + bfu2f(a12.y >> 16) + bfu2f(a13.y >> 16);
        s20 += bfu2f(a20.x & 0xFFFFu) + bfu2f(a21.x & 0xFFFFu)
             + bfu2f(a22.x & 0xFFFFu) + bfu2f(a23.x & 0xFFFFu);
        s21 += bfu2f(a20.x >> 16) + bfu2f(a21.x >> 16)
             + bfu2f(a22.x >> 16) + bfu2f(a23.x >> 16);
        s22 += bfu2f(a20.y & 0xFFFFu) + bfu2f(a21.y & 0xFFFFu)
             + bfu2f(a22.y & 0xFFFFu) + bfu2f(a23.y & 0xFFFFu);
        s23 += bfu2f(a20.y >> 16) + bfu2f(a21.y >> 16)
             + bfu2f(a22.y >> 16) + bfu2f(a23.y >> 16);
        j1 += 4; j2 += 4;
    }
    float dv1 = dis[v1], dv2 = dis[v2];
    float o1[4] = {s10, s11, s12, s13};
    float o2[4] = {s20, s21, s22, s23};
    uint2 w1, w2;
    if (FINALIZE) {
        int f32m = flag[0];
        #pragma unroll
        for (int k = 0; k < 4; k++) {
            int f1 = q1 * 4 + k, f2 = q2 * 4 + k;
            float bf1 = f32m ? ((const float*)bias)[f1] : b2f(((const bf16*)bias)[f1]);
            float bf2 = f32m ? ((const float*)bias)[f2] : b2f(((const bf16*)bias)[f2]);
            o1[k] = fmaf(dv1, o1[k], bf1); o1[k] = o1[k] > 0.f ? o1[k] : 0.f;
            o2[k] = fmaf(dv2, o2[k], bf2); o2[k] = o2[k] > 0.f ? o2[k] : 0.f;
        }
    } else {
        #pragma unroll
        for (int k = 0; k < 4; k++) { o1[k] *= dv1; o2[k] *= dv2; }
    }
    w1.x = (u32)f2bfu(o1[0]) | ((u32)f2bfu(o1[1]) << 16);
    w1.y = (u32)f2bfu(o1[2]) | ((u32)f2bfu(o1[3]) << 16);
    w2.x = (u32)f2bfu(o2[0]) | ((u32)f2bfu(o2[1]) << 16);
    w2.y = (u32)f2bfu(o2[2]) | ((u32)f2bfu(o2[3]) << 16);
    u32* o32 = (u32*)out;
    *(uint2*)(o32 + (u32)v1 * W2 + qo1) = w1;
    if (e2 < totq) *(uint2*)(o32 + (u32)v2 * W2 + qo2) = w2;
}

// ---------------- CSR gather, DUAL-ROW per thread (FOUT=3 path) -------------
template <int FOUT, bool FINALIZE>
__global__ void __launch_bounds__(256) k_gather2(
        const bf16* __restrict__ g, const int* __restrict__ rowptr,
        const int* __restrict__ csr, const float* __restrict__ dis,
        const void* __restrict__ bias, bf16* __restrict__ out,
        const int* __restrict__ flag, int total, int E) {
    int H = (total + 1) >> 1;
    int i = blockIdx.x * blockDim.x + threadIdx.x;
    if (i >= H) return;
    int Em1 = E - 1;
    int e1 = i;
    int e2 = i + H;
    int e2c = (e2 < total) ? e2 : e1;
    int v1 = e1 / FOUT, f1 = e1 - v1 * FOUT;
    int v2 = e2c / FOUT, f2 = e2c - v2 * FOUT;
    float s1 = b2f(g[e1]);    // self-loop terms
    float s2 = b2f(g[e2c]);
    int r1 = rowptr[v1]; int c1 = rowptr[v1 + 1] - r1;
    int r2 = rowptr[v2]; int c2 = rowptr[v2 + 1] - r2;
    int last1 = min(r1 + (c1 > 0 ? c1 - 1 : 0), Em1);
    int last2 = min(r2 + (c2 > 0 ? c2 - 1 : 0), Em1);
    int j1 = 0, j2 = 0;
    while (j1 < c1 || j2 < c2) {
        int i10 = min(r1 + j1 + 0, last1), i11 = min(r1 + j1 + 1, last1);
        int i12 = min(r1 + j1 + 2, last1), i13 = min(r1 + j1 + 3, last1);
        int i20 = min(r2 + j2 + 0, last2), i21 = min(r2 + j2 + 1, last2);
        int i22 = min(r2 + j2 + 2, last2), i23 = min(r2 + j2 + 3, last2);
        int u10 = csr[i10], u11 = csr[i11], u12 = csr[i12], u13 = csr[i13];
        int u20 = csr[i20], u21 = csr[i21], u22 = csr[i22], u23 = csr[i23];
        float a10 = b2f(g[(size_t)u10 * FOUT + f1]);
        float a11 = b2f(g[(size_t)u11 * FOUT + f1]);
        float a12 = b2f(g[(size_t)u12 * FOUT + f1]);
        float a13 = b2f(g[(size_t)u13 * FOUT + f1]);
        float a20 = b2f(g[(size_t)u20 * FOUT + f2]);
        float a21 = b2f(g[(size_t)u21 * FOUT + f2]);
        float a22 = b2f(g[(size_t)u22 * FOUT + f2]);
        float a23 = b2f(g[(size_t)u23 * FOUT + f2]);
        s1 += ((j1 + 0 < c1 ? a10 : 0.f) + (j1 + 1 < c1 ? a11 : 0.f))
            + ((j1 + 2 < c1 ? a12 : 0.f) + (j1 + 3 < c1 ? a13 : 0.f));
        s2 += ((j2 + 0 < c2 ? a20 : 0.f) + (j2 + 1 < c2 ? a21 : 0.f))
            + ((j2 + 2 < c2 ? a22 : 0.f) + (j2 + 3 < c2 ? a23 : 0.f));
        j1 += 4; j2 += 4;
    }
    float dv1 = dis[v1], dv2 = dis[v2];
    float o1, o2;
    if (FINALIZE) {
        float bf1 = flag[0] ? ((const float*)bias)[f1] : b2f(((const bf16*)bias)[f1]);
        float bf2 = flag[0] ? ((const float*)bias)[f2] : b2f(((const bf16*)bias)[f2]);
        o1 = fmaf(dv1, s1, bf1); o1 = o1 > 0.f ? o1 : 0.f;
        o2 = fmaf(dv2, s2, bf2); o2 = o2 > 0.f ? o2 : 0.f;
    } else {
        o1 = dv1 * s1;
        o2 = dv2 * s2;
    }
    out[e1] = __float2bfloat16(o1);
    if (e2 < total) out[e2] = __float2bfloat16(o2);
}

// ---------------- final unpool gather -> out (dtype per flag) ----------------
__global__ void k_gather_out(const bf16* __restrict__ act, const int* __restrict__ idx,
                             void* __restrict__ out, const int* __restrict__ flag, int n) {
    int u = blockIdx.x * blockDim.x + threadIdx.x;
    if (u >= n) return;
    size_t r = (size_t)idx[u];
    float v0 = b2f(act[3 * r + 0]);
    float v1 = b2f(act[3 * r + 1]);
    float v2 = b2f(act[3 * r + 2]);
    if (flag[0]) {
        float* o = (float*)out;
        o[3 * (size_t)u + 0] = v0; o[3 * (size_t)u + 1] = v1; o[3 * (size_t)u + 2] = v2;
    } else {
        bf16* o = (bf16*)out;
        o[3 * (size_t)u + 0] = __float2bfloat16(v0);
        o[3 * (size_t)u + 1] = __float2bfloat16(v1);
        o[3 * (size_t)u + 2] = __float2bfloat16(v2);
    }
}

static inline int cdiv(long long a, long long b) { return (int)((a + b - 1) / b); }

extern "C" void kernel_launch(void* const* d_in, const int* in_sizes, int n_in,
                              void* d_out, int out_size, void* d_ws, size_t ws_size,
                              hipStream_t stream) {
    const void* x  = d_in[0];
    const void* W1 = d_in[1]; const void* b1 = d_in[2];
    const void* W2 = d_in[3]; const void* b2 = d_in[4];
    const void* W3 = d_in[5]; const void* b3 = d_in[6];
    const void* W4 = d_in[7]; const void* b4 = d_in[8];
    const int* e0  = (const int*)d_in[9];
    const int* up1 = (const int*)d_in[10];
    const int* e1  = (const int*)d_in[11];
    const int* up2 = (const int*)d_in[12];
    const int* e2  = (const int*)d_in[13];
    const int* up3 = (const int*)d_in[14];
    const int* e3  = (const int*)d_in[15];
    const int* up4 = (const int*)d_in[16];

    const int N0 = in_sizes[0] / 3;
    const int N1 = in_sizes[10];
    const int N2 = in_sizes[12];
    const int N3 = in_sizes[14];
    const int N4 = in_sizes[16];
    const int E0 = in_sizes[9] / 2, E1 = in_sizes[11] / 2;
    const int E2 = in_sizes[13] / 2, E3 = in_sizes[15] / 2;

    int Ns[4] = {N0, N1, N2, N3};
    int Es[4] = {E0, E1, E2, E3};
    const int* srcs[4] = {e0, e1, e2, e3};
    const int* dsts[4] = {e0 + E0, e1 + E1, e2 + E2, e3 + E3};

    // buffer element counts
    size_t gmax = (size_t)N0 * 3;
    if ((size_t)N1 * 32 > gmax) gmax = (size_t)N1 * 32;
    if ((size_t)N2 * 32 > gmax) gmax = (size_t)N2 * 32;
    if ((size_t)N3 * 3  > gmax) gmax = (size_t)N3 * 3;
    size_t amax = (size_t)N0 * 32;
    if ((size_t)N1 * 64 > amax) amax = (size_t)N1 * 64;
    if ((size_t)N2 * 32 > amax) amax = (size_t)N2 * 32;
    if ((size_t)N3 * 3  > amax) amax = (size_t)N3 * 3;
    gmax = (gmax + 7) & ~(size_t)7;
    amax = (amax + 7) & ~(size_t)7;

    Pack pk;
    char* p = (char*)d_ws;
    int* flag = (int*)p;            p += 256;
    float* wf = (float*)p;          p += WF_TOT * 4;
    int* gcur_all = (int*)p;        p += 1024 * 4;
    int* bbase_all = (int*)p;       p += 1024 * 4;

    for (int s = 0; s < 4; s++) {
        pk.s[s].src = srcs[s]; pk.s[s].dst = dsts[s];
        pk.s[s].E = Es[s]; pk.s[s].N = Ns[s];
        int nb = cdiv(Ns[s], CRANGE);
        pk.s[s].nb = nb;
        pk.s[s].nblk = cdiv(Es[s], TILE);
        pk.s[s].nbpad = (nb + 15) & ~15;
        pk.s[s].cap = (Es[s] / nb + Es[s] / (8 * nb) + 256 + 3) & ~3;  // % 4 == 0
        pk.s[s].gcur = gcur_all + s * 256;
        pk.s[s].M = (int*)p;        p += (size_t)pk.s[s].nblk * pk.s[s].nbpad * 4;
        pk.s[s].rowptr = (int*)p;   p += ((size_t)(Ns[s] + 1 + 3) & ~(size_t)3) * 4;
        pk.s[s].dis = (float*)p;    p += ((size_t)(Ns[s] + 3) & ~(size_t)3) * 4;
    }
    for (int s = 0; s < 4; s++) {
        pk.s[s].csr = (int*)p;      p += ((size_t)(Es[s] + 3) & ~(size_t)3) * 4;
    }

    // union region (16B aligned): pairs (build) aliases g|act|xt (compute)
    char* U = (char*)(((size_t)p + 15) & ~(size_t)15);
    size_t pairsBytes = 0;
    for (int s = 0; s < 4; s++) {
        pk.s[s].pairs = (u32*)(U + pairsBytes);
        pairsBytes += (size_t)pk.s[s].cap * pk.s[s].nb * 4;
    }
    bf16* g   = (bf16*)U;
    bf16* act = g + gmax;
    bf16* xt  = act + amax;

    // grids
    int ptot = 0, btot = 0;
    for (int s = 0; s < 4; s++) {
        pk.poff[s] = ptot; ptot += pk.s[s].nblk;
        pk.boff[s] = btot; btot += pk.s[s].nb;
    }

    const int B = 256;

    k_detect<<<1, 256, 0, stream>>>((const u16*)x, flag);
    k_prep_w<<<cdiv(WF_TOT, B), B, 0, stream>>>(W1, b1, W2, b2, W3, W4, wf, flag);
    k_init<<<4, 256, 0, stream>>>(gcur_all, pk);
    k_part_hist<<<ptot, B, 0, stream>>>(pk);
    k_part_scan<<<btot, B, 0, stream>>>(pk);
    k_partition<<<ptot, B, 0, stream>>>(pk);
    k_scan_bbase<<<4, B, 0, stream>>>(pk, bbase_all);
    k_build<<<btot, 512, 0, stream>>>(pk, bbase_all);

    // ---- stage 1 (agg-first): aggregate x (3 feats) -> xt1
    {
        int T = N0 * 3, Hh = (T + 1) >> 1;
        k_pre<3, true><<<cdiv(T, B), B, 0, stream>>>(
            x, nullptr, nullptr, pk.s[0].dis, g, flag, T);
        k_gather2<3, false><<<cdiv(Hh, B), B, 0, stream>>>(
            g, pk.s[0].rowptr, pk.s[0].csr, pk.s[0].dis, nullptr, xt, flag, T, E0);
    }

    // ---- fused stage1-post + stage2-pre: g2 = dis2 * relu(xt1[up1]@W1+b1)
    k_fuse_mm_pre<<<cdiv(N1, B), B, 0, stream>>>(
        xt, up1, wf, pk.s[1].dis, g, N1);

    // ---- stage 2 aggregate -> xt2
    {
        int Tq = N1 * 8, Hq = (Tq + 1) >> 1;
        k_gather2v<32, false><<<cdiv(Hq, B), B, 0, stream>>>(
            g, pk.s[1].rowptr, pk.s[1].csr, pk.s[1].dis, nullptr, xt, flag, Tq, E1);
    }

    // ---- fused stage2-post + stage3-matmul: h3 = relu(xt2@W2+b2)@W3 -> act
    k_fuse_mm2<<<cdiv(N1, B), B, 0, stream>>>(xt, wf, act, N1);

    // ---- stage 3: g3 = dis3 * h3[up2], then quad-vector aggregate -> act3
    {
        int Tq = N2 * 8, Hq = (Tq + 1) >> 1;
        k_pre<32, false><<<cdiv((long long)N2 * 32, B), B, 0, stream>>>(
            nullptr, up2, act, pk.s[2].dis, g, flag, N2 * 32);
        k_gather2v<32, true><<<cdiv(Hq, B), B, 0, stream>>>(
            g, pk.s[2].rowptr, pk.s[2].csr, pk.s[2].dis, b3, act, flag, Tq, E2);
    }

    // ---- stage 4 (W-first): h4 = act3@W4 at N2, g4 = dis4*h4[up3], aggregate
    {
        int T = N3 * 3, Hh = (T + 1) >> 1;
        k_matmul_seq<32, 3><<<cdiv(N2, B), B, 0, stream>>>(act, wf + WF_W4, xt, N2);
        k_pre<3, false><<<cdiv(T, B), B, 0, stream>>>(
            nullptr, up3, xt, pk.s[3].dis, g, flag, T);
        k_gather2<3, true><<<cdiv(Hh, B), B, 0, stream>>>(
            g, pk.s[3].rowptr, pk.s[3].csr, pk.s[3].dis, b4, act, flag, T, E3);
    }

    // ---- final unpool
    k_gather_out<<<cdiv(N4, B), B, 0, stream>>>(act, up4, d_out, flag, N4);
}

// Round 13
// 438.415 us; speedup vs baseline: 1.1478x; 1.0607x over previous
//
#include <hip/hip_runtime.h>
#include <hip/hip_bf16.h>

typedef __hip_bfloat16 bf16;
typedef unsigned short u16;
typedef unsigned char u8;
typedef unsigned int u32;
typedef __attribute__((ext_vector_type(8))) unsigned short us8;
typedef __attribute__((ext_vector_type(8))) short short8;
typedef __attribute__((ext_vector_type(4))) float f32x4;

static __device__ __forceinline__ float b2f(bf16 v) { return __bfloat162float(v); }
static __device__ __forceinline__ float bfu2f(u32 u) {
    union { u32 i; float f; } c; c.i = u << 16; return c.f;
}
static __device__ __forceinline__ u16 f2bfu(float f) {
    u32 x = __float_as_uint(f);
    return (u16)((x + 0x7FFFu + ((x >> 16) & 1u)) >> 16);
}

#define TILE 4096        // edges per partition block
#define CBITS 12         // coarse bucket = 4096-vertex range (all stages)
#define CRANGE 4096
#define OUTB 26624       // build staging capacity (tot ~24.5K + >8 sigma); 104 KB
// f32 weight scratch layout (floats)
#define WF_W1 0
#define WF_B1 128
#define WF_W2 192
#define WF_B2 2240
#define WF_W3 2304
#define WF_W4 4352
#define WF_TOT 4608
#define NFRAG 4096       // u16 MFMA fragment entries after wf
#define RPT16(M) M(0) M(1) M(2) M(3) M(4) M(5) M(6) M(7) \
                 M(8) M(9) M(10) M(11) M(12) M(13) M(14) M(15)

struct SP {
    const int* src; const int* dst;
    int E, N, cap, nb, nblk, nbpad;
    int* gcur;      // [nb] per-bucket totals (written by k_part_scan)
    u32* pairs;     // [nb][cap] packed (local_dst12 << 20) | src20
    int* M;         // [nblk][nbpad] counts -> exclusive bases
    int* rowptr; float* dis; int* csr;
};
struct Pack {
    SP s[4];
    int poff[4];  // tile-grid start offset per stage
    int boff[4];  // bucket-grid start offset per stage
};

// ---------------- dtype detection ----------------
__global__ void k_detect(const u16* __restrict__ xraw, int* __restrict__ flag) {
    __shared__ int s;
    if (threadIdx.x == 0) s = 0;
    __syncthreads();
    u16 u = xraw[threadIdx.x];
    int e = (u >> 7) & 0xFF;
    if (e >= 0x8F) atomicAdd(&s, 1);
    __syncthreads();
    if (threadIdx.x == 0) flag[0] = (s > 0) ? 1 : 0;
}

// ---------------- one-time weight conversion: f32 scratch + MFMA fragments --
// wfrag layout (u16 bf16):
//   [0..2048)  W2 frags: sec t4=0..3:  [t4][l][i] = W2[8*(l>>4)+i][16*t4+(l&15)]
//   [2048..4096) W3 frags: q=kt*2+t2:  [q][l][i]  = W3[32*kt+8*(l>>4)+i][16*t2+(l&15)]
__global__ void k_prep_w(const void* W1, const void* b1, const void* W2,
                         const void* b2, const void* W3, const void* W4,
                         float* __restrict__ wf, u16* __restrict__ wfrag,
                         const int* __restrict__ flag) {
    int t = blockIdx.x * 256 + threadIdx.x;
    int f32m = flag[0];
    if (t < WF_TOT) {
        const void* src; int off; int len;
        if      (t < WF_B1)  { src = W1; off = t - WF_W1; len = 96;  }
        else if (t < WF_W2)  { src = b1; off = t - WF_B1; len = 32;  }
        else if (t < WF_B2)  { src = W2; off = t - WF_W2; len = 2048;}
        else if (t < WF_W3)  { src = b2; off = t - WF_B2; len = 64;  }
        else if (t < WF_W4)  { src = W3; off = t - WF_W3; len = 2048;}
        else                 { src = W4; off = t - WF_W4; len = 96;  }
        if (off >= len) return;
        wf[t] = f32m ? ((const float*)src)[off] : b2f(((const bf16*)src)[off]);
    } else if (t < WF_TOT + NFRAG) {
        int idx = t - WF_TOT;
        int sec = idx >> 9;        // 0..7
        int l = (idx >> 3) & 63;
        int i = idx & 7;
        int cl = l & 15, grp = l >> 4;
        float val;
        if (sec < 4) {             // W2 [32][64]
            int k = grp * 8 + i, col = sec * 16 + cl;
            val = f32m ? ((const float*)W2)[k * 64 + col]
                       : b2f(((const bf16*)W2)[k * 64 + col]);
        } else {                   // W3 [64][32]
            int q = sec - 4, kt = q >> 1, t2 = q & 1;
            int k = kt * 32 + grp * 8 + i, col = t2 * 16 + cl;
            val = f32m ? ((const float*)W3)[k * 32 + col]
                       : b2f(((const bf16*)W3)[k * 32 + col]);
        }
        wfrag[idx] = f2bfu(val);
    }
}

// zero gcur (4 x 256) + rowptr sentinels
__global__ void k_init(int* __restrict__ gcur_all, Pack pk) {
    int i = blockIdx.x * blockDim.x + threadIdx.x;
    if (i < 1024) gcur_all[i] = 0;
    if (i < 4) pk.s[i].rowptr[pk.s[i].N] = pk.s[i].E;
}

// ---------------- pass A0: per-tile bucket counts -> M[tile][bucket] ----------
__global__ void __launch_bounds__(256) k_part_hist(Pack pk) {
    __shared__ int hist[256];
    int bid = blockIdx.x;
    int si = (bid >= pk.poff[3]) ? 3 : (bid >= pk.poff[2]) ? 2 : (bid >= pk.poff[1]) ? 1 : 0;
    const SP sp = pk.s[si];
    int lb = bid - pk.poff[si];
    int t = threadIdx.x;
    int n = min(TILE, sp.E - lb * TILE);
    const int* dstp = sp.dst + lb * TILE;

#define LOADK(k) int d##k; { int i = t + 256*(k); d##k = (i < n) ? dstp[i] : -1; }
    RPT16(LOADK)
#undef LOADK
    hist[t] = 0;
    __syncthreads();
#define HISTK(k) if (d##k >= 0) atomicAdd(&hist[d##k >> CBITS], 1);
    RPT16(HISTK)
#undef HISTK
    __syncthreads();
    int* Mrow = sp.M + (size_t)lb * sp.nbpad;
    for (int b = t; b < sp.nb; b += 256) Mrow[b] = hist[b];
}

// ---------------- pass A-scan: per-bucket column scan of M (in place) --------
__global__ void __launch_bounds__(256) k_part_scan(Pack pk) {
    __shared__ int buf[256];
    int bid = blockIdx.x;
    int si = (bid >= pk.boff[3]) ? 3 : (bid >= pk.boff[2]) ? 2 : (bid >= pk.boff[1]) ? 1 : 0;
    const SP sp = pk.s[si];
    int b = bid - pk.boff[si];
    int t = threadIdx.x;
    int nblk = sp.nblk, nbpad = sp.nbpad;
    int* M = sp.M;
    int carry = 0;
    for (int base = 0; base < nblk; base += 256) {
        int m = min(256, nblk - base);
        int v = (t < m) ? M[(size_t)(base + t) * nbpad + b] : 0;
        buf[t] = v;
        __syncthreads();
        for (int off = 1; off < 256; off <<= 1) {
            int w = (t >= off) ? buf[t - off] : 0;
            __syncthreads();
            buf[t] += w;
            __syncthreads();
        }
        int excl = buf[t] - v + carry;
        int ctot = buf[255];
        __syncthreads();
        if (t < m) M[(size_t)(base + t) * nbpad + b] = excl;
        carry += ctot;
    }
    if (t == 0) sp.gcur[b] = carry;
}

// ---------------- pass A1: scatter to pairs at deterministic bases -----------
__global__ void __launch_bounds__(256) k_partition(Pack pk) {
    __shared__ u32 stage[TILE];   // 16 KB
    __shared__ u8  bkt[TILE];     //  4 KB
    __shared__ int hist[256];
    __shared__ int gofs[256];
    __shared__ int tmp[256];

    int bid = blockIdx.x;
    int si = (bid >= pk.poff[3]) ? 3 : (bid >= pk.poff[2]) ? 2 : (bid >= pk.poff[1]) ? 1 : 0;
    const SP sp = pk.s[si];
    int lb = bid - pk.poff[si];
    int t = threadIdx.x;
    int n = min(TILE, sp.E - lb * TILE);
    const int* dstp = sp.dst + lb * TILE;
    const int* srcp = sp.src + lb * TILE;

#define LOADK(k) int d##k, s##k; { int i = t + 256*(k); \
    if (i < n) { d##k = dstp[i]; s##k = srcp[i]; } else { d##k = -1; s##k = 0; } }
    RPT16(LOADK)
#undef LOADK

    hist[t] = 0;
    __syncthreads();
#define HISTK(k) if (d##k >= 0) atomicAdd(&hist[d##k >> CBITS], 1);
    RPT16(HISTK)
#undef HISTK
    __syncthreads();

    int h = hist[t];
    tmp[t] = h; __syncthreads();
    for (int off = 1; off < 256; off <<= 1) {
        int v = (t >= off) ? tmp[t - off] : 0;
        __syncthreads();
        tmp[t] += v;
        __syncthreads();
    }
    int lofs = tmp[t] - h;
    int gb = (t < sp.nb) ? sp.M[(size_t)lb * sp.nbpad + t] : 0;  // scanned base
    gofs[t] = gb - lofs;
    hist[t] = lofs;   // scatter cursor
    __syncthreads();

#define SCATK(k) if (d##k >= 0) { int b = d##k >> CBITS; \
    int pos = atomicAdd(&hist[b], 1); \
    stage[pos] = (((u32)d##k & 4095u) << 20) | (u32)s##k; \
    bkt[pos] = (u8)b; }
    RPT16(SCATK)
#undef SCATK
    __syncthreads();

    int cap = sp.cap;
    u32* pairs = sp.pairs;
    for (int i = t; i < n; i += 256) {
        int b = bkt[i];
        pairs[(size_t)b * cap + gofs[b] + i] = stage[i];
    }
}

// ---------------- bucket-base scan (one block per stage) ----------------
__global__ void k_scan_bbase(Pack pk, int* __restrict__ bbase_all) {
    __shared__ int tmp[256];
    int si = blockIdx.x;
    int t = threadIdx.x;
    int nb = pk.s[si].nb;
    int v = (t < nb) ? pk.s[si].gcur[t] : 0;
    tmp[t] = v; __syncthreads();
    for (int off = 1; off < 256; off <<= 1) {
        int w = (t >= off) ? tmp[t - off] : 0;
        __syncthreads();
        tmp[t] += w;
        __syncthreads();
    }
    bbase_all[si * 256 + t] = tmp[t] - v;
}

// ---------------- build: one block per coarse bucket, 3 passes --------------
__global__ void __launch_bounds__(512) k_build(Pack pk, const int* __restrict__ bbase_all) {
    __shared__ int hist[4096];    //  16 KB: counts -> local offsets -> cursor
    __shared__ int outb[OUTB];    // 104 KB staged csr for the whole bucket
    __shared__ int tmp[512];

    int bid = blockIdx.x;
    int si = (bid >= pk.boff[3]) ? 3 : (bid >= pk.boff[2]) ? 2 : (bid >= pk.boff[1]) ? 1 : 0;
    const SP sp = pk.s[si];
    int b = bid - pk.boff[si];
    int t = threadIdx.x;

    int bbase = bbase_all[si * 256 + b];
    int tot = sp.gcur[b];
    const u32* p = sp.pairs + (size_t)b * sp.cap;   // 16B aligned (cap % 4 == 0)
    const uint4* p4 = (const uint4*)p;
    int tot4 = tot >> 2;

    for (int i = t; i < 4096; i += 512) hist[i] = 0;
    __syncthreads();
    for (int i = t; i < tot4; i += 512) {
        uint4 u = p4[i];
        atomicAdd(&hist[u.x >> 20], 1);
        atomicAdd(&hist[u.y >> 20], 1);
        atomicAdd(&hist[u.z >> 20], 1);
        atomicAdd(&hist[u.w >> 20], 1);
    }
    for (int i = (tot4 << 2) + t; i < tot; i += 512)
        atomicAdd(&hist[p[i] >> 20], 1);
    __syncthreads();

    // in-place exclusive scan of 4096 bins; counts in registers (8/thread)
    int lbase = t * 8;
    int cnt[8], cof[8];
    #pragma unroll
    for (int k = 0; k < 8; k++) cnt[k] = hist[lbase + k];
    int s = 0;
    #pragma unroll
    for (int k = 0; k < 8; k++) { cof[k] = s; s += cnt[k]; }
    tmp[t] = s; __syncthreads();
    for (int off = 1; off < 512; off <<= 1) {
        int v = (t >= off) ? tmp[t - off] : 0;
        __syncthreads();
        tmp[t] += v;
        __syncthreads();
    }
    int tb = tmp[t] - s;

    int nbase = b << CBITS;
    #pragma unroll
    for (int k = 0; k < 8; k++) {
        int bin = lbase + k;
        hist[bin] = tb + cof[k];          // bucket-local offset (-> cursor)
        int v = nbase + bin;
        if (v < sp.N) {
            sp.rowptr[v] = bbase + tb + cof[k];
            sp.dis[v] = rsqrtf((float)(cnt[k] + 1));
        }
    }
    __syncthreads();

    if (tot <= OUTB) {
        for (int i = t; i < tot4; i += 512) {
            uint4 u = p4[i];
            int pos;
            pos = atomicAdd(&hist[u.x >> 20], 1); outb[pos] = (int)(u.x & 0xFFFFFu);
            pos = atomicAdd(&hist[u.y >> 20], 1); outb[pos] = (int)(u.y & 0xFFFFFu);
            pos = atomicAdd(&hist[u.z >> 20], 1); outb[pos] = (int)(u.z & 0xFFFFFu);
            pos = atomicAdd(&hist[u.w >> 20], 1); outb[pos] = (int)(u.w & 0xFFFFFu);
        }
        for (int i = (tot4 << 2) + t; i < tot; i += 512) {
            u32 u = p[i];
            int pos = atomicAdd(&hist[u >> 20], 1);
            outb[pos] = (int)(u & 0xFFFFFu);
        }
        __syncthreads();
        for (int i = t; i < tot; i += 512)
            sp.csr[bbase + i] = outb[i];
    } else {  // statistical overflow fallback: direct global scatter
        for (int i = t; i < tot; i += 512) {
            u32 u = p[i];
            int pos = atomicAdd(&hist[u >> 20], 1);
            sp.csr[bbase + pos] = (int)(u & 0xFFFFFu);
        }
    }
}

// ---------------- pre-scale: g[v,f] = dis[v] * x_in[row(v), f] ----------------
template <int F, bool EXT>
__global__ void k_pre(const void* __restrict__ xin, const int* __restrict__ gidx,
                      const bf16* __restrict__ actin, const float* __restrict__ dis,
                      bf16* __restrict__ g, const int* __restrict__ flag, int total) {
    int i = blockIdx.x * blockDim.x + threadIdx.x;
    if (i >= total) return;
    int v = i / F;
    int f = i - v * F;
    float x;
    if (EXT) {
        if (flag[0]) x = ((const float*)xin)[i];
        else         x = b2f(((const bf16*)xin)[i]);
    } else {
        int row = gidx[v];
        x = b2f(actin[(size_t)row * F + f]);
    }
    g[i] = __float2bfloat16(dis[v] * x);
}

// ---------------- fused stage1-post + stage2-pre ----------------------------
// g2[v] = dis2[v] * relu(xt1[up1[v]] @ W1 + b1).
__global__ void __launch_bounds__(256, 1) k_fuse_mm_pre(
        const bf16* __restrict__ xt1, const int* __restrict__ up,
        const float* __restrict__ wf, const float* __restrict__ dis,
        bf16* __restrict__ g, int n) {
    const float* W = wf + WF_W1;
    const float* B = wf + WF_B1;
    int v = blockIdx.x * 256 + threadIdx.x;
    if (v >= n) return;
    int r = up[v];
    float x0 = b2f(xt1[(size_t)r * 3 + 0]);
    float x1 = b2f(xt1[(size_t)r * 3 + 1]);
    float x2 = b2f(xt1[(size_t)r * 3 + 2]);
    float dv = dis[v];
    #pragma unroll
    for (int f8 = 0; f8 < 4; f8++) {
        us8 ov;
        #pragma unroll
        for (int j = 0; j < 8; j++) {
            int f = f8 * 8 + j;
            float y = B[f];
            y = fmaf(x0, W[f], y);
            y = fmaf(x1, W[32 + f], y);
            y = fmaf(x2, W[64 + f], y);
            y = y > 0.f ? y : 0.f;
            ov[j] = f2bfu(dv * y);
        }
        *(us8*)(g + (size_t)v * 32 + f8 * 8) = ov;
    }
}

// ---------------- fused stage2-post + stage3-matmul, MFMA -------------------
// h3[v] = relu(xt2[v] @ W2 + b2) @ W3 via mfma_f32_16x16x32_bf16.
// One wave = 16 rows. Fragment layouts (m92/m97-verified family):
//   A: lane l holds A[l&15][8*(l>>4)+i];  B: B[8*(l>>4)+i][l&15]
//   D: reg r -> D[4*(l>>4)+r][l&15]
// Y routed through per-wave LDS tile (same-wave ordering, no barriers);
// H through LDS for a fully coalesced us8 store.
__global__ void __launch_bounds__(256) k_fuse_mm2(
        const bf16* __restrict__ xt2, const u16* __restrict__ wfrag,
        const float* __restrict__ wf, bf16* __restrict__ h, int n) {
    __shared__ u16 Ys[4][16 * 72];   // per-wave Y[16][64], row pad 72 (9,216 B)
    __shared__ u16 Hs[4][16 * 32];   // per-wave H[16][32] flat   (4,096 B)
    const float* B2f = wf + WF_B2;
    int t = threadIdx.x;
    int w = t >> 6, l = t & 63;
    int cl = l & 15, grp = l >> 4;
    int v0 = blockIdx.x * 64 + w * 16;
    if (v0 >= n) return;              // whole-wave early out (no barriers used)
    int ar = v0 + cl; ar = ar < n ? ar : n - 1;
    short8 a1 = *(const short8*)(xt2 + (size_t)ar * 32 + grp * 8);
    const short8* wf2 = (const short8*)wfrag;          // [t4][l]
    const short8* wf3 = (const short8*)(wfrag + 2048); // [kt*2+t2][l]
    u16* Y = Ys[w];
    u16* H = Hs[w];
    #pragma unroll
    for (int t4 = 0; t4 < 4; t4++) {
        f32x4 acc = {0.f, 0.f, 0.f, 0.f};
        acc = __builtin_amdgcn_mfma_f32_16x16x32_bf16(a1, wf2[t4 * 64 + l], acc, 0, 0, 0);
        float bias = B2f[t4 * 16 + cl];
        #pragma unroll
        for (int r = 0; r < 4; r++) {
            float y = acc[r] + bias;
            y = y > 0.f ? y : 0.f;
            Y[(4 * grp + r) * 72 + t4 * 16 + cl] = f2bfu(y);
        }
    }
    // GEMM2 A-fragments from Y (16B aligned: cl*144 + {0,64} + grp*16 bytes)
    short8 a20 = *(const short8*)(Y + cl * 72 + grp * 8);
    short8 a21 = *(const short8*)(Y + cl * 72 + 32 + grp * 8);
    #pragma unroll
    for (int t2 = 0; t2 < 2; t2++) {
        f32x4 acc = {0.f, 0.f, 0.f, 0.f};
        acc = __builtin_amdgcn_mfma_f32_16x16x32_bf16(a20, wf3[t2 * 64 + l], acc, 0, 0, 0);
        acc = __builtin_amdgcn_mfma_f32_16x16x32_bf16(a21, wf3[(2 + t2) * 64 + l], acc, 0, 0, 0);
        #pragma unroll
        for (int r = 0; r < 4; r++)
            H[(4 * grp + r) * 32 + t2 * 16 + cl] = f2bfu(acc[r]);
    }
    int orow = v0 + (l >> 2);
    if (orow < n)
        *(us8*)(h + (size_t)orow * 32 + (l & 3) * 8) = *(const us8*)(H + l * 8);
}

// ---------------- streaming matmul: h[v,:] = actin[v,:] @ W  (f32 weights) ---
template <int FIN, int FOUT>
__global__ void __launch_bounds__(256, 1) k_matmul_seq(
        const bf16* __restrict__ actin, const float* __restrict__ W,
        bf16* __restrict__ h, int n) {
    int v = blockIdx.x * blockDim.x + threadIdx.x;
    if (v >= n) return;
    float y[FOUT];
    #pragma unroll
    for (int f = 0; f < FOUT; f++) y[f] = 0.f;
    #pragma unroll
    for (int k8 = 0; k8 < FIN / 8; k8++) {
        us8 xv = *(const us8*)(actin + (size_t)v * FIN + k8 * 8);
        #pragma unroll
        for (int j = 0; j < 8; j++) {
            float xk = bfu2f((u32)(u16)xv[j]);
            const float* wrow = &W[(k8 * 8 + j) * FOUT];
            #pragma unroll
            for (int f = 0; f < FOUT; f++) y[f] = fmaf(xk, wrow[f], y[f]);
        }
    }
    if constexpr (FOUT % 8 == 0) {
        #pragma unroll
        for (int f8 = 0; f8 < FOUT / 8; f8++) {
            us8 ov;
            #pragma unroll
            for (int j = 0; j < 8; j++) ov[j] = f2bfu(y[f8 * 8 + j]);
            *(us8*)(h + (size_t)v * FOUT + f8 * 8) = ov;
        }
    } else {
        #pragma unroll
        for (int f = 0; f < FOUT; f++)
            h[(size_t)v * FOUT + f] = __float2bfloat16(y[f]);
    }
}

// ---------------- CSR gather, QUAD-FEATURE x DUAL-ROW (FOUT%4==0) ----------
template <int FOUT, bool FINALIZE>
__global__ void __launch_bounds__(256) k_gather2v(
        const bf16* __restrict__ g, const int* __restrict__ rowptr,
        const int* __restrict__ csr, const float* __restrict__ dis,
        const void* __restrict__ bias, bf16* __restrict__ out,
        const int* __restrict__ flag, int totq, int E) {
    constexpr int Q = FOUT / 4;         // quads per row
    constexpr u32 W2 = FOUT / 2;        // u32 words per row
    int H = (totq + 1) >> 1;
    int i = blockIdx.x * blockDim.x + threadIdx.x;
    if (i >= H) return;
    int Em1 = E - 1;
    int e1 = i;
    int e2 = i + H;
    int e2c = (e2 < totq) ? e2 : e1;
    int v1 = e1 / Q, q1 = e1 - v1 * Q;
    int v2 = e2c / Q, q2 = e2c - v2 * Q;
    u32 qo1 = (u32)(q1 * 2), qo2 = (u32)(q2 * 2);
    const u32* g32 = (const u32*)g;

    uint2 sv1 = *(const uint2*)(g32 + (u32)v1 * W2 + qo1);
    uint2 sv2 = *(const uint2*)(g32 + (u32)v2 * W2 + qo2);
    float s10 = bfu2f(sv1.x & 0xFFFFu), s11 = bfu2f(sv1.x >> 16);
    float s12 = bfu2f(sv1.y & 0xFFFFu), s13 = bfu2f(sv1.y >> 16);
    float s20 = bfu2f(sv2.x & 0xFFFFu), s21 = bfu2f(sv2.x >> 16);
    float s22 = bfu2f(sv2.y & 0xFFFFu), s23 = bfu2f(sv2.y >> 16);

    int r1 = rowptr[v1]; int c1 = rowptr[v1 + 1] - r1;
    int r2 = rowptr[v2]; int c2 = rowptr[v2 + 1] - r2;
    int last1 = min(r1 + (c1 > 0 ? c1 - 1 : 0), Em1);
    int last2 = min(r2 + (c2 > 0 ? c2 - 1 : 0), Em1);
    int j1 = 0, j2 = 0;
    while (j1 < c1 || j2 < c2) {
        int i10 = min(r1 + j1 + 0, last1), i11 = min(r1 + j1 + 1, last1);
        int i12 = min(r1 + j1 + 2, last1), i13 = min(r1 + j1 + 3, last1);
        int i20 = min(r2 + j2 + 0, last2), i21 = min(r2 + j2 + 1, last2);
        int i22 = min(r2 + j2 + 2, last2), i23 = min(r2 + j2 + 3, last2);
        u32 u10 = (u32)csr[i10], u11 = (u32)csr[i11];
        u32 u12 = (u32)csr[i12], u13 = (u32)csr[i13];
        u32 u20 = (u32)csr[i20], u21 = (u32)csr[i21];
        u32 u22 = (u32)csr[i22], u23 = (u32)csr[i23];
        uint2 a10 = *(const uint2*)(g32 + u10 * W2 + qo1);
        uint2 a11 = *(const uint2*)(g32 + u11 * W2 + qo1);
        uint2 a12 = *(const uint2*)(g32 + u12 * W2 + qo1);
        uint2 a13 = *(const uint2*)(g32 + u13 * W2 + qo1);
        uint2 a20 = *(const uint2*)(g32 + u20 * W2 + qo2);
        uint2 a21 = *(const uint2*)(g32 + u21 * W2 + qo2);
        uint2 a22 = *(const uint2*)(g32 + u22 * W2 + qo2);
        uint2 a23 = *(const uint2*)(g32 + u23 * W2 + qo2);
        // zero masked edges on the raw words (bf16 0x0000 == 0.0f)
        if (j1 + 0 >= c1) { a10.x = 0; a10.y = 0; }
        if (j1 + 1 >= c1) { a11.x = 0; a11.y = 0; }
        if (j1 + 2 >= c1) { a12.x = 0; a12.y = 0; }
        if (j1 + 3 >= c1) { a13.x = 0; a13.y = 0; }
        if (j2 + 0 >= c2) { a20.x = 0; a20.y = 0; }
        if (j2 + 1 >= c2) { a21.x = 0; a21.y = 0; }
        if (j2 + 2 >= c2) { a22.x = 0; a22.y = 0; }
        if (j2 + 3 >= c2) { a23.x = 0; a23.y = 0; }
        s10 += bfu2f(a10.x & 0xFFFFu) + bfu2f(a11.x & 0xFFFFu)
             + bfu2f(a12.x & 0xFFFFu) + bfu2f(a13.x & 0xFFFFu);
        s11 += bfu2f(a10.x >> 16) + bfu2f(a11.x >> 16)
             + bfu2f(a12.x >> 16) + bfu2f(a13.x >> 16);
        s12 += bfu2f(a10.y & 0xFFFFu) + bfu2f(a11.y & 0xFFFFu)
             + bfu2f(a12.y & 0xFFFFu) + bfu2f(a13.y & 0xFFFFu);
        s13 += bfu2f(a10.y >> 16) + bfu2f(a11.y >> 16)
             + bfu2f(a12.y >> 16) + bfu2f(a13.y >> 16);
        s20 += bfu2f(a20.x & 0xFFFFu) + bfu2f(a21.x & 0xFFFFu)
             + bfu2f(a22.x & 0xFFFFu) + bfu2f(a23.x & 0xFFFFu);
        s21 += bfu2f(a20.x >> 16) + bfu2f(a21.x >> 16)
             + bfu2f(a22.x >> 16) + bfu2f(a23.x >> 16);
        s22 += bfu2f(a20.y & 0xFFFFu) + bfu2f(a21.y & 0xFFFFu)
             + bfu2f(a22.y & 0xFFFFu) + bfu2f(a23.y & 0xFFFFu);
        s23 += bfu2f(a20.y >> 16) + bfu2f(a21.y >> 16)
             + bfu2f(a22.y >> 16) + bfu2f(a23.y >> 16);
        j1 += 4; j2 += 4;
    }
    float dv1 = dis[v1], dv2 = dis[v2];
    float o1[4] = {s10, s11, s12, s13};
    float o2[4] = {s20, s21, s22, s23};
    uint2 w1, w2;
    if (FINALIZE) {
        int f32m = flag[0];
        #pragma unroll
        for (int k = 0; k < 4; k++) {
            int f1 = q1 * 4 + k, f2 = q2 * 4 + k;
            float bf1 = f32m ? ((const float*)bias)[f1] : b2f(((const bf16*)bias)[f1]);
            float bf2 = f32m ? ((const float*)bias)[f2] : b2f(((const bf16*)bias)[f2]);
            o1[k] = fmaf(dv1, o1[k], bf1); o1[k] = o1[k] > 0.f ? o1[k] : 0.f;
            o2[k] = fmaf(dv2, o2[k], bf2); o2[k] = o2[k] > 0.f ? o2[k] : 0.f;
        }
    } else {
        #pragma unroll
        for (int k = 0; k < 4; k++) { o1[k] *= dv1; o2[k] *= dv2; }
    }
    w1.x = (u32)f2bfu(o1[0]) | ((u32)f2bfu(o1[1]) << 16);
    w1.y = (u32)f2bfu(o1[2]) | ((u32)f2bfu(o1[3]) << 16);
    w2.x = (u32)f2bfu(o2[0]) | ((u32)f2bfu(o2[1]) << 16);
    w2.y = (u32)f2bfu(o2[2]) | ((u32)f2bfu(o2[3]) << 16);
    u32* o32 = (u32*)out;
    *(uint2*)(o32 + (u32)v1 * W2 + qo1) = w1;
    if (e2 < totq) *(uint2*)(o32 + (u32)v2 * W2 + qo2) = w2;
}

// ---------------- CSR gather, DUAL-ROW per thread (FOUT=3 path) -------------
template <int FOUT, bool FINALIZE>
__global__ void __launch_bounds__(256) k_gather2(
        const bf16* __restrict__ g, const int* __restrict__ rowptr,
        const int* __restrict__ csr, const float* __restrict__ dis,
        const void* __restrict__ bias, bf16* __restrict__ out,
        const int* __restrict__ flag, int total, int E) {
    int H = (total + 1) >> 1;
    int i = blockIdx.x * blockDim.x + threadIdx.x;
    if (i >= H) return;
    int Em1 = E - 1;
    int e1 = i;
    int e2 = i + H;
    int e2c = (e2 < total) ? e2 : e1;
    int v1 = e1 / FOUT, f1 = e1 - v1 * FOUT;
    int v2 = e2c / FOUT, f2 = e2c - v2 * FOUT;
    float s1 = b2f(g[e1]);    // self-loop terms
    float s2 = b2f(g[e2c]);
    int r1 = rowptr[v1]; int c1 = rowptr[v1 + 1] - r1;
    int r2 = rowptr[v2]; int c2 = rowptr[v2 + 1] - r2;
    int last1 = min(r1 + (c1 > 0 ? c1 - 1 : 0), Em1);
    int last2 = min(r2 + (c2 > 0 ? c2 - 1 : 0), Em1);
    int j1 = 0, j2 = 0;
    while (j1 < c1 || j2 < c2) {
        int i10 = min(r1 + j1 + 0, last1), i11 = min(r1 + j1 + 1, last1);
        int i12 = min(r1 + j1 + 2, last1), i13 = min(r1 + j1 + 3, last1);
        int i20 = min(r2 + j2 + 0, last2), i21 = min(r2 + j2 + 1, last2);
        int i22 = min(r2 + j2 + 2, last2), i23 = min(r2 + j2 + 3, last2);
        int u10 = csr[i10], u11 = csr[i11], u12 = csr[i12], u13 = csr[i13];
        int u20 = csr[i20], u21 = csr[i21], u22 = csr[i22], u23 = csr[i23];
        float a10 = b2f(g[(size_t)u10 * FOUT + f1]);
        float a11 = b2f(g[(size_t)u11 * FOUT + f1]);
        float a12 = b2f(g[(size_t)u12 * FOUT + f1]);
        float a13 = b2f(g[(size_t)u13 * FOUT + f1]);
        float a20 = b2f(g[(size_t)u20 * FOUT + f2]);
        float a21 = b2f(g[(size_t)u21 * FOUT + f2]);
        float a22 = b2f(g[(size_t)u22 * FOUT + f2]);
        float a23 = b2f(g[(size_t)u23 * FOUT + f2]);
        s1 += ((j1 + 0 < c1 ? a10 : 0.f) + (j1 + 1 < c1 ? a11 : 0.f))
            + ((j1 + 2 < c1 ? a12 : 0.f) + (j1 + 3 < c1 ? a13 : 0.f));
        s2 += ((j2 + 0 < c2 ? a20 : 0.f) + (j2 + 1 < c2 ? a21 : 0.f))
            + ((j2 + 2 < c2 ? a22 : 0.f) + (j2 + 3 < c2 ? a23 : 0.f));
        j1 += 4; j2 += 4;
    }
    float dv1 = dis[v1], dv2 = dis[v2];
    float o1, o2;
    if (FINALIZE) {
        float bf1 = flag[0] ? ((const float*)bias)[f1] : b2f(((const bf16*)bias)[f1]);
        float bf2 = flag[0] ? ((const float*)bias)[f2] : b2f(((const bf16*)bias)[f2]);
        o1 = fmaf(dv1, s1, bf1); o1 = o1 > 0.f ? o1 : 0.f;
        o2 = fmaf(dv2, s2, bf2); o2 = o2 > 0.f ? o2 : 0.f;
    } else {
        o1 = dv1 * s1;
        o2 = dv2 * s2;
    }
    out[e1] = __float2bfloat16(o1);
    if (e2 < total) out[e2] = __float2bfloat16(o2);
}

// ---------------- final unpool gather -> out (dtype per flag) ----------------
__global__ void k_gather_out(const bf16* __restrict__ act, const int* __restrict__ idx,
                             void* __restrict__ out, const int* __restrict__ flag, int n) {
    int u = blockIdx.x * blockDim.x + threadIdx.x;
    if (u >= n) return;
    size_t r = (size_t)idx[u];
    float v0 = b2f(act[3 * r + 0]);
    float v1 = b2f(act[3 * r + 1]);
    float v2 = b2f(act[3 * r + 2]);
    if (flag[0]) {
        float* o = (float*)out;
        o[3 * (size_t)u + 0] = v0; o[3 * (size_t)u + 1] = v1; o[3 * (size_t)u + 2] = v2;
    } else {
        bf16* o = (bf16*)out;
        o[3 * (size_t)u + 0] = __float2bfloat16(v0);
        o[3 * (size_t)u + 1] = __float2bfloat16(v1);
        o[3 * (size_t)u + 2] = __float2bfloat16(v2);
    }
}

static inline int cdiv(long long a, long long b) { return (int)((a + b - 1) / b); }

extern "C" void kernel_launch(void* const* d_in, const int* in_sizes, int n_in,
                              void* d_out, int out_size, void* d_ws, size_t ws_size,
                              hipStream_t stream) {
    const void* x  = d_in[0];
    const void* W1 = d_in[1]; const void* b1 = d_in[2];
    const void* W2 = d_in[3]; const void* b2 = d_in[4];
    const void* W3 = d_in[5]; const void* b3 = d_in[6];
    const void* W4 = d_in[7]; const void* b4 = d_in[8];
    const int* e0  = (const int*)d_in[9];
    const int* up1 = (const int*)d_in[10];
    const int* e1  = (const int*)d_in[11];
    const int* up2 = (const int*)d_in[12];
    const int* e2  = (const int*)d_in[13];
    const int* up3 = (const int*)d_in[14];
    const int* e3  = (const int*)d_in[15];
    const int* up4 = (const int*)d_in[16];

    const int N0 = in_sizes[0] / 3;
    const int N1 = in_sizes[10];
    const int N2 = in_sizes[12];
    const int N3 = in_sizes[14];
    const int N4 = in_sizes[16];
    const int E0 = in_sizes[9] / 2, E1 = in_sizes[11] / 2;
    const int E2 = in_sizes[13] / 2, E3 = in_sizes[15] / 2;

    int Ns[4] = {N0, N1, N2, N3};
    int Es[4] = {E0, E1, E2, E3};
    const int* srcs[4] = {e0, e1, e2, e3};
    const int* dsts[4] = {e0 + E0, e1 + E1, e2 + E2, e3 + E3};

    // buffer element counts
    size_t gmax = (size_t)N0 * 3;
    if ((size_t)N1 * 32 > gmax) gmax = (size_t)N1 * 32;
    if ((size_t)N2 * 32 > gmax) gmax = (size_t)N2 * 32;
    if ((size_t)N3 * 3  > gmax) gmax = (size_t)N3 * 3;
    size_t amax = (size_t)N0 * 32;
    if ((size_t)N1 * 64 > amax) amax = (size_t)N1 * 64;
    if ((size_t)N2 * 32 > amax) amax = (size_t)N2 * 32;
    if ((size_t)N3 * 3  > amax) amax = (size_t)N3 * 3;
    gmax = (gmax + 7) & ~(size_t)7;
    amax = (amax + 7) & ~(size_t)7;

    Pack pk;
    char* p = (char*)d_ws;
    int* flag = (int*)p;            p += 256;
    float* wf = (float*)p;          p += WF_TOT * 4;
    u16* wfrag = (u16*)p;           p += NFRAG * 2;
    int* gcur_all = (int*)p;        p += 1024 * 4;
    int* bbase_all = (int*)p;       p += 1024 * 4;

    for (int s = 0; s < 4; s++) {
        pk.s[s].src = srcs[s]; pk.s[s].dst = dsts[s];
        pk.s[s].E = Es[s]; pk.s[s].N = Ns[s];
        int nb = cdiv(Ns[s], CRANGE);
        pk.s[s].nb = nb;
        pk.s[s].nblk = cdiv(Es[s], TILE);
        pk.s[s].nbpad = (nb + 15) & ~15;
        pk.s[s].cap = (Es[s] / nb + Es[s] / (8 * nb) + 256 + 3) & ~3;  // % 4 == 0
        pk.s[s].gcur = gcur_all + s * 256;
        pk.s[s].M = (int*)p;        p += (size_t)pk.s[s].nblk * pk.s[s].nbpad * 4;
        pk.s[s].rowptr = (int*)p;   p += ((size_t)(Ns[s] + 1 + 3) & ~(size_t)3) * 4;
        pk.s[s].dis = (float*)p;    p += ((size_t)(Ns[s] + 3) & ~(size_t)3) * 4;
    }
    for (int s = 0; s < 4; s++) {
        pk.s[s].csr = (int*)p;      p += ((size_t)(Es[s] + 3) & ~(size_t)3) * 4;
    }

    // union region (16B aligned): pairs (build) aliases g|act|xt (compute)
    char* U = (char*)(((size_t)p + 15) & ~(size_t)15);
    size_t pairsBytes = 0;
    for (int s = 0; s < 4; s++) {
        pk.s[s].pairs = (u32*)(U + pairsBytes);
        pairsBytes += (size_t)pk.s[s].cap * pk.s[s].nb * 4;
    }
    bf16* g   = (bf16*)U;
    bf16* act = g + gmax;
    bf16* xt  = act + amax;

    // grids
    int ptot = 0, btot = 0;
    for (int s = 0; s < 4; s++) {
        pk.poff[s] = ptot; ptot += pk.s[s].nblk;
        pk.boff[s] = btot; btot += pk.s[s].nb;
    }

    const int B = 256;

    k_detect<<<1, 256, 0, stream>>>((const u16*)x, flag);
    k_prep_w<<<cdiv(WF_TOT + NFRAG, B), B, 0, stream>>>(
        W1, b1, W2, b2, W3, W4, wf, wfrag, flag);
    k_init<<<4, 256, 0, stream>>>(gcur_all, pk);
    k_part_hist<<<ptot, B, 0, stream>>>(pk);
    k_part_scan<<<btot, B, 0, stream>>>(pk);
    k_partition<<<ptot, B, 0, stream>>>(pk);
    k_scan_bbase<<<4, B, 0, stream>>>(pk, bbase_all);
    k_build<<<btot, 512, 0, stream>>>(pk, bbase_all);

    // ---- stage 1 (agg-first): aggregate x (3 feats) -> xt1
    {
        int T = N0 * 3, Hh = (T + 1) >> 1;
        k_pre<3, true><<<cdiv(T, B), B, 0, stream>>>(
            x, nullptr, nullptr, pk.s[0].dis, g, flag, T);
        k_gather2<3, false><<<cdiv(Hh, B), B, 0, stream>>>(
            g, pk.s[0].rowptr, pk.s[0].csr, pk.s[0].dis, nullptr, xt, flag, T, E0);
    }

    // ---- fused stage1-post + stage2-pre: g2 = dis2 * relu(xt1[up1]@W1+b1)
    k_fuse_mm_pre<<<cdiv(N1, B), B, 0, stream>>>(
        xt, up1, wf, pk.s[1].dis, g, N1);

    // ---- stage 2 aggregate -> xt2
    {
        int Tq = N1 * 8, Hq = (Tq + 1) >> 1;
        k_gather2v<32, false><<<cdiv(Hq, B), B, 0, stream>>>(
            g, pk.s[1].rowptr, pk.s[1].csr, pk.s[1].dis, nullptr, xt, flag, Tq, E1);
    }

    // ---- fused stage2-post + stage3-matmul (MFMA): h3 = relu(xt2@W2+b2)@W3
    k_fuse_mm2<<<cdiv(N1, 64), B, 0, stream>>>(xt, wfrag, wf, act, N1);

    // ---- stage 3: g3 = dis3 * h3[up2], then quad-vector aggregate -> act3
    {
        int Tq = N2 * 8, Hq = (Tq + 1) >> 1;
        k_pre<32, false><<<cdiv((long long)N2 * 32, B), B, 0, stream>>>(
            nullptr, up2, act, pk.s[2].dis, g, flag, N2 * 32);
        k_gather2v<32, true><<<cdiv(Hq, B), B, 0, stream>>>(
            g, pk.s[2].rowptr, pk.s[2].csr, pk.s[2].dis, b3, act, flag, Tq, E2);
    }

    // ---- stage 4 (W-first): h4 = act3@W4 at N2, g4 = dis4*h4[up3], aggregate
    {
        int T = N3 * 3, Hh = (T + 1) >> 1;
        k_matmul_seq<32, 3><<<cdiv(N2, B), B, 0, stream>>>(act, wf + WF_W4, xt, N2);
        k_pre<3, false><<<cdiv(T, B), B, 0, stream>>>(
            nullptr, up3, xt, pk.s[3].dis, g, flag, T);
        k_gather2<3, true><<<cdiv(Hh, B), B, 0, stream>>>(
            g, pk.s[3].rowptr, pk.s[3].csr, pk.s[3].dis, b4, act, flag, T, E3);
    }

    // ---- final unpool
    k_gather_out<<<cdiv(N4, B), B, 0, stream>>>(act, up4, d_out, flag, N4);
}

// Round 14
// 438.323 us; speedup vs baseline: 1.1481x; 1.0002x over previous
//
#include <hip/hip_runtime.h>
#include <hip/hip_bf16.h>

typedef __hip_bfloat16 bf16;
typedef unsigned short u16;
typedef unsigned char u8;
typedef unsigned int u32;
typedef __attribute__((ext_vector_type(8))) unsigned short us8;
typedef __attribute__((ext_vector_type(8))) short short8;
typedef __attribute__((ext_vector_type(4))) float f32x4;

static __device__ __forceinline__ float b2f(bf16 v) { return __bfloat162float(v); }
static __device__ __forceinline__ float bfu2f(u32 u) {
    union { u32 i; float f; } c; c.i = u << 16; return c.f;
}
static __device__ __forceinline__ u16 f2bfu(float f) {
    u32 x = __float_as_uint(f);
    return (u16)((x + 0x7FFFu + ((x >> 16) & 1u)) >> 16);
}

#define TILE 4096        // edges per partition block
#define CBITS 12         // coarse bucket = 4096-vertex range (all stages)
#define CRANGE 4096
#define OUTB 26624       // build staging capacity (tot ~24.5K + >8 sigma); 104 KB
// f32 weight scratch layout (floats)
#define WF_W1 0
#define WF_B1 128
#define WF_W2 192
#define WF_B2 2240
#define WF_W3 2304
#define WF_W4 4352
#define WF_TOT 4608
#define NFRAG 4096       // u16 MFMA fragment entries after wf
#define RPT16(M) M(0) M(1) M(2) M(3) M(4) M(5) M(6) M(7) \
                 M(8) M(9) M(10) M(11) M(12) M(13) M(14) M(15)

struct SP {
    const int* src; const int* dst;
    int E, N, cap, nb, nblk, nbpad;
    int* gcur;      // [nb] per-bucket totals (written by k_part_scan)
    u32* pairs;     // [nb][cap] packed (local_dst12 << 20) | src20
    int* M;         // [nblk][nbpad] counts -> exclusive bases
    int* rowptr; float* dis; int* csr;
};
struct Pack {
    SP s[4];
    int poff[4];  // tile-grid start offset per stage
    int boff[4];  // bucket-grid start offset per stage
};

// ---------------- dtype detection ----------------
__global__ void k_detect(const u16* __restrict__ xraw, int* __restrict__ flag) {
    __shared__ int s;
    if (threadIdx.x == 0) s = 0;
    __syncthreads();
    u16 u = xraw[threadIdx.x];
    int e = (u >> 7) & 0xFF;
    if (e >= 0x8F) atomicAdd(&s, 1);
    __syncthreads();
    if (threadIdx.x == 0) flag[0] = (s > 0) ? 1 : 0;
}

// ---------------- one-time weight conversion: f32 scratch + MFMA fragments --
__global__ void k_prep_w(const void* W1, const void* b1, const void* W2,
                         const void* b2, const void* W3, const void* W4,
                         float* __restrict__ wf, u16* __restrict__ wfrag,
                         const int* __restrict__ flag) {
    int t = blockIdx.x * 256 + threadIdx.x;
    int f32m = flag[0];
    if (t < WF_TOT) {
        const void* src; int off; int len;
        if      (t < WF_B1)  { src = W1; off = t - WF_W1; len = 96;  }
        else if (t < WF_W2)  { src = b1; off = t - WF_B1; len = 32;  }
        else if (t < WF_B2)  { src = W2; off = t - WF_W2; len = 2048;}
        else if (t < WF_W3)  { src = b2; off = t - WF_B2; len = 64;  }
        else if (t < WF_W4)  { src = W3; off = t - WF_W3; len = 2048;}
        else                 { src = W4; off = t - WF_W4; len = 96;  }
        if (off >= len) return;
        wf[t] = f32m ? ((const float*)src)[off] : b2f(((const bf16*)src)[off]);
    } else if (t < WF_TOT + NFRAG) {
        int idx = t - WF_TOT;
        int sec = idx >> 9;        // 0..7
        int l = (idx >> 3) & 63;
        int i = idx & 7;
        int cl = l & 15, grp = l >> 4;
        float val;
        if (sec < 4) {             // W2 [32][64]
            int k = grp * 8 + i, col = sec * 16 + cl;
            val = f32m ? ((const float*)W2)[k * 64 + col]
                       : b2f(((const bf16*)W2)[k * 64 + col]);
        } else {                   // W3 [64][32]
            int q = sec - 4, kt = q >> 1, t2 = q & 1;
            int k = kt * 32 + grp * 8 + i, col = t2 * 16 + cl;
            val = f32m ? ((const float*)W3)[k * 32 + col]
                       : b2f(((const bf16*)W3)[k * 32 + col]);
        }
        wfrag[idx] = f2bfu(val);
    }
}

// zero gcur (4 x 256) + rowptr sentinels
__global__ void k_init(int* __restrict__ gcur_all, Pack pk) {
    int i = blockIdx.x * blockDim.x + threadIdx.x;
    if (i < 1024) gcur_all[i] = 0;
    if (i < 4) pk.s[i].rowptr[pk.s[i].N] = pk.s[i].E;
}

// ---------------- pass A0: per-tile bucket counts -> M[tile][bucket] ----------
__global__ void __launch_bounds__(256) k_part_hist(Pack pk) {
    __shared__ int hist[256];
    int bid = blockIdx.x;
    int si = (bid >= pk.poff[3]) ? 3 : (bid >= pk.poff[2]) ? 2 : (bid >= pk.poff[1]) ? 1 : 0;
    const SP sp = pk.s[si];
    int lb = bid - pk.poff[si];
    int t = threadIdx.x;
    int n = min(TILE, sp.E - lb * TILE);
    const int* dstp = sp.dst + lb * TILE;

#define LOADK(k) int d##k; { int i = t + 256*(k); d##k = (i < n) ? dstp[i] : -1; }
    RPT16(LOADK)
#undef LOADK
    hist[t] = 0;
    __syncthreads();
#define HISTK(k) if (d##k >= 0) atomicAdd(&hist[d##k >> CBITS], 1);
    RPT16(HISTK)
#undef HISTK
    __syncthreads();
    int* Mrow = sp.M + (size_t)lb * sp.nbpad;
    for (int b = t; b < sp.nb; b += 256) Mrow[b] = hist[b];
}

// ---------------- pass A-scan: per-bucket column scan of M (in place) --------
__global__ void __launch_bounds__(256) k_part_scan(Pack pk) {
    __shared__ int buf[256];
    int bid = blockIdx.x;
    int si = (bid >= pk.boff[3]) ? 3 : (bid >= pk.boff[2]) ? 2 : (bid >= pk.boff[1]) ? 1 : 0;
    const SP sp = pk.s[si];
    int b = bid - pk.boff[si];
    int t = threadIdx.x;
    int nblk = sp.nblk, nbpad = sp.nbpad;
    int* M = sp.M;
    int carry = 0;
    for (int base = 0; base < nblk; base += 256) {
        int m = min(256, nblk - base);
        int v = (t < m) ? M[(size_t)(base + t) * nbpad + b] : 0;
        buf[t] = v;
        __syncthreads();
        for (int off = 1; off < 256; off <<= 1) {
            int w = (t >= off) ? buf[t - off] : 0;
            __syncthreads();
            buf[t] += w;
            __syncthreads();
        }
        int excl = buf[t] - v + carry;
        int ctot = buf[255];
        __syncthreads();
        if (t < m) M[(size_t)(base + t) * nbpad + b] = excl;
        carry += ctot;
    }
    if (t == 0) sp.gcur[b] = carry;
}

// ---------------- pass A1: scatter to pairs at deterministic bases -----------
__global__ void __launch_bounds__(256) k_partition(Pack pk) {
    __shared__ u32 stage[TILE];   // 16 KB
    __shared__ u8  bkt[TILE];     //  4 KB
    __shared__ int hist[256];
    __shared__ int gofs[256];
    __shared__ int tmp[256];

    int bid = blockIdx.x;
    int si = (bid >= pk.poff[3]) ? 3 : (bid >= pk.poff[2]) ? 2 : (bid >= pk.poff[1]) ? 1 : 0;
    const SP sp = pk.s[si];
    int lb = bid - pk.poff[si];
    int t = threadIdx.x;
    int n = min(TILE, sp.E - lb * TILE);
    const int* dstp = sp.dst + lb * TILE;
    const int* srcp = sp.src + lb * TILE;

#define LOADK(k) int d##k, s##k; { int i = t + 256*(k); \
    if (i < n) { d##k = dstp[i]; s##k = srcp[i]; } else { d##k = -1; s##k = 0; } }
    RPT16(LOADK)
#undef LOADK

    hist[t] = 0;
    __syncthreads();
#define HISTK(k) if (d##k >= 0) atomicAdd(&hist[d##k >> CBITS], 1);
    RPT16(HISTK)
#undef HISTK
    __syncthreads();

    int h = hist[t];
    tmp[t] = h; __syncthreads();
    for (int off = 1; off < 256; off <<= 1) {
        int v = (t >= off) ? tmp[t - off] : 0;
        __syncthreads();
        tmp[t] += v;
        __syncthreads();
    }
    int lofs = tmp[t] - h;
    int gb = (t < sp.nb) ? sp.M[(size_t)lb * sp.nbpad + t] : 0;  // scanned base
    gofs[t] = gb - lofs;
    hist[t] = lofs;   // scatter cursor
    __syncthreads();

#define SCATK(k) if (d##k >= 0) { int b = d##k >> CBITS; \
    int pos = atomicAdd(&hist[b], 1); \
    stage[pos] = (((u32)d##k & 4095u) << 20) | (u32)s##k; \
    bkt[pos] = (u8)b; }
    RPT16(SCATK)
#undef SCATK
    __syncthreads();

    int cap = sp.cap;
    u32* pairs = sp.pairs;
    for (int i = t; i < n; i += 256) {
        int b = bkt[i];
        pairs[(size_t)b * cap + gofs[b] + i] = stage[i];
    }
}

// ---------------- bucket-base scan (one block per stage) ----------------
__global__ void k_scan_bbase(Pack pk, int* __restrict__ bbase_all) {
    __shared__ int tmp[256];
    int si = blockIdx.x;
    int t = threadIdx.x;
    int nb = pk.s[si].nb;
    int v = (t < nb) ? pk.s[si].gcur[t] : 0;
    tmp[t] = v; __syncthreads();
    for (int off = 1; off < 256; off <<= 1) {
        int w = (t >= off) ? tmp[t - off] : 0;
        __syncthreads();
        tmp[t] += w;
        __syncthreads();
    }
    bbase_all[si * 256 + t] = tmp[t] - v;
}

// ---------------- build: one block per coarse bucket, 3 passes --------------
__global__ void __launch_bounds__(512) k_build(Pack pk, const int* __restrict__ bbase_all) {
    __shared__ int hist[4096];    //  16 KB: counts -> local offsets -> cursor
    __shared__ int outb[OUTB];    // 104 KB staged csr for the whole bucket
    __shared__ int tmp[512];

    int bid = blockIdx.x;
    int si = (bid >= pk.boff[3]) ? 3 : (bid >= pk.boff[2]) ? 2 : (bid >= pk.boff[1]) ? 1 : 0;
    const SP sp = pk.s[si];
    int b = bid - pk.boff[si];
    int t = threadIdx.x;

    int bbase = bbase_all[si * 256 + b];
    int tot = sp.gcur[b];
    const u32* p = sp.pairs + (size_t)b * sp.cap;   // 16B aligned (cap % 4 == 0)
    const uint4* p4 = (const uint4*)p;
    int tot4 = tot >> 2;

    for (int i = t; i < 4096; i += 512) hist[i] = 0;
    __syncthreads();
    for (int i = t; i < tot4; i += 512) {
        uint4 u = p4[i];
        atomicAdd(&hist[u.x >> 20], 1);
        atomicAdd(&hist[u.y >> 20], 1);
        atomicAdd(&hist[u.z >> 20], 1);
        atomicAdd(&hist[u.w >> 20], 1);
    }
    for (int i = (tot4 << 2) + t; i < tot; i += 512)
        atomicAdd(&hist[p[i] >> 20], 1);
    __syncthreads();

    // in-place exclusive scan of 4096 bins; counts in registers (8/thread)
    int lbase = t * 8;
    int cnt[8], cof[8];
    #pragma unroll
    for (int k = 0; k < 8; k++) cnt[k] = hist[lbase + k];
    int s = 0;
    #pragma unroll
    for (int k = 0; k < 8; k++) { cof[k] = s; s += cnt[k]; }
    tmp[t] = s; __syncthreads();
    for (int off = 1; off < 512; off <<= 1) {
        int v = (t >= off) ? tmp[t - off] : 0;
        __syncthreads();
        tmp[t] += v;
        __syncthreads();
    }
    int tb = tmp[t] - s;

    int nbase = b << CBITS;
    #pragma unroll
    for (int k = 0; k < 8; k++) {
        int bin = lbase + k;
        hist[bin] = tb + cof[k];          // bucket-local offset (-> cursor)
        int v = nbase + bin;
        if (v < sp.N) {
            sp.rowptr[v] = bbase + tb + cof[k];
            sp.dis[v] = rsqrtf((float)(cnt[k] + 1));
        }
    }
    __syncthreads();

    if (tot <= OUTB) {
        for (int i = t; i < tot4; i += 512) {
            uint4 u = p4[i];
            int pos;
            pos = atomicAdd(&hist[u.x >> 20], 1); outb[pos] = (int)(u.x & 0xFFFFFu);
            pos = atomicAdd(&hist[u.y >> 20], 1); outb[pos] = (int)(u.y & 0xFFFFFu);
            pos = atomicAdd(&hist[u.z >> 20], 1); outb[pos] = (int)(u.z & 0xFFFFFu);
            pos = atomicAdd(&hist[u.w >> 20], 1); outb[pos] = (int)(u.w & 0xFFFFFu);
        }
        for (int i = (tot4 << 2) + t; i < tot; i += 512) {
            u32 u = p[i];
            int pos = atomicAdd(&hist[u >> 20], 1);
            outb[pos] = (int)(u & 0xFFFFFu);
        }
        __syncthreads();
        for (int i = t; i < tot; i += 512)
            sp.csr[bbase + i] = outb[i];
    } else {  // statistical overflow fallback: direct global scatter
        for (int i = t; i < tot; i += 512) {
            u32 u = p[i];
            int pos = atomicAdd(&hist[u >> 20], 1);
            sp.csr[bbase + pos] = (int)(u & 0xFFFFFu);
        }
    }
}

// ---------------- pre-scale: g[v,f] = dis[v] * x_in[row(v), f] ----------------
template <int F, bool EXT>
__global__ void k_pre(const void* __restrict__ xin, const int* __restrict__ gidx,
                      const bf16* __restrict__ actin, const float* __restrict__ dis,
                      bf16* __restrict__ g, const int* __restrict__ flag, int total) {
    int i = blockIdx.x * blockDim.x + threadIdx.x;
    if (i >= total) return;
    int v = i / F;
    int f = i - v * F;
    float x;
    if (EXT) {
        if (flag[0]) x = ((const float*)xin)[i];
        else         x = b2f(((const bf16*)xin)[i]);
    } else {
        int row = gidx[v];
        x = b2f(actin[(size_t)row * F + f]);
    }
    g[i] = __float2bfloat16(dis[v] * x);
}

// ---------------- fused stage1-post + stage2-pre ----------------------------
__global__ void __launch_bounds__(256, 1) k_fuse_mm_pre(
        const bf16* __restrict__ xt1, const int* __restrict__ up,
        const float* __restrict__ wf, const float* __restrict__ dis,
        bf16* __restrict__ g, int n) {
    const float* W = wf + WF_W1;
    const float* B = wf + WF_B1;
    int v = blockIdx.x * 256 + threadIdx.x;
    if (v >= n) return;
    int r = up[v];
    float x0 = b2f(xt1[(size_t)r * 3 + 0]);
    float x1 = b2f(xt1[(size_t)r * 3 + 1]);
    float x2 = b2f(xt1[(size_t)r * 3 + 2]);
    float dv = dis[v];
    #pragma unroll
    for (int f8 = 0; f8 < 4; f8++) {
        us8 ov;
        #pragma unroll
        for (int j = 0; j < 8; j++) {
            int f = f8 * 8 + j;
            float y = B[f];
            y = fmaf(x0, W[f], y);
            y = fmaf(x1, W[32 + f], y);
            y = fmaf(x2, W[64 + f], y);
            y = y > 0.f ? y : 0.f;
            ov[j] = f2bfu(dv * y);
        }
        *(us8*)(g + (size_t)v * 32 + f8 * 8) = ov;
    }
}

// ---------------- fused stage2-post + stage3-matmul, MFMA -------------------
__global__ void __launch_bounds__(256) k_fuse_mm2(
        const bf16* __restrict__ xt2, const u16* __restrict__ wfrag,
        const float* __restrict__ wf, bf16* __restrict__ h, int n) {
    __shared__ u16 Ys[4][16 * 72];   // per-wave Y[16][64], row pad 72
    __shared__ u16 Hs[4][16 * 32];   // per-wave H[16][32] flat
    const float* B2f = wf + WF_B2;
    int t = threadIdx.x;
    int w = t >> 6, l = t & 63;
    int cl = l & 15, grp = l >> 4;
    int v0 = blockIdx.x * 64 + w * 16;
    if (v0 >= n) return;              // whole-wave early out (no barriers used)
    int ar = v0 + cl; ar = ar < n ? ar : n - 1;
    short8 a1 = *(const short8*)(xt2 + (size_t)ar * 32 + grp * 8);
    const short8* wf2 = (const short8*)wfrag;          // [t4][l]
    const short8* wf3 = (const short8*)(wfrag + 2048); // [kt*2+t2][l]
    u16* Y = Ys[w];
    u16* H = Hs[w];
    #pragma unroll
    for (int t4 = 0; t4 < 4; t4++) {
        f32x4 acc = {0.f, 0.f, 0.f, 0.f};
        acc = __builtin_amdgcn_mfma_f32_16x16x32_bf16(a1, wf2[t4 * 64 + l], acc, 0, 0, 0);
        float bias = B2f[t4 * 16 + cl];
        #pragma unroll
        for (int r = 0; r < 4; r++) {
            float y = acc[r] + bias;
            y = y > 0.f ? y : 0.f;
            Y[(4 * grp + r) * 72 + t4 * 16 + cl] = f2bfu(y);
        }
    }
    short8 a20 = *(const short8*)(Y + cl * 72 + grp * 8);
    short8 a21 = *(const short8*)(Y + cl * 72 + 32 + grp * 8);
    #pragma unroll
    for (int t2 = 0; t2 < 2; t2++) {
        f32x4 acc = {0.f, 0.f, 0.f, 0.f};
        acc = __builtin_amdgcn_mfma_f32_16x16x32_bf16(a20, wf3[t2 * 64 + l], acc, 0, 0, 0);
        acc = __builtin_amdgcn_mfma_f32_16x16x32_bf16(a21, wf3[(2 + t2) * 64 + l], acc, 0, 0, 0);
        #pragma unroll
        for (int r = 0; r < 4; r++)
            H[(4 * grp + r) * 32 + t2 * 16 + cl] = f2bfu(acc[r]);
    }
    int orow = v0 + (l >> 2);
    if (orow < n)
        *(us8*)(h + (size_t)orow * 32 + (l & 3) * 8) = *(const us8*)(H + l * 8);
}

// ---------------- streaming matmul: h[v,:] = actin[v,:] @ W  (f32 weights) ---
template <int FIN, int FOUT>
__global__ void __launch_bounds__(256, 1) k_matmul_seq(
        const bf16* __restrict__ actin, const float* __restrict__ W,
        bf16* __restrict__ h, int n) {
    int v = blockIdx.x * blockDim.x + threadIdx.x;
    if (v >= n) return;
    float y[FOUT];
    #pragma unroll
    for (int f = 0; f < FOUT; f++) y[f] = 0.f;
    #pragma unroll
    for (int k8 = 0; k8 < FIN / 8; k8++) {
        us8 xv = *(const us8*)(actin + (size_t)v * FIN + k8 * 8);
        #pragma unroll
        for (int j = 0; j < 8; j++) {
            float xk = bfu2f((u32)(u16)xv[j]);
            const float* wrow = &W[(k8 * 8 + j) * FOUT];
            #pragma unroll
            for (int f = 0; f < FOUT; f++) y[f] = fmaf(xk, wrow[f], y[f]);
        }
    }
    if constexpr (FOUT % 8 == 0) {
        #pragma unroll
        for (int f8 = 0; f8 < FOUT / 8; f8++) {
            us8 ov;
            #pragma unroll
            for (int j = 0; j < 8; j++) ov[j] = f2bfu(y[f8 * 8 + j]);
            *(us8*)(h + (size_t)v * FOUT + f8 * 8) = ov;
        }
    } else {
        #pragma unroll
        for (int f = 0; f < FOUT; f++)
            h[(size_t)v * FOUT + f] = __float2bfloat16(y[f]);
    }
}

// ---------------- CSR gather, QUAD-FEATURE x DUAL-ROW, batch-8 --------------
// 16 independent 8B loads in flight per thread; ~84% of rows (Poisson deg 6)
// finish in ONE batch -> serial chain halves vs batch-4. Clamped slots re-read
// the row's last csr/g lines (L1-hot, no HBM cost).
template <int FOUT, bool FINALIZE>
__global__ void __launch_bounds__(256) k_gather2v(
        const bf16* __restrict__ g, const int* __restrict__ rowptr,
        const int* __restrict__ csr, const float* __restrict__ dis,
        const void* __restrict__ bias, bf16* __restrict__ out,
        const int* __restrict__ flag, int totq, int E) {
    constexpr int Q = FOUT / 4;         // quads per row
    constexpr u32 W2 = FOUT / 2;        // u32 words per row
    int H = (totq + 1) >> 1;
    int i = blockIdx.x * blockDim.x + threadIdx.x;
    if (i >= H) return;
    int Em1 = E - 1;
    int e1 = i;
    int e2 = i + H;
    int e2c = (e2 < totq) ? e2 : e1;
    int v1 = e1 / Q, q1 = e1 - v1 * Q;
    int v2 = e2c / Q, q2 = e2c - v2 * Q;
    u32 qo1 = (u32)(q1 * 2), qo2 = (u32)(q2 * 2);
    const u32* g32 = (const u32*)g;

    uint2 sv1 = *(const uint2*)(g32 + (u32)v1 * W2 + qo1);
    uint2 sv2 = *(const uint2*)(g32 + (u32)v2 * W2 + qo2);
    float s10 = bfu2f(sv1.x & 0xFFFFu), s11 = bfu2f(sv1.x >> 16);
    float s12 = bfu2f(sv1.y & 0xFFFFu), s13 = bfu2f(sv1.y >> 16);
    float s20 = bfu2f(sv2.x & 0xFFFFu), s21 = bfu2f(sv2.x >> 16);
    float s22 = bfu2f(sv2.y & 0xFFFFu), s23 = bfu2f(sv2.y >> 16);

    int r1 = rowptr[v1]; int c1 = rowptr[v1 + 1] - r1;
    int r2 = rowptr[v2]; int c2 = rowptr[v2 + 1] - r2;
    int last1 = min(r1 + (c1 > 0 ? c1 - 1 : 0), Em1);
    int last2 = min(r2 + (c2 > 0 ? c2 - 1 : 0), Em1);
    int j1 = 0, j2 = 0;
    while (j1 < c1 || j2 < c2) {
        u32 uu1[8], uu2[8];
        #pragma unroll
        for (int k = 0; k < 8; k++) {
            uu1[k] = (u32)csr[min(r1 + j1 + k, last1)];
            uu2[k] = (u32)csr[min(r2 + j2 + k, last2)];
        }
        uint2 a1[8], a2[8];
        #pragma unroll
        for (int k = 0; k < 8; k++) {
            a1[k] = *(const uint2*)(g32 + uu1[k] * W2 + qo1);
            a2[k] = *(const uint2*)(g32 + uu2[k] * W2 + qo2);
        }
        #pragma unroll
        for (int k = 0; k < 8; k++) {
            if (j1 + k >= c1) { a1[k].x = 0; a1[k].y = 0; }
            if (j2 + k >= c2) { a2[k].x = 0; a2[k].y = 0; }
        }
        #pragma unroll
        for (int k = 0; k < 8; k++) {
            s10 += bfu2f(a1[k].x & 0xFFFFu);
            s11 += bfu2f(a1[k].x >> 16);
            s12 += bfu2f(a1[k].y & 0xFFFFu);
            s13 += bfu2f(a1[k].y >> 16);
            s20 += bfu2f(a2[k].x & 0xFFFFu);
            s21 += bfu2f(a2[k].x >> 16);
            s22 += bfu2f(a2[k].y & 0xFFFFu);
            s23 += bfu2f(a2[k].y >> 16);
        }
        j1 += 8; j2 += 8;
    }
    float dv1 = dis[v1], dv2 = dis[v2];
    float o1[4] = {s10, s11, s12, s13};
    float o2[4] = {s20, s21, s22, s23};
    uint2 w1, w2;
    if (FINALIZE) {
        int f32m = flag[0];
        #pragma unroll
        for (int k = 0; k < 4; k++) {
            int f1 = q1 * 4 + k, f2 = q2 * 4 + k;
            float bf1 = f32m ? ((const float*)bias)[f1] : b2f(((const bf16*)bias)[f1]);
            float bf2 = f32m ? ((const float*)bias)[f2] : b2f(((const bf16*)bias)[f2]);
            o1[k] = fmaf(dv1, o1[k], bf1); o1[k] = o1[k] > 0.f ? o1[k] : 0.f;
            o2[k] = fmaf(dv2, o2[k], bf2); o2[k] = o2[k] > 0.f ? o2[k] : 0.f;
        }
    } else {
        #pragma unroll
        for (int k = 0; k < 4; k++) { o1[k] *= dv1; o2[k] *= dv2; }
    }
    w1.x = (u32)f2bfu(o1[0]) | ((u32)f2bfu(o1[1]) << 16);
    w1.y = (u32)f2bfu(o1[2]) | ((u32)f2bfu(o1[3]) << 16);
    w2.x = (u32)f2bfu(o2[0]) | ((u32)f2bfu(o2[1]) << 16);
    w2.y = (u32)f2bfu(o2[2]) | ((u32)f2bfu(o2[3]) << 16);
    u32* o32 = (u32*)out;
    *(uint2*)(o32 + (u32)v1 * W2 + qo1) = w1;
    if (e2 < totq) *(uint2*)(o32 + (u32)v2 * W2 + qo2) = w2;
}

// ---------------- CSR gather, DUAL-ROW per thread (FOUT=3 path) -------------
template <int FOUT, bool FINALIZE>
__global__ void __launch_bounds__(256) k_gather2(
        const bf16* __restrict__ g, const int* __restrict__ rowptr,
        const int* __restrict__ csr, const float* __restrict__ dis,
        const void* __restrict__ bias, bf16* __restrict__ out,
        const int* __restrict__ flag, int total, int E) {
    int H = (total + 1) >> 1;
    int i = blockIdx.x * blockDim.x + threadIdx.x;
    if (i >= H) return;
    int Em1 = E - 1;
    int e1 = i;
    int e2 = i + H;
    int e2c = (e2 < total) ? e2 : e1;
    int v1 = e1 / FOUT, f1 = e1 - v1 * FOUT;
    int v2 = e2c / FOUT, f2 = e2c - v2 * FOUT;
    float s1 = b2f(g[e1]);    // self-loop terms
    float s2 = b2f(g[e2c]);
    int r1 = rowptr[v1]; int c1 = rowptr[v1 + 1] - r1;
    int r2 = rowptr[v2]; int c2 = rowptr[v2 + 1] - r2;
    int last1 = min(r1 + (c1 > 0 ? c1 - 1 : 0), Em1);
    int last2 = min(r2 + (c2 > 0 ? c2 - 1 : 0), Em1);
    int j1 = 0, j2 = 0;
    while (j1 < c1 || j2 < c2) {
        int i10 = min(r1 + j1 + 0, last1), i11 = min(r1 + j1 + 1, last1);
        int i12 = min(r1 + j1 + 2, last1), i13 = min(r1 + j1 + 3, last1);
        int i20 = min(r2 + j2 + 0, last2), i21 = min(r2 + j2 + 1, last2);
        int i22 = min(r2 + j2 + 2, last2), i23 = min(r2 + j2 + 3, last2);
        int u10 = csr[i10], u11 = csr[i11], u12 = csr[i12], u13 = csr[i13];
        int u20 = csr[i20], u21 = csr[i21], u22 = csr[i22], u23 = csr[i23];
        float a10 = b2f(g[(size_t)u10 * FOUT + f1]);
        float a11 = b2f(g[(size_t)u11 * FOUT + f1]);
        float a12 = b2f(g[(size_t)u12 * FOUT + f1]);
        float a13 = b2f(g[(size_t)u13 * FOUT + f1]);
        float a20 = b2f(g[(size_t)u20 * FOUT + f2]);
        float a21 = b2f(g[(size_t)u21 * FOUT + f2]);
        float a22 = b2f(g[(size_t)u22 * FOUT + f2]);
        float a23 = b2f(g[(size_t)u23 * FOUT + f2]);
        s1 += ((j1 + 0 < c1 ? a10 : 0.f) + (j1 + 1 < c1 ? a11 : 0.f))
            + ((j1 + 2 < c1 ? a12 : 0.f) + (j1 + 3 < c1 ? a13 : 0.f));
        s2 += ((j2 + 0 < c2 ? a20 : 0.f) + (j2 + 1 < c2 ? a21 : 0.f))
            + ((j2 + 2 < c2 ? a22 : 0.f) + (j2 + 3 < c2 ? a23 : 0.f));
        j1 += 4; j2 += 4;
    }
    float dv1 = dis[v1], dv2 = dis[v2];
    float o1, o2;
    if (FINALIZE) {
        float bf1 = flag[0] ? ((const float*)bias)[f1] : b2f(((const bf16*)bias)[f1]);
        float bf2 = flag[0] ? ((const float*)bias)[f2] : b2f(((const bf16*)bias)[f2]);
        o1 = fmaf(dv1, s1, bf1); o1 = o1 > 0.f ? o1 : 0.f;
        o2 = fmaf(dv2, s2, bf2); o2 = o2 > 0.f ? o2 : 0.f;
    } else {
        o1 = dv1 * s1;
        o2 = dv2 * s2;
    }
    out[e1] = __float2bfloat16(o1);
    if (e2 < total) out[e2] = __float2bfloat16(o2);
}

// ---------------- final unpool gather -> out (dtype per flag) ----------------
__global__ void k_gather_out(const bf16* __restrict__ act, const int* __restrict__ idx,
                             void* __restrict__ out, const int* __restrict__ flag, int n) {
    int u = blockIdx.x * blockDim.x + threadIdx.x;
    if (u >= n) return;
    size_t r = (size_t)idx[u];
    float v0 = b2f(act[3 * r + 0]);
    float v1 = b2f(act[3 * r + 1]);
    float v2 = b2f(act[3 * r + 2]);
    if (flag[0]) {
        float* o = (float*)out;
        o[3 * (size_t)u + 0] = v0; o[3 * (size_t)u + 1] = v1; o[3 * (size_t)u + 2] = v2;
    } else {
        bf16* o = (bf16*)out;
        o[3 * (size_t)u + 0] = __float2bfloat16(v0);
        o[3 * (size_t)u + 1] = __float2bfloat16(v1);
        o[3 * (size_t)u + 2] = __float2bfloat16(v2);
    }
}

static inline int cdiv(long long a, long long b) { return (int)((a + b - 1) / b); }

extern "C" void kernel_launch(void* const* d_in, const int* in_sizes, int n_in,
                              void* d_out, int out_size, void* d_ws, size_t ws_size,
                              hipStream_t stream) {
    const void* x  = d_in[0];
    const void* W1 = d_in[1]; const void* b1 = d_in[2];
    const void* W2 = d_in[3]; const void* b2 = d_in[4];
    const void* W3 = d_in[5]; const void* b3 = d_in[6];
    const void* W4 = d_in[7]; const void* b4 = d_in[8];
    const int* e0  = (const int*)d_in[9];
    const int* up1 = (const int*)d_in[10];
    const int* e1  = (const int*)d_in[11];
    const int* up2 = (const int*)d_in[12];
    const int* e2  = (const int*)d_in[13];
    const int* up3 = (const int*)d_in[14];
    const int* e3  = (const int*)d_in[15];
    const int* up4 = (const int*)d_in[16];

    const int N0 = in_sizes[0] / 3;
    const int N1 = in_sizes[10];
    const int N2 = in_sizes[12];
    const int N3 = in_sizes[14];
    const int N4 = in_sizes[16];
    const int E0 = in_sizes[9] / 2, E1 = in_sizes[11] / 2;
    const int E2 = in_sizes[13] / 2, E3 = in_sizes[15] / 2;

    int Ns[4] = {N0, N1, N2, N3};
    int Es[4] = {E0, E1, E2, E3};
    const int* srcs[4] = {e0, e1, e2, e3};
    const int* dsts[4] = {e0 + E0, e1 + E1, e2 + E2, e3 + E3};

    // buffer element counts
    size_t gmax = (size_t)N0 * 3;
    if ((size_t)N1 * 32 > gmax) gmax = (size_t)N1 * 32;
    if ((size_t)N2 * 32 > gmax) gmax = (size_t)N2 * 32;
    if ((size_t)N3 * 3  > gmax) gmax = (size_t)N3 * 3;
    size_t amax = (size_t)N0 * 32;
    if ((size_t)N1 * 64 > amax) amax = (size_t)N1 * 64;
    if ((size_t)N2 * 32 > amax) amax = (size_t)N2 * 32;
    if ((size_t)N3 * 3  > amax) amax = (size_t)N3 * 3;
    gmax = (gmax + 7) & ~(size_t)7;
    amax = (amax + 7) & ~(size_t)7;

    Pack pk;
    char* p = (char*)d_ws;
    int* flag = (int*)p;            p += 256;
    float* wf = (float*)p;          p += WF_TOT * 4;
    u16* wfrag = (u16*)p;           p += NFRAG * 2;
    int* gcur_all = (int*)p;        p += 1024 * 4;
    int* bbase_all = (int*)p;       p += 1024 * 4;

    for (int s = 0; s < 4; s++) {
        pk.s[s].src = srcs[s]; pk.s[s].dst = dsts[s];
        pk.s[s].E = Es[s]; pk.s[s].N = Ns[s];
        int nb = cdiv(Ns[s], CRANGE);
        pk.s[s].nb = nb;
        pk.s[s].nblk = cdiv(Es[s], TILE);
        pk.s[s].nbpad = (nb + 15) & ~15;
        pk.s[s].cap = (Es[s] / nb + Es[s] / (8 * nb) + 256 + 3) & ~3;  // % 4 == 0
        pk.s[s].gcur = gcur_all + s * 256;
        pk.s[s].M = (int*)p;        p += (size_t)pk.s[s].nblk * pk.s[s].nbpad * 4;
        pk.s[s].rowptr = (int*)p;   p += ((size_t)(Ns[s] + 1 + 3) & ~(size_t)3) * 4;
        pk.s[s].dis = (float*)p;    p += ((size_t)(Ns[s] + 3) & ~(size_t)3) * 4;
    }
    for (int s = 0; s < 4; s++) {
        pk.s[s].csr = (int*)p;      p += ((size_t)(Es[s] + 3) & ~(size_t)3) * 4;
    }

    // union region (16B aligned): pairs (build) aliases g|act|xt (compute)
    char* U = (char*)(((size_t)p + 15) & ~(size_t)15);
    size_t pairsBytes = 0;
    for (int s = 0; s < 4; s++) {
        pk.s[s].pairs = (u32*)(U + pairsBytes);
        pairsBytes += (size_t)pk.s[s].cap * pk.s[s].nb * 4;
    }
    bf16* g   = (bf16*)U;
    bf16* act = g + gmax;
    bf16* xt  = act + amax;

    // grids
    int ptot = 0, btot = 0;
    for (int s = 0; s < 4; s++) {
        pk.poff[s] = ptot; ptot += pk.s[s].nblk;
        pk.boff[s] = btot; btot += pk.s[s].nb;
    }

    const int B = 256;

    k_detect<<<1, 256, 0, stream>>>((const u16*)x, flag);
    k_prep_w<<<cdiv(WF_TOT + NFRAG, B), B, 0, stream>>>(
        W1, b1, W2, b2, W3, W4, wf, wfrag, flag);
    k_init<<<4, 256, 0, stream>>>(gcur_all, pk);
    k_part_hist<<<ptot, B, 0, stream>>>(pk);
    k_part_scan<<<btot, B, 0, stream>>>(pk);
    k_partition<<<ptot, B, 0, stream>>>(pk);
    k_scan_bbase<<<4, B, 0, stream>>>(pk, bbase_all);
    k_build<<<btot, 512, 0, stream>>>(pk, bbase_all);

    // ---- stage 1 (agg-first): aggregate x (3 feats) -> xt1
    {
        int T = N0 * 3, Hh = (T + 1) >> 1;
        k_pre<3, true><<<cdiv(T, B), B, 0, stream>>>(
            x, nullptr, nullptr, pk.s[0].dis, g, flag, T);
        k_gather2<3, false><<<cdiv(Hh, B), B, 0, stream>>>(
            g, pk.s[0].rowptr, pk.s[0].csr, pk.s[0].dis, nullptr, xt, flag, T, E0);
    }

    // ---- fused stage1-post + stage2-pre: g2 = dis2 * relu(xt1[up1]@W1+b1)
    k_fuse_mm_pre<<<cdiv(N1, B), B, 0, stream>>>(
        xt, up1, wf, pk.s[1].dis, g, N1);

    // ---- stage 2 aggregate -> xt2
    {
        int Tq = N1 * 8, Hq = (Tq + 1) >> 1;
        k_gather2v<32, false><<<cdiv(Hq, B), B, 0, stream>>>(
            g, pk.s[1].rowptr, pk.s[1].csr, pk.s[1].dis, nullptr, xt, flag, Tq, E1);
    }

    // ---- fused stage2-post + stage3-matmul (MFMA): h3 = relu(xt2@W2+b2)@W3
    k_fuse_mm2<<<cdiv(N1, 64), B, 0, stream>>>(xt, wfrag, wf, act, N1);

    // ---- stage 3: g3 = dis3 * h3[up2], then quad-vector aggregate -> act3
    {
        int Tq = N2 * 8, Hq = (Tq + 1) >> 1;
        k_pre<32, false><<<cdiv((long long)N2 * 32, B), B, 0, stream>>>(
            nullptr, up2, act, pk.s[2].dis, g, flag, N2 * 32);
        k_gather2v<32, true><<<cdiv(Hq, B), B, 0, stream>>>(
            g, pk.s[2].rowptr, pk.s[2].csr, pk.s[2].dis, b3, act, flag, Tq, E2);
    }

    // ---- stage 4 (W-first): h4 = act3@W4 at N2, g4 = dis4*h4[up3], aggregate
    {
        int T = N3 * 3, Hh = (T + 1) >> 1;
        k_matmul_seq<32, 3><<<cdiv(N2, B), B, 0, stream>>>(act, wf + WF_W4, xt, N2);
        k_pre<3, false><<<cdiv(T, B), B, 0, stream>>>(
            nullptr, up3, xt, pk.s[3].dis, g, flag, T);
        k_gather2<3, true><<<cdiv(Hh, B), B, 0, stream>>>(
            g, pk.s[3].rowptr, pk.s[3].csr, pk.s[3].dis, b4, act, flag, T, E3);
    }

    // ---- final unpool
    k_gather_out<<<cdiv(N4, B), B, 0, stream>>>(act, up4, d_out, flag, N4);
}